// Round 10
// baseline (2247.177 us; speedup 1.0000x reference)
//
#include <hip/hip_runtime.h>
#include <string.h>

// ---------------- problem constants ----------------
constexpr int M_LZ = 64;           // Lanczos steps (absmax 64 = 1 bf16 ulp, 5.5x under threshold)

// CSR capacity per matrix (expected nnz * ~1.25)
constexpr int CAP_L0 = 26240, CAP_L1 = 118016, CAP_L2 = 52480, CAP_B1 = 39360, CAP_B2 = 78720;
constexpr int CB_L0 = 0;
constexpr int CB_L1D = CB_L0 + CAP_L0;
constexpr int CB_L1U = CB_L1D + CAP_L1;
constexpr int CB_L2  = CB_L1U + CAP_L1;
constexpr int CB_B1  = CB_L2 + CAP_L2;
constexpr int CB_B2  = CB_B1 + CAP_B1;
constexpr int CAP_TOT= CB_B2 + CAP_B2;   // 432832
constexpr int CB_B1T = CAP_TOT;
constexpr int CB_B2T = CB_B1T + CAP_B1;
constexpr int CAP_TOT2 = CB_B2T + CAP_B2; // 550912

// rowptr offsets (ints) within W_PTR region
constexpr int P_L0=0, P_L1D=1025, P_L1U=4098, P_L2=7171, P_B1=9220, P_B2=10245;
constexpr int P_B1T=13320, P_B2T=16393;   // region size 18444
// row-count offsets within W_CNT region
constexpr int C_L0=0, C_L1D=1024, C_L1U=4096, C_L2=7168, C_B1=9216, C_B2=10240;
constexpr int C_B1T=13312, C_B2T=16384;   // region size 18432

constexpr size_t HBUF  = (size_t)6144*128;          // 786432 words
constexpr size_t SLSTR = (size_t)6144*16;           // 98304 words per channel-slice

// workspace layout (units: 4-byte words)
constexpr size_t W_CNT = 0;                         // 18432 ints
constexpr size_t W_PTR = 18432;                     // 18444 ints
constexpr size_t W_CUR = W_PTR + 18444;             // 5120 ints
constexpr size_t W_CIDX= W_CUR + 5120;              // CAP_TOT2 ints
constexpr size_t W_VAL = W_CIDX + CAP_TOT2;         // CAP_TOT2 floats
// write-once step-indexed Lanczos vectors: v_0..v_63 then w_0..w_63 (global 6144 rows)
constexpr size_t W_VW  = W_VAL + CAP_TOT2;          // 128*6144 = 786432
// tridiagonal entries: TT[g][j] = (a, g, n), padded to one 128B line each
constexpr size_t W_TT  = W_VW + 786432;             // 3*64*32 = 6144
constexpr size_t W_EPS = W_TT + 6144;               // 4*32 (per-group padded line)
constexpr size_t W_UV  = W_EPS + 128;               // 4*3072 (U_d,V_d,U_u,V_u)
// write-once harmonic buffers, CHANNEL-SLICED: [s][slice][row][16]
constexpr size_t W_H   = W_UV + 4*3072;             // 15*HBUF
constexpr size_t W_SCAT= W_H + 15*HBUF;
constexpr size_t S0_OFF= 0;                          // 1024 x 384
constexpr size_t S1_OFF= (size_t)1024*384;           // 3072 x 640
constexpr size_t S2_OFF= S1_OFF + (size_t)3072*640;  // 2048 x 384
constexpr size_t SCAT_TOT = S2_OFF + (size_t)2048*384;
constexpr size_t W_WCAT= W_SCAT + SCAT_TOT;          // 1408*128 concatenated weights
constexpr size_t WC0=0, WC1=(size_t)384*128, WC2=WC1+(size_t)640*128;
// per-block dot partial slots, step-indexed (write-once): [j][b] -> 8 floats (32B)
constexpr size_t W_SLOT= W_WCAT + (size_t)1408*128;  // 64*1024*8 = 524288
// per-block arrival flags (monotonic phase counters), padded 128B each
constexpr size_t W_FLG = W_SLOT + 524288;            // 1024*32
// release copies: 4 groups x 16 leaves, padded 128B each
constexpr size_t W_REL = W_FLG + 32768;              // 2048

__device__ __forceinline__ float wredf(float v){
  #pragma unroll
  for(int o=32;o;o>>=1) v += __shfl_xor(v,o,64);
  return v;
}
__device__ __forceinline__ int wredi(int v){
  #pragma unroll
  for(int o=32;o;o>>=1) v += __shfl_xor(v,o,64);
  return v;
}

// agent-scope (L2-bypassing) ops
__device__ __forceinline__ float ldc(const float* p){
  return __hip_atomic_load(p, __ATOMIC_RELAXED, __HIP_MEMORY_SCOPE_AGENT);
}
__device__ __forceinline__ float2 ldc2(const float* p){
  unsigned long long u = __hip_atomic_load((const unsigned long long*)p,
                          __ATOMIC_RELAXED, __HIP_MEMORY_SCOPE_AGENT);
  float2 r; memcpy(&r,&u,8); return r;
}
__device__ __forceinline__ void stc(float* p, float v){
  __hip_atomic_store(p, v, __ATOMIC_RELAXED, __HIP_MEMORY_SCOPE_AGENT);
}
__device__ __forceinline__ void stc2(float* p, float2 v){
  unsigned long long u; memcpy(&u,&v,8);
  __hip_atomic_store((unsigned long long*)p, u, __ATOMIC_RELAXED, __HIP_MEMORY_SCOPE_AGENT);
}
__device__ __forceinline__ int ldci(const int* p){
  return __hip_atomic_load(p, __ATOMIC_RELAXED, __HIP_MEMORY_SCOPE_AGENT);
}
__device__ __forceinline__ void stci(int* p, int v){
  __hip_atomic_store(p, v, __ATOMIC_RELAXED, __HIP_MEMORY_SCOPE_AGENT);
}

// ---- flag-array barrier: NO same-address RMW anywhere ----
__device__ __forceinline__ void barx(float* ws, int b, int grp, int lbase, int Ng,
                                     bool chk, int lb, int ph, int jslot, float* shr){
  const int t = threadIdx.x, lane = t&63, wvv = t>>6;
  int* flg = (int*)ws + W_FLG;
  int* rel = (int*)ws + W_REL;
  __builtin_amdgcn_s_waitcnt(0);   // every thread drains its stores
  __syncthreads();
  if (t==0) stci(flg + (size_t)b*32, ph+1);
  if (chk){
    for (int s=t; s<Ng; s+=256){
      const int* f = flg + (size_t)(lbase+s)*32;
      while (ldci(f) < ph+1) __builtin_amdgcn_s_sleep(2);
    }
    if (jslot>=0){
      float pa=0.f, pg=0.f, pn=0.f;
      for (int s=t; s<Ng; s+=256){
        const float* sl = ws + W_SLOT + ((size_t)jslot*1024 + lbase+s)*8;
        float2 ag = ldc2(sl); float nn = ldc(sl+2);
        pa+=ag.x; pg+=ag.y; pn+=nn;
      }
      pa=wredf(pa); pg=wredf(pg); pn=wredf(pn);
      if (lane==0){ shr[0*4+wvv]=pa; shr[1*4+wvv]=pg; shr[2*4+wvv]=pn; }
    }
    __syncthreads();
    if (t==0){
      if (jslot>=0){
        float a=shr[0]+shr[1]+shr[2]+shr[3];
        float g=shr[4]+shr[5]+shr[6]+shr[7];
        float n=shr[8]+shr[9]+shr[10]+shr[11];
        float* TT = ws + W_TT + (size_t)(grp*64 + jslot)*32;
        stc2(TT, make_float2(a,g)); stc(TT+2, n);
        __builtin_amdgcn_s_waitcnt(0);   // TT visible before release
      }
      #pragma unroll
      for (int i=0;i<16;i++) stci(rel + (size_t)(grp*16+i)*32, ph+1);
    }
    __syncthreads();
  } else {
    if (t==0){
      const int* r = rel + (size_t)(grp*16 + (lb&15))*32;
      while (ldci(r) < ph+1) __builtin_amdgcn_s_sleep(2);
    }
    __syncthreads();
  }
}

// ---------------- weight prep + zeroing of counters/flags ----------------
__global__ void k_wprep(const float* Wd,const float* Wu,const float* Wh,
                        const float* Wb1,const float* Wb2, float* ws){
  int t = blockIdx.x*256 + threadIdx.x;
  if (t >= 16384) return;
  int* wsi = (int*)ws;
  if (t < 5120) wsi[W_CNT + 13312 + t] = 0;          // transpose col counters
  if (t < 5120) wsi[W_CUR + t] = 0;                  // cursors
  for (int i=t; i<32768+2048; i+=16384) wsi[W_FLG+i] = 0;  // flags + releases
  float sd = Wd[t]  + Wd[16384+t]  + Wd[32768+t];
  float su = Wu[t]  + Wu[16384+t]  + Wu[32768+t];
  float s1 = Wb1[t] + Wb1[16384+t] + Wb1[32768+t];
  float s2 = Wb2[t] + Wb2[16384+t] + Wb2[32768+t];
  float wh = Wh[t];
  float* W0 = ws + W_WCAT + WC0;
  float* W1 = ws + W_WCAT + WC1;
  float* W2 = ws + W_WCAT + WC2;
  W0[t]=sd; W0[16384+t]=s1; W0[32768+t]=wh;
  W1[t]=sd; W1[16384+t]=su; W1[32768+t]=s1; W1[49152+t]=s2; W1[65536+t]=wh;
  W2[t]=su; W2[16384+t]=s2; W2[32768+t]=wh;
}

// ---------------- CSR extraction (proven) ----------------
__device__ __forceinline__ void mat_meta(int wid, const float* L0,const float* L1d,const float* L1u,
    const float* L2,const float* B1,const float* B2,
    const float*& M,int& ncol,int& lrow,int& co,int& po,int& cb,int& cap,int& tco){
  if (wid < 1024){ M=L0;  ncol=1024; lrow=wid;        co=C_L0;  po=P_L0;  cb=CB_L0;  cap=CAP_L0; tco=-1; }
  else if (wid < 4096){ M=L1d; ncol=3072; lrow=wid-1024;  co=C_L1D; po=P_L1D; cb=CB_L1D; cap=CAP_L1; tco=-1; }
  else if (wid < 7168){ M=L1u; ncol=3072; lrow=wid-4096;  co=C_L1U; po=P_L1U; cb=CB_L1U; cap=CAP_L1; tco=-1; }
  else if (wid < 9216){ M=L2;  ncol=2048; lrow=wid-7168;  co=C_L2;  po=P_L2;  cb=CB_L2;  cap=CAP_L2; tco=-1; }
  else if (wid < 10240){ M=B1; ncol=3072; lrow=wid-9216;  co=C_B1;  po=P_B1;  cb=CB_B1;  cap=CAP_B1; tco=C_B1T; }
  else { M=B2; ncol=2048; lrow=wid-10240; co=C_B2;  po=P_B2;  cb=CB_B2;  cap=CAP_B2; tco=C_B2T; }
}

__global__ void k_count(const float* L0,const float* L1d,const float* L1u,const float* L2,
                        const float* B1,const float* B2,int* cnt){
  int wid = blockIdx.x*4 + (threadIdx.x>>6);
  int lane = threadIdx.x & 63;
  if (wid >= 13312) return;
  const float* M; int ncol,lrow,co,po,cb,cap,tco;
  mat_meta(wid,L0,L1d,L1u,L2,B1,B2,M,ncol,lrow,co,po,cb,cap,tco);
  const float4* row4 = (const float4*)(M + (size_t)lrow*ncol);
  int c = 0;
  for (int j0=0; j0<ncol; j0+=256){
    float4 v = row4[(j0>>2)+lane];
    int n0=v.x!=0.f, n1=v.y!=0.f, n2=v.z!=0.f, n3=v.w!=0.f;
    c += n0+n1+n2+n3;
    if (tco>=0){
      int jb = j0 + lane*4;
      if (n0) atomicAdd(cnt+tco+jb,   1);
      if (n1) atomicAdd(cnt+tco+jb+1, 1);
      if (n2) atomicAdd(cnt+tco+jb+2, 1);
      if (n3) atomicAdd(cnt+tco+jb+3, 1);
    }
  }
  c = wredi(c);
  if (lane==0) cnt[co+lrow] = c;
}

__global__ void k_prefix(const int* cnt, int* ptr, int* cur){
  __shared__ int lds[257];
  const int rows[8]={1024,3072,3072,2048,1024,3072,3072,2048};
  const int cofs[8]={C_L0,C_L1D,C_L1U,C_L2,C_B1,C_B2,C_B1T,C_B2T};
  const int pofs[8]={P_L0,P_L1D,P_L1U,P_L2,P_B1,P_B2,P_B1T,P_B2T};
  int b=blockIdx.x, t=threadIdx.x;
  int R=rows[b]; const int* c=cnt+cofs[b]; int* p=ptr+pofs[b];
  int* cc = (b==6)? cur : (b==7)? cur+3072 : nullptr;
  int chunk=(R+255)/256;
  int lo=t*chunk, hi=min(R,lo+chunk);
  int s=0;
  for(int i=lo;i<hi;i++) s+=c[i];
  lds[t]=s; __syncthreads();
  if(t==0){ int run=0; for(int i=0;i<256;i++){int x=lds[i];lds[i]=run;run+=x;} lds[256]=run; }
  __syncthreads();
  int run=lds[t];
  for(int i=lo;i<hi;i++){ p[i]=run; if(cc) cc[i]=run; run+=c[i]; }
  if(t==0) p[R]=lds[256];
}

__global__ void k_fill(const float* L0,const float* L1d,const float* L1u,const float* L2,
                       const float* B1,const float* B2,const int* ptr,int* cidx,float* val){
  int wid = blockIdx.x*4 + (threadIdx.x>>6);
  int lane = threadIdx.x & 63;
  if (wid >= 13312) return;
  const float* M; int ncol,lrow,co,po,cb,cap,tco;
  mat_meta(wid,L0,L1d,L1u,L2,B1,B2,M,ncol,lrow,co,po,cb,cap,tco);
  const float4* row4 = (const float4*)(M + (size_t)lrow*ncol);
  int base = ptr[po+lrow];
  int run = 0;
  for (int j0=0; j0<ncol; j0+=256){
    float4 v = row4[(j0>>2)+lane];
    int n0=v.x!=0.f, n1=v.y!=0.f, n2=v.z!=0.f, n3=v.w!=0.f;
    int local = n0+n1+n2+n3;
    int incl = local;
    #pragma unroll
    for (int o=1;o<64;o<<=1){
      int tmp = __shfl_up(incl,o,64);
      if (lane>=o) incl += tmp;
    }
    int tot = __shfl(incl,63,64);
    int pos = base + run + incl - local;
    int jb = j0 + lane*4;
    if (n0){ if(pos<cap){cidx[cb+pos]=jb;   val[cb+pos]=v.x;} pos++; }
    if (n1){ if(pos<cap){cidx[cb+pos]=jb+1; val[cb+pos]=v.y;} pos++; }
    if (n2){ if(pos<cap){cidx[cb+pos]=jb+2; val[cb+pos]=v.z;} pos++; }
    if (n3){ if(pos<cap){cidx[cb+pos]=jb+3; val[cb+pos]=v.w;} pos++; }
    run += tot;
  }
}

__global__ void k_fillT(float* ws){
  int wid = blockIdx.x*4 + (threadIdx.x>>6);
  int lane = threadIdx.x & 63;
  if (wid >= 4096) return;
  int* wsi=(int*)ws;
  const int* ptr=wsi+W_PTR; int* cidx=wsi+W_CIDX; float* val=ws+W_VAL;
  int* cur=wsi+W_CUR;
  if (wid < 1024){
    int r=wid;
    int e=ptr[P_B1+r+1];
    for(int k=ptr[P_B1+r]+lane;k<e;k+=64){
      int c=cidx[CB_B1+k]; float v=val[CB_B1+k];
      int pos=atomicAdd(cur+c,1);
      cidx[CB_B1T+pos]=r; val[CB_B1T+pos]=v;
    }
  } else {
    int r=wid-1024;
    int e=ptr[P_B2+r+1];
    for(int k=ptr[P_B2+r]+lane;k<e;k+=64){
      int c=cidx[CB_B2+k]; float v=val[CB_B2+k];
      int pos=atomicAdd(cur+3072+c,1);
      cidx[CB_B2T+pos]=r; val[CB_B2T+pos]=v;
    }
  }
}

// ================= FUSED PERSISTENT SOLVER =================
// 1024 blocks x 256 threads = 4 blocks/CU, all co-resident.
// Groups: g0=c0 [0,128), g1=c1 [128,704), g2=c2 [704,1024).
// Lanczos: w_j = (A w_{j-1} - a w_{j-1} - g w_{j-2})/beta -> ONE gather load/nnz.
// Harmonic: channel-sliced by b%8 (XCD round-robin) -> slice buffers L2-resident.
__global__ __launch_bounds__(256,4) void k_solve(float* ws,
    const float* z0,const float* z1,const float* z2,
    const float* adw,const float* adb,const float* auw,const float* aub,
    float* out){
  const int b = blockIdx.x, t = threadIdx.x;
  const int wv = t>>6, lane = t&63;
  const int* wsi=(const int*)ws;
  const int* ptr=wsi+W_PTR; const int* cidx=wsi+W_CIDX; const float* val=ws+W_VAL;

  __shared__ float smem[2616];             // 10464 B
  float* Sl  = smem;                       // [544]   phase E
  float* Wl  = smem + 544;                 // [2048]  phase E
  float* TTa = smem;                       // [64]    eig (alias, disjoint in time)
  float* TTb = smem + 64;                  // [64]
  float* redm= smem + 2592;                // [12]    phase B block partials
  float* shr = smem + 2604;                // [12]    barrier payload scratch

  // group mapping
  int g, u, NW, nb, crows, bbase, Ng, lb;
  if (b<128){ g=0; lb=b;      u=lb*4+wv; NW=512;  nb=0;    crows=1024; bbase=0;   Ng=128; }
  else if (b<704){ g=1; lb=b-128; u=lb*4+wv; NW=2304; nb=1024; crows=3072; bbase=128; Ng=576; }
  else { g=2; lb=b-704; u=lb*4+wv; NW=1280; nb=4096; crows=2048; bbase=704; Ng=320; }
  const int p1 = u;
  const bool has2 = (u + NW) < crows;
  const int p2 = u + NW;
  const bool chk = (b==bbase);
  const float* zc = (g==0)?z0:(g==1)?z1:z2;
  int ph = 0;

  // ---- Phase A: v_0 init + attention U,V ----
  { int i = b*256+t;
    if (i < 6144){
      float invs = (i<1024)?0.03125f:(i<4096)?0.0180421959f:0.0220970869f;
      unsigned uu=(unsigned)i*2654435761u; uu^=uu>>16; uu*=2246822519u; uu^=uu>>13;
      stc(ws+W_VW+i, (uu&1)?invs:-invs);     // v_0
    }
  }
  { int gw = b*4+wv;
    if (gw < 3072){
      float2 x  = ((const float2*)(z1+(size_t)gw*128))[lane];
      float2 a0 = ((const float2*)adw)[lane];
      float2 a1 = ((const float2*)adw)[64+lane];
      float2 b0 = ((const float2*)auw)[lane];
      float2 b1 = ((const float2*)auw)[64+lane];
      float ud=x.x*a0.x+x.y*a0.y, vd=x.x*a1.x+x.y*a1.y;
      float uu=x.x*b0.x+x.y*b0.y, vu=x.x*b1.x+x.y*b1.y;
      ud=wredf(ud); vd=wredf(vd); uu=wredf(uu); vu=wredf(vu);
      if(lane==0){ stc(ws+W_UV+gw,ud); stc(ws+W_UV+3072+gw,vd);
                   stc(ws+W_UV+6144+gw,uu); stc(ws+W_UV+9216+gw,vu); }
    }
  }
  barx(ws, b, 3, 0, 1024, b==0, b, ph, -1, shr); ph++;   // global: v_0, UV visible

  // ---- Phase B: M_LZ Lanczos steps (1 gather load per nnz) ----
  for (int j=0;j<M_LZ;j++){
    float a, gmm, ib;
    if (j==0){ a=0.f; gmm=0.f; ib=1.f; }
    else {
      const float* TT = ws + W_TT + (size_t)(g*64 + (j-1))*32;   // write-once padded line
      a = TT[0]; gmm = TT[1]; float n = TT[2];
      ib = 1.f/sqrtf(fmaxf(n - a*a - gmm*gmm, 1e-20f));
    }
    const float* gsrc = ws + W_VW + (size_t)(j==0 ? 0 : 64+j-1)*6144;  // v_0 or w_{j-1}
    const float* vm1v = ws + W_VW + (size_t)(j>0? j-1:0)*6144;
    const float* vm2v = ws + W_VW + (size_t)(j>1? j-2:0)*6144;
    const float* wm2v = ws + W_VW + (size_t)(64+(j>1? j-2:0))*6144;
    float* vjw        = ws + W_VW + (size_t)j*6144;
    float* wjw        = ws + W_VW + (size_t)(64+j)*6144;
    float Aa=0.f, Gg=0.f, Nn=0.f;
    auto lz_row = [&](int p){
      float gth=0.f;
      #define GATHER(PP,CBB) { \
        const int* rp = ptr + PP; int e=rp[p+1]; \
        for (int k=rp[p]+lane; k<e; k+=64) \
          gth += val[CBB+k]*gsrc[nb + cidx[CBB+k]]; \
        }
      if (g==0){ GATHER(P_L0, CB_L0) }
      else if (g==1){ GATHER(P_L1D, CB_L1D) GATHER(P_L1U, CB_L1U) }
      else { GATHER(P_L2, CB_L2) }
      #undef GATHER
      gth = wredf(gth);
      if (lane==0){
        int gp = nb + p;
        float vp, wp, vm1p;
        if (j==0){ vp = gsrc[gp]; wp = gth; vm1p = 0.f; }
        else {
          float wm1p = gsrc[gp];             // w_{j-1}[p]
          float wm2p = wm2v[gp];             // w_{j-2}[p]
          vm1p = vm1v[gp];
          vp = (wm1p - a*vm1p - gmm*vm2v[gp])*ib;
          wp = (gth  - a*wm1p - gmm*wm2p   )*ib;
          stc(vjw+gp, vp);
        }
        stc(wjw+gp, wp);
        Aa += vp*wp; Gg += vm1p*wp; Nn += wp*wp;
      }
    };
    lz_row(p1);
    if (has2) lz_row(p2);
    if (lane==0){ redm[0*4+wv]=Aa; redm[1*4+wv]=Gg; redm[2*4+wv]=Nn; }
    __syncthreads();
    if (t==0){
      float A0=redm[0]+redm[1]+redm[2]+redm[3];
      float G0=redm[4]+redm[5]+redm[6]+redm[7];
      float N0=redm[8]+redm[9]+redm[10]+redm[11];
      float* sl2 = ws + W_SLOT + ((size_t)j*1024 + b)*8;
      stc2(sl2, make_float2(A0,G0)); stc(sl2+2, N0);
    }
    barx(ws, b, g, bbase, Ng, chk, lb, ph, j, shr); ph++;
  }

  // ---- eig: one wave of each group's checker block ----
  if (chk && t<64){
    int i = t;
    { const float* TT = ws + W_TT + (size_t)(g*64 + i)*32;
      float a=TT[0], gg=TT[1], n=TT[2];
      TTa[i]=a; TTb[i]=sqrtf(fmaxf(n-a*a-gg*gg,1e-20f));
    }
    double lo, hi;
    { double r=(i? fabs((double)TTb[i-1]):0.0) + (i<M_LZ-1? fabs((double)TTb[i]):0.0);
      lo=(double)TTa[i]-r; hi=(double)TTa[i]+r; }
    #pragma unroll
    for(int o=32;o;o>>=1){ lo=fmin(lo,__shfl_xor(lo,o,64)); hi=fmax(hi,__shfl_xor(hi,o,64)); }
    lo -= 1.0; hi += 1.0;
    for (int round=0; round<4; round++){
      double x = lo + (hi-lo)*(double)(i+1)/65.0;
      double d = 1.0; int cnt2=0;
      for (int k2=0;k2<M_LZ;k2++){
        double bi = k2? (double)TTb[k2-1] : 0.0;
        d = ((double)TTa[k2]-x) - bi*bi/d;
        if (d==0.0) d = -1e-300;
        if (d<0.0) cnt2++;
      }
      double nlo = (cnt2< M_LZ)? x : -1e300;
      double nhi = (cnt2==M_LZ)? x :  1e300;
      #pragma unroll
      for(int o=32;o;o>>=1){ nlo=fmax(nlo,__shfl_xor(nlo,o,64)); nhi=fmin(nhi,__shfl_xor(nhi,o,64)); }
      if (nlo>-1e299) lo=nlo;
      if (nhi< 1e299) hi=nhi;
    }
    double lam = 0.5*(lo+hi);
    if (i==0) stc(ws+W_EPS+(size_t)g*32, (lam>0.0)? (float)(1.0/lam) : 0.1f);
  }
  barx(ws, b, g, bbase, Ng, chk, lb, ph, -1, shr); ph++;   // eps visible within group

  // ---- Phase D: 16 harmonic steps, CHANNEL-SLICED by b%8 ----
  {
    float eps = ws[W_EPS+(size_t)g*32];
    const int sl = lb & 7;                 // slice id (group bases are 0 mod 8)
    const int swv = (lb>>3)*4 + wv;        // slice-local wave id
    const int nwps = (Ng>>3)*4;            // waves per slice
    const int sub = lane>>4, cch = lane&15;
    for (int s=0;s<16;s++){
      const float* inH = ws + W_H + (size_t)(s>0? s-1:0)*HBUF + (size_t)sl*SLSTR;
      for (int p = swv; p < crows; p += nwps){
        int gp = nb + p;
        float pacc = 0.f;
        #define HG(PP,CBB) { \
          const int* rp=ptr+PP; int e=rp[p+1]; \
          for (int k=rp[p]+sub; k<e; k+=4){ \
            int q = cidx[CBB+k]; float v = val[CBB+k]; \
            float xq = (s==0)? zc[(size_t)q*128 + sl*16 + cch] \
                             : inH[(size_t)(nb+q)*16 + cch]; \
            pacc += v*xq; \
          } }
        if (g==0){ HG(P_L0, CB_L0) }
        else if (g==1){ HG(P_L1D, CB_L1D) HG(P_L1U, CB_L1U) }
        else { HG(P_L2, CB_L2) }
        #undef HG
        pacc += __shfl_xor(pacc, 16, 64);
        pacc += __shfl_xor(pacc, 32, 64);
        if (sub==0){
          float own = (s==0)? zc[(size_t)p*128 + sl*16 + cch]
                            : inH[(size_t)gp*16 + cch];
          float r = own - eps*pacc;
          if (s<15){
            stc(ws + W_H + (size_t)s*HBUF + (size_t)sl*SLSTR + (size_t)gp*16 + cch, r);
          } else {
            float* outp; size_t ostride;
            if(g==0){ outp=ws+W_SCAT+S0_OFF+256; ostride=384; }
            else if(g==1){ outp=ws+W_SCAT+S1_OFF+512; ostride=640; }
            else { outp=ws+W_SCAT+S2_OFF+256; ostride=384; }
            stc(outp + (size_t)p*ostride + sl*16 + cch, r);
          }
        }
      }
      if (s<15){ barx(ws, b, g, bbase, Ng, chk, lb, ph, -1, shr); ph++; }
    }
  }

  // ---- Phase C: forward SpMMs (all blocks) ----
  for (int wid2 = b*4+wv; wid2 < 18432; wid2 += 4096){
    int task,p;
    if(wid2<1024){task=0;p=wid2;}
    else if(wid2<2048){task=1;p=wid2-1024;}
    else if(wid2<5120){task=2;p=wid2-2048;}
    else if(wid2<8192){task=3;p=wid2-5120;}
    else if(wid2<11264){task=4;p=wid2-8192;}
    else if(wid2<13312){task=5;p=wid2-11264;}
    else if(wid2<16384){task=6;p=wid2-13312;}
    else {task=7;p=wid2-16384;}
    const float* in; const int* rp; int cb2; float* outp; int ostride;
    int mode=0; float Vp=0.f, bb=0.f; const float* U=nullptr;
    switch(task){
      case 0: rp=ptr+P_L0;  cb2=CB_L0;  in=z0; outp=ws+W_SCAT+S0_OFF+0;   ostride=384; break;
      case 1: rp=ptr+P_B1;  cb2=CB_B1;  in=z1; outp=ws+W_SCAT+S0_OFF+128; ostride=384; break;
      case 2: rp=ptr+P_L1D; cb2=CB_L1D; in=z1; outp=ws+W_SCAT+S1_OFF+0;   ostride=640;
              mode=1; U=ws+W_UV; Vp=ws[W_UV+3072+p]; bb=adb[0]; break;
      case 3: rp=ptr+P_L1U; cb2=CB_L1U; in=z1; outp=ws+W_SCAT+S1_OFF+128; ostride=640;
              mode=1; U=ws+W_UV+6144; Vp=ws[W_UV+9216+p]; bb=aub[0]; break;
      case 4: rp=ptr+P_B2;  cb2=CB_B2;  in=z2; outp=ws+W_SCAT+S1_OFF+384; ostride=640; break;
      case 5: rp=ptr+P_L2;  cb2=CB_L2;  in=z2; outp=ws+W_SCAT+S2_OFF+0;   ostride=384; break;
      case 6: rp=ptr+P_B1T; cb2=CB_B1T; in=z0; outp=ws+W_SCAT+S1_OFF+256; ostride=640; break;
      default:rp=ptr+P_B2T; cb2=CB_B2T; in=z1; outp=ws+W_SCAT+S2_OFF+128; ostride=384; break;
    }
    float2 s={0.f,0.f};
    int e=rp[p+1];
    for (int k=rp[p]; k<e; k++){
      int q = cidx[cb2+k];
      float v;
      if (mode) v = 1.0f/(1.0f+__expf(-(U[q]+Vp+bb)));
      else v = val[cb2+k];
      float2 xq = ((const float2*)(in+(size_t)q*128))[lane];
      s.x += v*xq.x; s.y += v*xq.y;
    }
    stc2(outp + (size_t)p*ostride + 2*lane, s);
  }
  barx(ws, b, 3, 0, 1024, b==0, b, ph, -1, shr); ph++;   // global join: SCAT complete

  // ---- Phase E: projection GEMMs (blocks 0..191), K-tile 16 ----
  if (b < 192){
    const float* S; const float* W; float* outp; int K; int blk;
    if (b<32){       S=ws+W_SCAT+S0_OFF; W=ws+W_WCAT+WC0; outp=out;        K=384; blk=b; }
    else if (b<128){ S=ws+W_SCAT+S1_OFF; W=ws+W_WCAT+WC1; outp=out+131072; K=640; blk=b-32; }
    else {           S=ws+W_SCAT+S2_OFF; W=ws+W_WCAT+WC2; outp=out+524288; K=384; blk=b-128; }
    int r0=blk*32;
    int ty=t>>5, tx=t&31;
    float acc[4][4]={};
    for (int k0=0; k0<K; k0+=16){
      {
        int r=t>>3, kq=(t&7)*2;
        const float* src=S+(size_t)(r0+r)*K + k0+kq;
        Sl[r*17+kq]=src[0]; Sl[r*17+kq+1]=src[1];
      }
      {
        int kk=t>>4, cq=(t&15)*8;
        const float* src=W+(size_t)(k0+kk)*128+cq;
        #pragma unroll
        for(int i=0;i<8;i++) Wl[kk*128+cq+i]=src[i];
      }
      __syncthreads();
      #pragma unroll
      for(int k=0;k<16;k++){
        float sv[4], wvv2[4];
        #pragma unroll
        for(int i=0;i<4;i++) sv[i]=Sl[(ty*4+i)*17+k];
        #pragma unroll
        for(int i=0;i<4;i++) wvv2[i]=Wl[k*128+tx+32*i];
        #pragma unroll
        for(int a2=0;a2<4;a2++)
          #pragma unroll
          for(int b2=0;b2<4;b2++) acc[a2][b2]+=sv[a2]*wvv2[b2];
      }
      __syncthreads();
    }
    #pragma unroll
    for(int a2=0;a2<4;a2++)
      #pragma unroll
      for(int b2=0;b2<4;b2++){
        int r=r0+ty*4+a2, col=tx+32*b2;
        outp[(size_t)r*128+col]=fmaxf(acc[a2][b2],0.f);
      }
  }
}

// ---------------- host ----------------
extern "C" void kernel_launch(void* const* d_in, const int* in_sizes, int n_in,
                              void* d_out, int out_size, void* d_ws, size_t ws_size,
                              hipStream_t stream){
  const float* z0 =(const float*)d_in[0];
  const float* z1 =(const float*)d_in[1];
  const float* z2 =(const float*)d_in[2];
  const float* L0 =(const float*)d_in[3];
  const float* L1d=(const float*)d_in[4];
  const float* L1u=(const float*)d_in[5];
  const float* L2 =(const float*)d_in[6];
  const float* B1 =(const float*)d_in[7];
  const float* B2 =(const float*)d_in[8];
  const float* Wd =(const float*)d_in[9];
  const float* Wu =(const float*)d_in[10];
  const float* Wh =(const float*)d_in[11];
  const float* Wb1=(const float*)d_in[12];
  const float* Wb2=(const float*)d_in[13];
  const float* adw=(const float*)d_in[14];
  const float* adb=(const float*)d_in[15];
  const float* auw=(const float*)d_in[16];
  const float* aub=(const float*)d_in[17];
  float* ws=(float*)d_ws;
  int* wsi=(int*)d_ws;
  float* out=(float*)d_out;

  hipLaunchKernelGGL(k_wprep, dim3(64), dim3(256), 0, stream, Wd,Wu,Wh,Wb1,Wb2,ws);
  hipLaunchKernelGGL(k_count, dim3(3328), dim3(256), 0, stream, L0,L1d,L1u,L2,B1,B2, wsi+W_CNT);
  hipLaunchKernelGGL(k_prefix, dim3(8), dim3(256), 0, stream, wsi+W_CNT, wsi+W_PTR, wsi+W_CUR);
  hipLaunchKernelGGL(k_fill, dim3(3328), dim3(256), 0, stream, L0,L1d,L1u,L2,B1,B2, wsi+W_PTR, wsi+W_CIDX, ws+W_VAL);
  hipLaunchKernelGGL(k_fillT, dim3(1024), dim3(256), 0, stream, ws);
  hipLaunchKernelGGL(k_solve, dim3(1024), dim3(256), 0, stream,
                     ws, z0, z1, z2, adw, adb, auw, aub, out);
}

// Round 11
// 1522.889 us; speedup vs baseline: 1.4756x; 1.4756x over previous
//
#include <hip/hip_runtime.h>
#include <string.h>

// ---------------- problem constants ----------------
constexpr int M_LZ = 64;           // Lanczos steps

// CSR capacity per matrix (expected nnz * ~1.25)
constexpr int CAP_L0 = 26240, CAP_L1 = 118016, CAP_L2 = 52480, CAP_B1 = 39360, CAP_B2 = 78720;
constexpr int CB_L0 = 0;
constexpr int CB_L1D = CB_L0 + CAP_L0;
constexpr int CB_L1U = CB_L1D + CAP_L1;
constexpr int CB_L2  = CB_L1U + CAP_L1;
constexpr int CB_B1  = CB_L2 + CAP_L2;
constexpr int CB_B2  = CB_B1 + CAP_B1;
constexpr int CAP_TOT= CB_B2 + CAP_B2;   // 432832
constexpr int CB_B1T = CAP_TOT;
constexpr int CB_B2T = CB_B1T + CAP_B1;
constexpr int CAP_TOT2 = CB_B2T + CAP_B2; // 550912

// rowptr offsets (ints) within W_PTR region
constexpr int P_L0=0, P_L1D=1025, P_L1U=4098, P_L2=7171, P_B1=9220, P_B2=10245;
constexpr int P_B1T=13320, P_B2T=16393;   // region size 18444
// row-count offsets within W_CNT region
constexpr int C_L0=0, C_L1D=1024, C_L1U=4096, C_L2=7168, C_B1=9216, C_B2=10240;
constexpr int C_B1T=13312, C_B2T=16384;   // region size 18432

constexpr size_t HBUF  = (size_t)6144*128;          // 786432 words

// workspace layout (units: 4-byte words)
constexpr size_t W_CNT = 0;                         // 18432 ints
constexpr size_t W_PTR = 18432;                     // 18444 ints
constexpr size_t W_CUR = W_PTR + 18444;             // 5120 ints
constexpr size_t W_CIDX= W_CUR + 5120;              // CAP_TOT2 ints
constexpr size_t W_VAL = W_CIDX + CAP_TOT2;         // CAP_TOT2 floats
// write-once step-indexed Lanczos vectors: v_0..v_63 then w_0..w_63 (global 6144 rows)
constexpr size_t W_VW  = W_VAL + CAP_TOT2;          // 128*6144 = 786432
// tridiagonal entries: TT[g][j] = (a, g, n), padded to one 128B line each
constexpr size_t W_TT  = W_VW + 786432;             // 3*64*32 = 6144
constexpr size_t W_EPS = W_TT + 6144;               // 4*32 (per-group padded line)
constexpr size_t W_UV  = W_EPS + 128;               // 4*3072 (U_d,V_d,U_u,V_u)
// write-once harmonic buffers: [s][row][128]
constexpr size_t W_H   = W_UV + 4*3072;             // 15*HBUF
constexpr size_t W_SCAT= W_H + 15*HBUF;
constexpr size_t S0_OFF= 0;                          // 1024 x 384
constexpr size_t S1_OFF= (size_t)1024*384;           // 3072 x 640
constexpr size_t S2_OFF= S1_OFF + (size_t)3072*640;  // 2048 x 384
constexpr size_t SCAT_TOT = S2_OFF + (size_t)2048*384;
constexpr size_t W_WCAT= W_SCAT + SCAT_TOT;          // 1408*128 concatenated weights
constexpr size_t WC0=0, WC1=(size_t)384*128, WC2=WC1+(size_t)640*128;
// per-block dot partial slots, step-indexed (write-once): [j][b] -> 8 floats (32B)
constexpr size_t W_SLOT= W_WCAT + (size_t)1408*128;  // 64*1024*8 = 524288
// per-block arrival flags (monotonic phase counters), padded 128B each
constexpr size_t W_FLG = W_SLOT + 524288;            // 1024*32
// release copies: 4 groups x 16 leaves, padded 128B each
constexpr size_t W_REL = W_FLG + 32768;              // 2048

__device__ __forceinline__ float wredf(float v){
  #pragma unroll
  for(int o=32;o;o>>=1) v += __shfl_xor(v,o,64);
  return v;
}
__device__ __forceinline__ float wredh(float v){   // reduce within 32-lane half
  #pragma unroll
  for(int o=16;o;o>>=1) v += __shfl_xor(v,o,64);
  return v;
}
__device__ __forceinline__ int wredi(int v){
  #pragma unroll
  for(int o=32;o;o>>=1) v += __shfl_xor(v,o,64);
  return v;
}

// agent-scope (L2-bypassing) ops
__device__ __forceinline__ float ldc(const float* p){
  return __hip_atomic_load(p, __ATOMIC_RELAXED, __HIP_MEMORY_SCOPE_AGENT);
}
__device__ __forceinline__ float2 ldc2(const float* p){
  unsigned long long u = __hip_atomic_load((const unsigned long long*)p,
                          __ATOMIC_RELAXED, __HIP_MEMORY_SCOPE_AGENT);
  float2 r; memcpy(&r,&u,8); return r;
}
__device__ __forceinline__ void stc(float* p, float v){
  __hip_atomic_store(p, v, __ATOMIC_RELAXED, __HIP_MEMORY_SCOPE_AGENT);
}
__device__ __forceinline__ void stc2(float* p, float2 v){
  unsigned long long u; memcpy(&u,&v,8);
  __hip_atomic_store((unsigned long long*)p, u, __ATOMIC_RELAXED, __HIP_MEMORY_SCOPE_AGENT);
}
__device__ __forceinline__ int ldci(const int* p){
  return __hip_atomic_load(p, __ATOMIC_RELAXED, __HIP_MEMORY_SCOPE_AGENT);
}
__device__ __forceinline__ void stci(int* p, int v){
  __hip_atomic_store(p, v, __ATOMIC_RELAXED, __HIP_MEMORY_SCOPE_AGENT);
}

// ---- flag-array barrier: NO same-address RMW anywhere ----
__device__ __forceinline__ void barx(float* ws, int b, int grp, int lbase, int Ng,
                                     bool chk, int lb, int ph, int jslot, float* shr){
  const int t = threadIdx.x, lane = t&63, wvv = t>>6;
  int* flg = (int*)ws + W_FLG;
  int* rel = (int*)ws + W_REL;
  __builtin_amdgcn_s_waitcnt(0);   // every thread drains its stores
  __syncthreads();
  if (t==0) stci(flg + (size_t)b*32, ph+1);
  if (chk){
    for (int s=t; s<Ng; s+=256){
      const int* f = flg + (size_t)(lbase+s)*32;
      while (ldci(f) < ph+1) __builtin_amdgcn_s_sleep(2);
    }
    if (jslot>=0){
      float pa=0.f, pg=0.f, pn=0.f;
      for (int s=t; s<Ng; s+=256){
        const float* sl = ws + W_SLOT + ((size_t)jslot*1024 + lbase+s)*8;
        float2 ag = ldc2(sl); float nn = ldc(sl+2);
        pa+=ag.x; pg+=ag.y; pn+=nn;
      }
      pa=wredf(pa); pg=wredf(pg); pn=wredf(pn);
      if (lane==0){ shr[0*4+wvv]=pa; shr[1*4+wvv]=pg; shr[2*4+wvv]=pn; }
    }
    __syncthreads();
    if (t==0){
      if (jslot>=0){
        float a=shr[0]+shr[1]+shr[2]+shr[3];
        float g=shr[4]+shr[5]+shr[6]+shr[7];
        float n=shr[8]+shr[9]+shr[10]+shr[11];
        float* TT = ws + W_TT + (size_t)(grp*64 + jslot)*32;
        stc2(TT, make_float2(a,g)); stc(TT+2, n);
        __builtin_amdgcn_s_waitcnt(0);   // TT visible before release
      }
      #pragma unroll
      for (int i=0;i<16;i++) stci(rel + (size_t)(grp*16+i)*32, ph+1);
    }
    __syncthreads();
  } else {
    if (t==0){
      const int* r = rel + (size_t)(grp*16 + (lb&15))*32;
      while (ldci(r) < ph+1) __builtin_amdgcn_s_sleep(2);
    }
    __syncthreads();
  }
}

// ---------------- weight prep + zeroing of counters/flags ----------------
__global__ void k_wprep(const float* Wd,const float* Wu,const float* Wh,
                        const float* Wb1,const float* Wb2, float* ws){
  int t = blockIdx.x*256 + threadIdx.x;
  if (t >= 16384) return;
  int* wsi = (int*)ws;
  if (t < 5120) wsi[W_CNT + 13312 + t] = 0;          // transpose col counters
  if (t < 5120) wsi[W_CUR + t] = 0;                  // cursors
  for (int i=t; i<32768+2048; i+=16384) wsi[W_FLG+i] = 0;  // flags + releases
  float sd = Wd[t]  + Wd[16384+t]  + Wd[32768+t];
  float su = Wu[t]  + Wu[16384+t]  + Wu[32768+t];
  float s1 = Wb1[t] + Wb1[16384+t] + Wb1[32768+t];
  float s2 = Wb2[t] + Wb2[16384+t] + Wb2[32768+t];
  float wh = Wh[t];
  float* W0 = ws + W_WCAT + WC0;
  float* W1 = ws + W_WCAT + WC1;
  float* W2 = ws + W_WCAT + WC2;
  W0[t]=sd; W0[16384+t]=s1; W0[32768+t]=wh;
  W1[t]=sd; W1[16384+t]=su; W1[32768+t]=s1; W1[49152+t]=s2; W1[65536+t]=wh;
  W2[t]=su; W2[16384+t]=s2; W2[32768+t]=wh;
}

// ---------------- CSR extraction (proven) ----------------
__device__ __forceinline__ void mat_meta(int wid, const float* L0,const float* L1d,const float* L1u,
    const float* L2,const float* B1,const float* B2,
    const float*& M,int& ncol,int& lrow,int& co,int& po,int& cb,int& cap,int& tco){
  if (wid < 1024){ M=L0;  ncol=1024; lrow=wid;        co=C_L0;  po=P_L0;  cb=CB_L0;  cap=CAP_L0; tco=-1; }
  else if (wid < 4096){ M=L1d; ncol=3072; lrow=wid-1024;  co=C_L1D; po=P_L1D; cb=CB_L1D; cap=CAP_L1; tco=-1; }
  else if (wid < 7168){ M=L1u; ncol=3072; lrow=wid-4096;  co=C_L1U; po=P_L1U; cb=CB_L1U; cap=CAP_L1; tco=-1; }
  else if (wid < 9216){ M=L2;  ncol=2048; lrow=wid-7168;  co=C_L2;  po=P_L2;  cb=CB_L2;  cap=CAP_L2; tco=-1; }
  else if (wid < 10240){ M=B1; ncol=3072; lrow=wid-9216;  co=C_B1;  po=P_B1;  cb=CB_B1;  cap=CAP_B1; tco=C_B1T; }
  else { M=B2; ncol=2048; lrow=wid-10240; co=C_B2;  po=P_B2;  cb=CB_B2;  cap=CAP_B2; tco=C_B2T; }
}

__global__ void k_count(const float* L0,const float* L1d,const float* L1u,const float* L2,
                        const float* B1,const float* B2,int* cnt){
  int wid = blockIdx.x*4 + (threadIdx.x>>6);
  int lane = threadIdx.x & 63;
  if (wid >= 13312) return;
  const float* M; int ncol,lrow,co,po,cb,cap,tco;
  mat_meta(wid,L0,L1d,L1u,L2,B1,B2,M,ncol,lrow,co,po,cb,cap,tco);
  const float4* row4 = (const float4*)(M + (size_t)lrow*ncol);
  int c = 0;
  for (int j0=0; j0<ncol; j0+=256){
    float4 v = row4[(j0>>2)+lane];
    int n0=v.x!=0.f, n1=v.y!=0.f, n2=v.z!=0.f, n3=v.w!=0.f;
    c += n0+n1+n2+n3;
    if (tco>=0){
      int jb = j0 + lane*4;
      if (n0) atomicAdd(cnt+tco+jb,   1);
      if (n1) atomicAdd(cnt+tco+jb+1, 1);
      if (n2) atomicAdd(cnt+tco+jb+2, 1);
      if (n3) atomicAdd(cnt+tco+jb+3, 1);
    }
  }
  c = wredi(c);
  if (lane==0) cnt[co+lrow] = c;
}

__global__ void k_prefix(const int* cnt, int* ptr, int* cur){
  __shared__ int lds[257];
  const int rows[8]={1024,3072,3072,2048,1024,3072,3072,2048};
  const int cofs[8]={C_L0,C_L1D,C_L1U,C_L2,C_B1,C_B2,C_B1T,C_B2T};
  const int pofs[8]={P_L0,P_L1D,P_L1U,P_L2,P_B1,P_B2,P_B1T,P_B2T};
  int b=blockIdx.x, t=threadIdx.x;
  int R=rows[b]; const int* c=cnt+cofs[b]; int* p=ptr+pofs[b];
  int* cc = (b==6)? cur : (b==7)? cur+3072 : nullptr;
  int chunk=(R+255)/256;
  int lo=t*chunk, hi=min(R,lo+chunk);
  int s=0;
  for(int i=lo;i<hi;i++) s+=c[i];
  lds[t]=s; __syncthreads();
  if(t==0){ int run=0; for(int i=0;i<256;i++){int x=lds[i];lds[i]=run;run+=x;} lds[256]=run; }
  __syncthreads();
  int run=lds[t];
  for(int i=lo;i<hi;i++){ p[i]=run; if(cc) cc[i]=run; run+=c[i]; }
  if(t==0) p[R]=lds[256];
}

__global__ void k_fill(const float* L0,const float* L1d,const float* L1u,const float* L2,
                       const float* B1,const float* B2,const int* ptr,int* cidx,float* val){
  int wid = blockIdx.x*4 + (threadIdx.x>>6);
  int lane = threadIdx.x & 63;
  if (wid >= 13312) return;
  const float* M; int ncol,lrow,co,po,cb,cap,tco;
  mat_meta(wid,L0,L1d,L1u,L2,B1,B2,M,ncol,lrow,co,po,cb,cap,tco);
  const float4* row4 = (const float4*)(M + (size_t)lrow*ncol);
  int base = ptr[po+lrow];
  int run = 0;
  for (int j0=0; j0<ncol; j0+=256){
    float4 v = row4[(j0>>2)+lane];
    int n0=v.x!=0.f, n1=v.y!=0.f, n2=v.z!=0.f, n3=v.w!=0.f;
    int local = n0+n1+n2+n3;
    int incl = local;
    #pragma unroll
    for (int o=1;o<64;o<<=1){
      int tmp = __shfl_up(incl,o,64);
      if (lane>=o) incl += tmp;
    }
    int tot = __shfl(incl,63,64);
    int pos = base + run + incl - local;
    int jb = j0 + lane*4;
    if (n0){ if(pos<cap){cidx[cb+pos]=jb;   val[cb+pos]=v.x;} pos++; }
    if (n1){ if(pos<cap){cidx[cb+pos]=jb+1; val[cb+pos]=v.y;} pos++; }
    if (n2){ if(pos<cap){cidx[cb+pos]=jb+2; val[cb+pos]=v.z;} pos++; }
    if (n3){ if(pos<cap){cidx[cb+pos]=jb+3; val[cb+pos]=v.w;} pos++; }
    run += tot;
  }
}

__global__ void k_fillT(float* ws){
  int wid = blockIdx.x*4 + (threadIdx.x>>6);
  int lane = threadIdx.x & 63;
  if (wid >= 4096) return;
  int* wsi=(int*)ws;
  const int* ptr=wsi+W_PTR; int* cidx=wsi+W_CIDX; float* val=ws+W_VAL;
  int* cur=wsi+W_CUR;
  if (wid < 1024){
    int r=wid;
    int e=ptr[P_B1+r+1];
    for(int k=ptr[P_B1+r]+lane;k<e;k+=64){
      int c=cidx[CB_B1+k]; float v=val[CB_B1+k];
      int pos=atomicAdd(cur+c,1);
      cidx[CB_B1T+pos]=r; val[CB_B1T+pos]=v;
    }
  } else {
    int r=wid-1024;
    int e=ptr[P_B2+r+1];
    for(int k=ptr[P_B2+r]+lane;k<e;k+=64){
      int c=cidx[CB_B2+k]; float v=val[CB_B2+k];
      int pos=atomicAdd(cur+3072+c,1);
      cidx[CB_B2T+pos]=r; val[CB_B2T+pos]=v;
    }
  }
}

// ================= FUSED PERSISTENT SOLVER =================
// 1024 blocks x 256 threads = 4 blocks/CU, all co-resident.
// Groups rebalanced by nnz: g0=c0 [0,80), g1=c1 [80,848), g2=c2 [848,1024).
// g1 (critical chain): 3072 waves for 3072 rows -> perfectly balanced.
// Rows processed at HALF-WAVE (32-lane) granularity; harm uses float4 loads.
__global__ __launch_bounds__(256,4) void k_solve(float* ws,
    const float* z0,const float* z1,const float* z2,
    const float* adw,const float* adb,const float* auw,const float* aub,
    float* out){
  const int b = blockIdx.x, t = threadIdx.x;
  const int wv = t>>6, lane = t&63;
  const int hl = lane & 31;                // lane within half-wave
  const int* wsi=(const int*)ws;
  const int* ptr=wsi+W_PTR; const int* cidx=wsi+W_CIDX; const float* val=ws+W_VAL;

  __shared__ float smem[2616];             // 10464 B
  float* Sl  = smem;                       // [544]   phase E
  float* Wl  = smem + 544;                 // [2048]  phase E
  float* TTa = smem;                       // [64]    eig (alias, disjoint in time)
  float* TTb = smem + 64;                  // [64]
  float* redm= smem + 2592;                // [12]    phase B block partials
  float* shr = smem + 2604;                // [12]    barrier payload scratch

  // group mapping (block counts proportional to nnz; all divisible by 16)
  int g, nb, crows, bbase, Ng, lb;
  if (b<80){ g=0; lb=b;      nb=0;    crows=1024; bbase=0;   Ng=80;  }
  else if (b<848){ g=1; lb=b-80; nb=1024; crows=3072; bbase=80;  Ng=768; }
  else { g=2; lb=b-848; nb=4096; crows=2048; bbase=848; Ng=176; }
  const int h  = (lb*4+wv)*2 + (lane>>5);  // half-wave id within group
  const int NH = Ng*8;                     // halves per group
  const bool chk = (b==bbase);
  const float* zc = (g==0)?z0:(g==1)?z1:z2;
  int ph = 0;

  // ---- Phase A: v_0 init + attention U,V ----
  { int i = b*256+t;
    if (i < 6144){
      float invs = (i<1024)?0.03125f:(i<4096)?0.0180421959f:0.0220970869f;
      unsigned uu=(unsigned)i*2654435761u; uu^=uu>>16; uu*=2246822519u; uu^=uu>>13;
      stc(ws+W_VW+i, (uu&1)?invs:-invs);     // v_0
    }
  }
  { int gw = b*4+wv;
    if (gw < 3072){
      float2 x  = ((const float2*)(z1+(size_t)gw*128))[lane];
      float2 a0 = ((const float2*)adw)[lane];
      float2 a1 = ((const float2*)adw)[64+lane];
      float2 b0 = ((const float2*)auw)[lane];
      float2 b1 = ((const float2*)auw)[64+lane];
      float ud=x.x*a0.x+x.y*a0.y, vd=x.x*a1.x+x.y*a1.y;
      float uu=x.x*b0.x+x.y*b0.y, vu=x.x*b1.x+x.y*b1.y;
      ud=wredf(ud); vd=wredf(vd); uu=wredf(uu); vu=wredf(vu);
      if(lane==0){ stc(ws+W_UV+gw,ud); stc(ws+W_UV+3072+gw,vd);
                   stc(ws+W_UV+6144+gw,uu); stc(ws+W_UV+9216+gw,vu); }
    }
  }
  barx(ws, b, 3, 0, 1024, b==0, b, ph, -1, shr); ph++;   // global: v_0, UV visible

  // ---- Phase B: M_LZ Lanczos steps (half-wave per row; 3-load reconstruction) ----
  for (int j=0;j<M_LZ;j++){
    float a, gmm, ib;
    if (j==0){ a=0.f; gmm=0.f; ib=1.f; }
    else {
      const float* TT = ws + W_TT + (size_t)(g*64 + (j-1))*32;   // write-once padded line
      a = TT[0]; gmm = TT[1]; float n = TT[2];
      ib = 1.f/sqrtf(fmaxf(n - a*a - gmm*gmm, 1e-20f));
    }
    const float* vj   = ws + W_VW + (size_t)j*6144;
    const float* vm1  = ws + W_VW + (size_t)(j>0? j-1:0)*6144;
    const float* vm2  = ws + W_VW + (size_t)(j>1? j-2:0)*6144;
    const float* wpv  = ws + W_VW + (size_t)(64 + (j>0? j-1:0))*6144;
    float* vjw        = ws + W_VW + (size_t)j*6144;
    float* wjw        = ws + W_VW + (size_t)(64+j)*6144;
    float Aa=0.f, Gg=0.f, Nn=0.f;
    for (int p = h; p < crows; p += NH){
      float wp=0.f;
      #define GATHER(PP,CBB) { \
        const int* rp = ptr + PP; int e=rp[p+1]; \
        for (int k=rp[p]+hl; k<e; k+=32){ \
          int q = nb + cidx[CBB+k]; float v = val[CBB+k]; \
          float vq = (j==0)? vj[q] : (wpv[q] - a*vm1[q] - gmm*vm2[q])*ib; \
          wp += v*vq; \
        } }
      if (g==0){ GATHER(P_L0, CB_L0) }
      else if (g==1){ GATHER(P_L1D, CB_L1D) GATHER(P_L1U, CB_L1U) }
      else { GATHER(P_L2, CB_L2) }
      #undef GATHER
      wp = wredh(wp);
      if (hl==0){
        int gp = nb + p;
        float vp, vm1p;
        if (j==0){ vp = vj[gp]; vm1p = 0.f; }
        else { vp = (wpv[gp] - a*vm1[gp] - gmm*vm2[gp])*ib; stc(vjw+gp, vp); vm1p = vm1[gp]; }
        stc(wjw+gp, wp);
        Aa += vp*wp; Gg += vm1p*wp; Nn += wp*wp;
      }
    }
    Aa = wredf(Aa); Gg = wredf(Gg); Nn = wredf(Nn);   // halves fold (hl!=0 are 0)
    if (lane==0){ redm[0*4+wv]=Aa; redm[1*4+wv]=Gg; redm[2*4+wv]=Nn; }
    __syncthreads();
    if (t==0){
      float A0=redm[0]+redm[1]+redm[2]+redm[3];
      float G0=redm[4]+redm[5]+redm[6]+redm[7];
      float N0=redm[8]+redm[9]+redm[10]+redm[11];
      float* sl2 = ws + W_SLOT + ((size_t)j*1024 + b)*8;
      stc2(sl2, make_float2(A0,G0)); stc(sl2+2, N0);
    }
    barx(ws, b, g, bbase, Ng, chk, lb, ph, j, shr); ph++;
  }

  // ---- eig: one wave of each group's checker block ----
  if (chk && t<64){
    int i = t;
    { const float* TT = ws + W_TT + (size_t)(g*64 + i)*32;
      float a=TT[0], gg=TT[1], n=TT[2];
      TTa[i]=a; TTb[i]=sqrtf(fmaxf(n-a*a-gg*gg,1e-20f));
    }
    double lo, hi;
    { double r=(i? fabs((double)TTb[i-1]):0.0) + (i<M_LZ-1? fabs((double)TTb[i]):0.0);
      lo=(double)TTa[i]-r; hi=(double)TTa[i]+r; }
    #pragma unroll
    for(int o=32;o;o>>=1){ lo=fmin(lo,__shfl_xor(lo,o,64)); hi=fmax(hi,__shfl_xor(hi,o,64)); }
    lo -= 1.0; hi += 1.0;
    for (int round=0; round<4; round++){
      double x = lo + (hi-lo)*(double)(i+1)/65.0;
      double d = 1.0; int cnt2=0;
      for (int k2=0;k2<M_LZ;k2++){
        double bi = k2? (double)TTb[k2-1] : 0.0;
        d = ((double)TTa[k2]-x) - bi*bi/d;
        if (d==0.0) d = -1e-300;
        if (d<0.0) cnt2++;
      }
      double nlo = (cnt2< M_LZ)? x : -1e300;
      double nhi = (cnt2==M_LZ)? x :  1e300;
      #pragma unroll
      for(int o=32;o;o>>=1){ nlo=fmax(nlo,__shfl_xor(nlo,o,64)); nhi=fmin(nhi,__shfl_xor(nhi,o,64)); }
      if (nlo>-1e299) lo=nlo;
      if (nhi< 1e299) hi=nhi;
    }
    double lam = 0.5*(lo+hi);
    if (i==0) stc(ws+W_EPS+(size_t)g*32, (lam>0.0)? (float)(1.0/lam) : 0.1f);
  }
  barx(ws, b, g, bbase, Ng, chk, lb, ph, -1, shr); ph++;   // eps visible within group

  // ---- Phase D: 16 harmonic steps (half-wave per row, float4 loads) ----
  {
    float eps = ws[W_EPS+(size_t)g*32];
    for (int s=0;s<16;s++){
      const float* inH = ws + W_H + (size_t)(s>0? s-1:0)*HBUF;
      for (int p = h; p < crows; p += NH){
        int gp = nb + p;
        float4 own, acc={0.f,0.f,0.f,0.f};
        if (s==0) own = ((const float4*)(zc + (size_t)p*128))[hl];
        else      own = ((const float4*)(inH + (size_t)gp*128))[hl];
        #define HG(PP,CBB) { \
          const int* rp=ptr+PP; int e=rp[p+1]; \
          for(int k=rp[p];k<e;k++){ \
            float v=val[CBB+k]; int q=cidx[CBB+k]; \
            float4 xq; \
            if (s==0) xq = ((const float4*)(zc+(size_t)q*128))[hl]; \
            else      xq = ((const float4*)(inH+(size_t)(nb+q)*128))[hl]; \
            acc.x+=v*xq.x; acc.y+=v*xq.y; acc.z+=v*xq.z; acc.w+=v*xq.w; \
          } }
        if (g==0){ HG(P_L0, CB_L0) }
        else if (g==1){ HG(P_L1D, CB_L1D) HG(P_L1U, CB_L1U) }
        else { HG(P_L2, CB_L2) }
        #undef HG
        float4 r;
        r.x = own.x - eps*acc.x; r.y = own.y - eps*acc.y;
        r.z = own.z - eps*acc.z; r.w = own.w - eps*acc.w;
        float* dst;
        if (s<15) dst = ws + W_H + (size_t)s*HBUF + (size_t)gp*128;
        else {
          float* outp; size_t ostride;
          if(g==0){ outp=ws+W_SCAT+S0_OFF+256; ostride=384; }
          else if(g==1){ outp=ws+W_SCAT+S1_OFF+512; ostride=640; }
          else { outp=ws+W_SCAT+S2_OFF+256; ostride=384; }
          dst = outp + (size_t)p*ostride;
        }
        stc2(dst + hl*4,     make_float2(r.x,r.y));
        stc2(dst + hl*4 + 2, make_float2(r.z,r.w));
      }
      if (s<15){ barx(ws, b, g, bbase, Ng, chk, lb, ph, -1, shr); ph++; }
    }
  }

  // ---- Phase C: forward SpMMs (all blocks) ----
  for (int wid2 = b*4+wv; wid2 < 18432; wid2 += 4096){
    int task,p;
    if(wid2<1024){task=0;p=wid2;}
    else if(wid2<2048){task=1;p=wid2-1024;}
    else if(wid2<5120){task=2;p=wid2-2048;}
    else if(wid2<8192){task=3;p=wid2-5120;}
    else if(wid2<11264){task=4;p=wid2-8192;}
    else if(wid2<13312){task=5;p=wid2-11264;}
    else if(wid2<16384){task=6;p=wid2-13312;}
    else {task=7;p=wid2-16384;}
    const float* in; const int* rp; int cb2; float* outp; int ostride;
    int mode=0; float Vp=0.f, bb=0.f; const float* U=nullptr;
    switch(task){
      case 0: rp=ptr+P_L0;  cb2=CB_L0;  in=z0; outp=ws+W_SCAT+S0_OFF+0;   ostride=384; break;
      case 1: rp=ptr+P_B1;  cb2=CB_B1;  in=z1; outp=ws+W_SCAT+S0_OFF+128; ostride=384; break;
      case 2: rp=ptr+P_L1D; cb2=CB_L1D; in=z1; outp=ws+W_SCAT+S1_OFF+0;   ostride=640;
              mode=1; U=ws+W_UV; Vp=ws[W_UV+3072+p]; bb=adb[0]; break;
      case 3: rp=ptr+P_L1U; cb2=CB_L1U; in=z1; outp=ws+W_SCAT+S1_OFF+128; ostride=640;
              mode=1; U=ws+W_UV+6144; Vp=ws[W_UV+9216+p]; bb=aub[0]; break;
      case 4: rp=ptr+P_B2;  cb2=CB_B2;  in=z2; outp=ws+W_SCAT+S1_OFF+384; ostride=640; break;
      case 5: rp=ptr+P_L2;  cb2=CB_L2;  in=z2; outp=ws+W_SCAT+S2_OFF+0;   ostride=384; break;
      case 6: rp=ptr+P_B1T; cb2=CB_B1T; in=z0; outp=ws+W_SCAT+S1_OFF+256; ostride=640; break;
      default:rp=ptr+P_B2T; cb2=CB_B2T; in=z1; outp=ws+W_SCAT+S2_OFF+128; ostride=384; break;
    }
    float2 s={0.f,0.f};
    int e=rp[p+1];
    for (int k=rp[p]; k<e; k++){
      int q = cidx[cb2+k];
      float v;
      if (mode) v = 1.0f/(1.0f+__expf(-(U[q]+Vp+bb)));
      else v = val[cb2+k];
      float2 xq = ((const float2*)(in+(size_t)q*128))[lane];
      s.x += v*xq.x; s.y += v*xq.y;
    }
    stc2(outp + (size_t)p*ostride + 2*lane, s);
  }
  barx(ws, b, 3, 0, 1024, b==0, b, ph, -1, shr); ph++;   // global join: SCAT complete

  // ---- Phase E: projection GEMMs (blocks 0..191), K-tile 16 ----
  if (b < 192){
    const float* S; const float* W; float* outp; int K; int blk;
    if (b<32){       S=ws+W_SCAT+S0_OFF; W=ws+W_WCAT+WC0; outp=out;        K=384; blk=b; }
    else if (b<128){ S=ws+W_SCAT+S1_OFF; W=ws+W_WCAT+WC1; outp=out+131072; K=640; blk=b-32; }
    else {           S=ws+W_SCAT+S2_OFF; W=ws+W_WCAT+WC2; outp=out+524288; K=384; blk=b-128; }
    int r0=blk*32;
    int ty=t>>5, tx=t&31;
    float acc[4][4]={};
    for (int k0=0; k0<K; k0+=16){
      {
        int r=t>>3, kq=(t&7)*2;
        const float* src=S+(size_t)(r0+r)*K + k0+kq;
        Sl[r*17+kq]=src[0]; Sl[r*17+kq+1]=src[1];
      }
      {
        int kk=t>>4, cq=(t&15)*8;
        const float* src=W+(size_t)(k0+kk)*128+cq;
        #pragma unroll
        for(int i=0;i<8;i++) Wl[kk*128+cq+i]=src[i];
      }
      __syncthreads();
      #pragma unroll
      for(int k=0;k<16;k++){
        float sv[4], wvv2[4];
        #pragma unroll
        for(int i=0;i<4;i++) sv[i]=Sl[(ty*4+i)*17+k];
        #pragma unroll
        for(int i=0;i<4;i++) wvv2[i]=Wl[k*128+tx+32*i];
        #pragma unroll
        for(int a2=0;a2<4;a2++)
          #pragma unroll
          for(int b2=0;b2<4;b2++) acc[a2][b2]+=sv[a2]*wvv2[b2];
      }
      __syncthreads();
    }
    #pragma unroll
    for(int a2=0;a2<4;a2++)
      #pragma unroll
      for(int b2=0;b2<4;b2++){
        int r=r0+ty*4+a2, col=tx+32*b2;
        outp[(size_t)r*128+col]=fmaxf(acc[a2][b2],0.f);
      }
  }
}

// ---------------- host ----------------
extern "C" void kernel_launch(void* const* d_in, const int* in_sizes, int n_in,
                              void* d_out, int out_size, void* d_ws, size_t ws_size,
                              hipStream_t stream){
  const float* z0 =(const float*)d_in[0];
  const float* z1 =(const float*)d_in[1];
  const float* z2 =(const float*)d_in[2];
  const float* L0 =(const float*)d_in[3];
  const float* L1d=(const float*)d_in[4];
  const float* L1u=(const float*)d_in[5];
  const float* L2 =(const float*)d_in[6];
  const float* B1 =(const float*)d_in[7];
  const float* B2 =(const float*)d_in[8];
  const float* Wd =(const float*)d_in[9];
  const float* Wu =(const float*)d_in[10];
  const float* Wh =(const float*)d_in[11];
  const float* Wb1=(const float*)d_in[12];
  const float* Wb2=(const float*)d_in[13];
  const float* adw=(const float*)d_in[14];
  const float* adb=(const float*)d_in[15];
  const float* auw=(const float*)d_in[16];
  const float* aub=(const float*)d_in[17];
  float* ws=(float*)d_ws;
  int* wsi=(int*)d_ws;
  float* out=(float*)d_out;

  hipLaunchKernelGGL(k_wprep, dim3(64), dim3(256), 0, stream, Wd,Wu,Wh,Wb1,Wb2,ws);
  hipLaunchKernelGGL(k_count, dim3(3328), dim3(256), 0, stream, L0,L1d,L1u,L2,B1,B2, wsi+W_CNT);
  hipLaunchKernelGGL(k_prefix, dim3(8), dim3(256), 0, stream, wsi+W_CNT, wsi+W_PTR, wsi+W_CUR);
  hipLaunchKernelGGL(k_fill, dim3(3328), dim3(256), 0, stream, L0,L1d,L1u,L2,B1,B2, wsi+W_PTR, wsi+W_CIDX, ws+W_VAL);
  hipLaunchKernelGGL(k_fillT, dim3(1024), dim3(256), 0, stream, ws);
  hipLaunchKernelGGL(k_solve, dim3(1024), dim3(256), 0, stream,
                     ws, z0, z1, z2, adw, adb, auw, aub, out);
}

// Round 12
// 1513.346 us; speedup vs baseline: 1.4849x; 1.0063x over previous
//
#include <hip/hip_runtime.h>
#include <string.h>

// ---------------- problem constants ----------------
constexpr int M_LZ = 48;   // Lanczos steps (m=64/96 both at bf16 floor; 48 keeps ~2.7x margin)

// CSR capacity per matrix (expected nnz * ~1.25)
constexpr int CAP_L0 = 26240, CAP_L1 = 118016, CAP_L2 = 52480, CAP_B1 = 39360, CAP_B2 = 78720;
constexpr int CB_L0 = 0;
constexpr int CB_L1D = CB_L0 + CAP_L0;
constexpr int CB_L1U = CB_L1D + CAP_L1;
constexpr int CB_L2  = CB_L1U + CAP_L1;
constexpr int CB_B1  = CB_L2 + CAP_L2;
constexpr int CB_B2  = CB_B1 + CAP_B1;
constexpr int CAP_TOT= CB_B2 + CAP_B2;   // 432832
constexpr int CB_B1T = CAP_TOT;
constexpr int CB_B2T = CB_B1T + CAP_B1;
constexpr int CAP_TOT2 = CB_B2T + CAP_B2; // 550912

// rowptr offsets (ints) within W_PTR region
constexpr int P_L0=0, P_L1D=1025, P_L1U=4098, P_L2=7171, P_B1=9220, P_B2=10245;
constexpr int P_B1T=13320, P_B2T=16393;   // region size 18444
// row-count offsets within W_CNT region
constexpr int C_L0=0, C_L1D=1024, C_L1U=4096, C_L2=7168, C_B1=9216, C_B2=10240;
constexpr int C_B1T=13312, C_B2T=16384;   // region size 18432

constexpr size_t HBUF  = (size_t)6144*128;          // 786432 words

// workspace layout (units: 4-byte words)
constexpr size_t W_CNT = 0;                         // 18432 ints
constexpr size_t W_PTR = 18432;                     // 18444 ints
constexpr size_t W_CUR = W_PTR + 18444;             // 5120 ints
constexpr size_t W_CIDX= W_CUR + 5120;              // CAP_TOT2 ints
constexpr size_t W_VAL = W_CIDX + CAP_TOT2;         // CAP_TOT2 floats
// write-once step-indexed Lanczos vectors: v_0..v_63 then w_0..w_63 (global 6144 rows)
constexpr size_t W_VW  = W_VAL + CAP_TOT2;          // 128*6144 = 786432
// tridiagonal entries: TT[g][j] = (a, g, n), padded to one 128B line each
constexpr size_t W_TT  = W_VW + 786432;             // 3*64*32 = 6144
constexpr size_t W_EPS = W_TT + 6144;               // 4*32 (per-group padded line)
constexpr size_t W_UV  = W_EPS + 128;               // 4*3072 (U_d,V_d,U_u,V_u)
// write-once harmonic buffers: [s][row][128]
constexpr size_t W_H   = W_UV + 4*3072;             // 15*HBUF
constexpr size_t W_SCAT= W_H + 15*HBUF;
constexpr size_t S0_OFF= 0;                          // 1024 x 384
constexpr size_t S1_OFF= (size_t)1024*384;           // 3072 x 640
constexpr size_t S2_OFF= S1_OFF + (size_t)3072*640;  // 2048 x 384
constexpr size_t SCAT_TOT = S2_OFF + (size_t)2048*384;
constexpr size_t W_WCAT= W_SCAT + SCAT_TOT;          // 1408*128 concatenated weights
constexpr size_t WC0=0, WC1=(size_t)384*128, WC2=WC1+(size_t)640*128;
// per-block dot partial slots, step-indexed (write-once): [j][b] -> 8 floats (32B)
constexpr size_t W_SLOT= W_WCAT + (size_t)1408*128;  // 64*1024*8 = 524288
// per-block arrival flags (monotonic phase counters), padded 128B each
constexpr size_t W_FLG = W_SLOT + 524288;            // 1024*32
// release copies: 4 groups x 16 leaves, padded 128B each
constexpr size_t W_REL = W_FLG + 32768;              // 2048

__device__ __forceinline__ float wredf(float v){
  #pragma unroll
  for(int o=32;o;o>>=1) v += __shfl_xor(v,o,64);
  return v;
}
__device__ __forceinline__ int wredi(int v){
  #pragma unroll
  for(int o=32;o;o>>=1) v += __shfl_xor(v,o,64);
  return v;
}

// agent-scope (L2-bypassing) ops
__device__ __forceinline__ float ldc(const float* p){
  return __hip_atomic_load(p, __ATOMIC_RELAXED, __HIP_MEMORY_SCOPE_AGENT);
}
__device__ __forceinline__ float2 ldc2(const float* p){
  unsigned long long u = __hip_atomic_load((const unsigned long long*)p,
                          __ATOMIC_RELAXED, __HIP_MEMORY_SCOPE_AGENT);
  float2 r; memcpy(&r,&u,8); return r;
}
__device__ __forceinline__ void stc(float* p, float v){
  __hip_atomic_store(p, v, __ATOMIC_RELAXED, __HIP_MEMORY_SCOPE_AGENT);
}
__device__ __forceinline__ void stc2(float* p, float2 v){
  unsigned long long u; memcpy(&u,&v,8);
  __hip_atomic_store((unsigned long long*)p, u, __ATOMIC_RELAXED, __HIP_MEMORY_SCOPE_AGENT);
}
__device__ __forceinline__ int ldci(const int* p){
  return __hip_atomic_load(p, __ATOMIC_RELAXED, __HIP_MEMORY_SCOPE_AGENT);
}
__device__ __forceinline__ void stci(int* p, int v){
  __hip_atomic_store(p, v, __ATOMIC_RELAXED, __HIP_MEMORY_SCOPE_AGENT);
}

// ---- flag-array barrier: NO same-address RMW anywhere ----
__device__ __forceinline__ void barx(float* ws, int b, int grp, int lbase, int Ng,
                                     bool chk, int lb, int ph, int jslot, float* shr){
  const int t = threadIdx.x, lane = t&63, wvv = t>>6;
  int* flg = (int*)ws + W_FLG;
  int* rel = (int*)ws + W_REL;
  __builtin_amdgcn_s_waitcnt(0);   // every thread drains its stores
  __syncthreads();
  if (t==0) stci(flg + (size_t)b*32, ph+1);
  if (chk){
    for (int s=t; s<Ng; s+=256){
      const int* f = flg + (size_t)(lbase+s)*32;
      while (ldci(f) < ph+1) __builtin_amdgcn_s_sleep(1);
    }
    if (jslot>=0){
      float pa=0.f, pg=0.f, pn=0.f;
      for (int s=t; s<Ng; s+=256){
        const float* sl = ws + W_SLOT + ((size_t)jslot*1024 + lbase+s)*8;
        float2 ag = ldc2(sl); float nn = ldc(sl+2);
        pa+=ag.x; pg+=ag.y; pn+=nn;
      }
      pa=wredf(pa); pg=wredf(pg); pn=wredf(pn);
      if (lane==0){ shr[0*4+wvv]=pa; shr[1*4+wvv]=pg; shr[2*4+wvv]=pn; }
    }
    __syncthreads();
    if (t==0){
      if (jslot>=0){
        float a=shr[0]+shr[1]+shr[2]+shr[3];
        float g=shr[4]+shr[5]+shr[6]+shr[7];
        float n=shr[8]+shr[9]+shr[10]+shr[11];
        float* TT = ws + W_TT + (size_t)(grp*64 + jslot)*32;
        stc2(TT, make_float2(a,g)); stc(TT+2, n);
        __builtin_amdgcn_s_waitcnt(0);   // TT visible before release
      }
      #pragma unroll
      for (int i=0;i<16;i++) stci(rel + (size_t)(grp*16+i)*32, ph+1);
    }
    __syncthreads();
  } else {
    if (t==0){
      const int* r = rel + (size_t)(grp*16 + (lb&15))*32;
      while (ldci(r) < ph+1) __builtin_amdgcn_s_sleep(1);
    }
    __syncthreads();
  }
}

// ---------------- weight prep + zeroing of counters/flags ----------------
__global__ void k_wprep(const float* Wd,const float* Wu,const float* Wh,
                        const float* Wb1,const float* Wb2, float* ws){
  int t = blockIdx.x*256 + threadIdx.x;
  if (t >= 16384) return;
  int* wsi = (int*)ws;
  if (t < 5120) wsi[W_CNT + 13312 + t] = 0;          // transpose col counters
  if (t < 5120) wsi[W_CUR + t] = 0;                  // cursors
  for (int i=t; i<32768+2048; i+=16384) wsi[W_FLG+i] = 0;  // flags + releases
  float sd = Wd[t]  + Wd[16384+t]  + Wd[32768+t];
  float su = Wu[t]  + Wu[16384+t]  + Wu[32768+t];
  float s1 = Wb1[t] + Wb1[16384+t] + Wb1[32768+t];
  float s2 = Wb2[t] + Wb2[16384+t] + Wb2[32768+t];
  float wh = Wh[t];
  float* W0 = ws + W_WCAT + WC0;
  float* W1 = ws + W_WCAT + WC1;
  float* W2 = ws + W_WCAT + WC2;
  W0[t]=sd; W0[16384+t]=s1; W0[32768+t]=wh;
  W1[t]=sd; W1[16384+t]=su; W1[32768+t]=s1; W1[49152+t]=s2; W1[65536+t]=wh;
  W2[t]=su; W2[16384+t]=s2; W2[32768+t]=wh;
}

// ---------------- CSR extraction (proven) ----------------
__device__ __forceinline__ void mat_meta(int wid, const float* L0,const float* L1d,const float* L1u,
    const float* L2,const float* B1,const float* B2,
    const float*& M,int& ncol,int& lrow,int& co,int& po,int& cb,int& cap,int& tco){
  if (wid < 1024){ M=L0;  ncol=1024; lrow=wid;        co=C_L0;  po=P_L0;  cb=CB_L0;  cap=CAP_L0; tco=-1; }
  else if (wid < 4096){ M=L1d; ncol=3072; lrow=wid-1024;  co=C_L1D; po=P_L1D; cb=CB_L1D; cap=CAP_L1; tco=-1; }
  else if (wid < 7168){ M=L1u; ncol=3072; lrow=wid-4096;  co=C_L1U; po=P_L1U; cb=CB_L1U; cap=CAP_L1; tco=-1; }
  else if (wid < 9216){ M=L2;  ncol=2048; lrow=wid-7168;  co=C_L2;  po=P_L2;  cb=CB_L2;  cap=CAP_L2; tco=-1; }
  else if (wid < 10240){ M=B1; ncol=3072; lrow=wid-9216;  co=C_B1;  po=P_B1;  cb=CB_B1;  cap=CAP_B1; tco=C_B1T; }
  else { M=B2; ncol=2048; lrow=wid-10240; co=C_B2;  po=P_B2;  cb=CB_B2;  cap=CAP_B2; tco=C_B2T; }
}

__global__ void k_count(const float* L0,const float* L1d,const float* L1u,const float* L2,
                        const float* B1,const float* B2,int* cnt){
  int wid = blockIdx.x*4 + (threadIdx.x>>6);
  int lane = threadIdx.x & 63;
  if (wid >= 13312) return;
  const float* M; int ncol,lrow,co,po,cb,cap,tco;
  mat_meta(wid,L0,L1d,L1u,L2,B1,B2,M,ncol,lrow,co,po,cb,cap,tco);
  const float4* row4 = (const float4*)(M + (size_t)lrow*ncol);
  int c = 0;
  for (int j0=0; j0<ncol; j0+=256){
    float4 v = row4[(j0>>2)+lane];
    int n0=v.x!=0.f, n1=v.y!=0.f, n2=v.z!=0.f, n3=v.w!=0.f;
    c += n0+n1+n2+n3;
    if (tco>=0){
      int jb = j0 + lane*4;
      if (n0) atomicAdd(cnt+tco+jb,   1);
      if (n1) atomicAdd(cnt+tco+jb+1, 1);
      if (n2) atomicAdd(cnt+tco+jb+2, 1);
      if (n3) atomicAdd(cnt+tco+jb+3, 1);
    }
  }
  c = wredi(c);
  if (lane==0) cnt[co+lrow] = c;
}

__global__ void k_prefix(const int* cnt, int* ptr, int* cur){
  __shared__ int lds[257];
  const int rows[8]={1024,3072,3072,2048,1024,3072,3072,2048};
  const int cofs[8]={C_L0,C_L1D,C_L1U,C_L2,C_B1,C_B2,C_B1T,C_B2T};
  const int pofs[8]={P_L0,P_L1D,P_L1U,P_L2,P_B1,P_B2,P_B1T,P_B2T};
  int b=blockIdx.x, t=threadIdx.x;
  int R=rows[b]; const int* c=cnt+cofs[b]; int* p=ptr+pofs[b];
  int* cc = (b==6)? cur : (b==7)? cur+3072 : nullptr;
  int chunk=(R+255)/256;
  int lo=t*chunk, hi=min(R,lo+chunk);
  int s=0;
  for(int i=lo;i<hi;i++) s+=c[i];
  lds[t]=s; __syncthreads();
  if(t==0){ int run=0; for(int i=0;i<256;i++){int x=lds[i];lds[i]=run;run+=x;} lds[256]=run; }
  __syncthreads();
  int run=lds[t];
  for(int i=lo;i<hi;i++){ p[i]=run; if(cc) cc[i]=run; run+=c[i]; }
  if(t==0) p[R]=lds[256];
}

__global__ void k_fill(const float* L0,const float* L1d,const float* L1u,const float* L2,
                       const float* B1,const float* B2,const int* ptr,int* cidx,float* val){
  int wid = blockIdx.x*4 + (threadIdx.x>>6);
  int lane = threadIdx.x & 63;
  if (wid >= 13312) return;
  const float* M; int ncol,lrow,co,po,cb,cap,tco;
  mat_meta(wid,L0,L1d,L1u,L2,B1,B2,M,ncol,lrow,co,po,cb,cap,tco);
  const float4* row4 = (const float4*)(M + (size_t)lrow*ncol);
  int base = ptr[po+lrow];
  int run = 0;
  for (int j0=0; j0<ncol; j0+=256){
    float4 v = row4[(j0>>2)+lane];
    int n0=v.x!=0.f, n1=v.y!=0.f, n2=v.z!=0.f, n3=v.w!=0.f;
    int local = n0+n1+n2+n3;
    int incl = local;
    #pragma unroll
    for (int o=1;o<64;o<<=1){
      int tmp = __shfl_up(incl,o,64);
      if (lane>=o) incl += tmp;
    }
    int tot = __shfl(incl,63,64);
    int pos = base + run + incl - local;
    int jb = j0 + lane*4;
    if (n0){ if(pos<cap){cidx[cb+pos]=jb;   val[cb+pos]=v.x;} pos++; }
    if (n1){ if(pos<cap){cidx[cb+pos]=jb+1; val[cb+pos]=v.y;} pos++; }
    if (n2){ if(pos<cap){cidx[cb+pos]=jb+2; val[cb+pos]=v.z;} pos++; }
    if (n3){ if(pos<cap){cidx[cb+pos]=jb+3; val[cb+pos]=v.w;} pos++; }
    run += tot;
  }
}

__global__ void k_fillT(float* ws){
  int wid = blockIdx.x*4 + (threadIdx.x>>6);
  int lane = threadIdx.x & 63;
  if (wid >= 4096) return;
  int* wsi=(int*)ws;
  const int* ptr=wsi+W_PTR; int* cidx=wsi+W_CIDX; float* val=ws+W_VAL;
  int* cur=wsi+W_CUR;
  if (wid < 1024){
    int r=wid;
    int e=ptr[P_B1+r+1];
    for(int k=ptr[P_B1+r]+lane;k<e;k+=64){
      int c=cidx[CB_B1+k]; float v=val[CB_B1+k];
      int pos=atomicAdd(cur+c,1);
      cidx[CB_B1T+pos]=r; val[CB_B1T+pos]=v;
    }
  } else {
    int r=wid-1024;
    int e=ptr[P_B2+r+1];
    for(int k=ptr[P_B2+r]+lane;k<e;k+=64){
      int c=cidx[CB_B2+k]; float v=val[CB_B2+k];
      int pos=atomicAdd(cur+3072+c,1);
      cidx[CB_B2T+pos]=r; val[CB_B2T+pos]=v;
    }
  }
}

// ================= FUSED PERSISTENT SOLVER =================
// 1024 blocks x 256 threads = 4 blocks/CU, all co-resident.
// Groups by nnz: g0=c0 [0,80), g1=c1 [80,848), g2=c2 [848,1024).
// ONE FULL WAVE PER ROW. g1: 3072 waves <-> 3072 rows, zero imbalance.
__global__ __launch_bounds__(256,4) void k_solve(float* ws,
    const float* z0,const float* z1,const float* z2,
    const float* adw,const float* adb,const float* auw,const float* aub,
    float* out){
  const int b = blockIdx.x, t = threadIdx.x;
  const int wv = t>>6, lane = t&63;
  const int* wsi=(const int*)ws;
  const int* ptr=wsi+W_PTR; const int* cidx=wsi+W_CIDX; const float* val=ws+W_VAL;

  __shared__ float smem[2616];             // 10464 B
  float* Sl  = smem;                       // [544]   phase E
  float* Wl  = smem + 544;                 // [2048]  phase E
  float* TTa = smem;                       // [<=64]  eig (alias, disjoint in time)
  float* TTb = smem + 64;                  // [<=64]
  float* redm= smem + 2592;                // [12]    phase B block partials
  float* shr = smem + 2604;                // [12]    barrier payload scratch

  // group mapping (block counts proportional to nnz; all divisible by 16)
  int g, nb, crows, bbase, Ng, lb;
  if (b<80){ g=0; lb=b;      nb=0;    crows=1024; bbase=0;   Ng=80;  }
  else if (b<848){ g=1; lb=b-80; nb=1024; crows=3072; bbase=80;  Ng=768; }
  else { g=2; lb=b-848; nb=4096; crows=2048; bbase=848; Ng=176; }
  const int gwv = lb*4 + wv;               // wave id within group
  const int GW  = Ng*4;                    // waves per group
  const bool chk = (b==bbase);
  const float* zc = (g==0)?z0:(g==1)?z1:z2;
  int ph = 0;

  // ---- Phase A: v_0 init + attention U,V ----
  { int i = b*256+t;
    if (i < 6144){
      float invs = (i<1024)?0.03125f:(i<4096)?0.0180421959f:0.0220970869f;
      unsigned uu=(unsigned)i*2654435761u; uu^=uu>>16; uu*=2246822519u; uu^=uu>>13;
      stc(ws+W_VW+i, (uu&1)?invs:-invs);     // v_0
    }
  }
  { int gw = b*4+wv;
    if (gw < 3072){
      float2 x  = ((const float2*)(z1+(size_t)gw*128))[lane];
      float2 a0 = ((const float2*)adw)[lane];
      float2 a1 = ((const float2*)adw)[64+lane];
      float2 b0 = ((const float2*)auw)[lane];
      float2 b1 = ((const float2*)auw)[64+lane];
      float ud=x.x*a0.x+x.y*a0.y, vd=x.x*a1.x+x.y*a1.y;
      float uu=x.x*b0.x+x.y*b0.y, vu=x.x*b1.x+x.y*b1.y;
      ud=wredf(ud); vd=wredf(vd); uu=wredf(uu); vu=wredf(vu);
      if(lane==0){ stc(ws+W_UV+gw,ud); stc(ws+W_UV+3072+gw,vd);
                   stc(ws+W_UV+6144+gw,uu); stc(ws+W_UV+9216+gw,vu); }
    }
  }
  barx(ws, b, 3, 0, 1024, b==0, b, ph, -1, shr); ph++;   // global: v_0, UV visible

  // ---- Phase B: M_LZ Lanczos steps (one wave per row) ----
  for (int j=0;j<M_LZ;j++){
    float a, gmm, ib;
    if (j==0){ a=0.f; gmm=0.f; ib=1.f; }
    else {
      const float* TT = ws + W_TT + (size_t)(g*64 + (j-1))*32;   // write-once padded line
      a = TT[0]; gmm = TT[1]; float n = TT[2];
      ib = 1.f/sqrtf(fmaxf(n - a*a - gmm*gmm, 1e-20f));
    }
    const float* vj   = ws + W_VW + (size_t)j*6144;
    const float* vm1  = ws + W_VW + (size_t)(j>0? j-1:0)*6144;
    const float* vm2  = ws + W_VW + (size_t)(j>1? j-2:0)*6144;
    const float* wpv  = ws + W_VW + (size_t)(64 + (j>0? j-1:0))*6144;
    float* vjw        = ws + W_VW + (size_t)j*6144;
    float* wjw        = ws + W_VW + (size_t)(64+j)*6144;
    float Aa=0.f, Gg=0.f, Nn=0.f;
    for (int p = gwv; p < crows; p += GW){
      float wp=0.f;
      #define GATHER(PP,CBB) { \
        const int* rp = ptr + PP; int e=rp[p+1]; \
        for (int k=rp[p]+lane; k<e; k+=64){ \
          int q = nb + cidx[CBB+k]; float v = val[CBB+k]; \
          float vq = (j==0)? vj[q] : (wpv[q] - a*vm1[q] - gmm*vm2[q])*ib; \
          wp += v*vq; \
        } }
      if (g==0){ GATHER(P_L0, CB_L0) }
      else if (g==1){ GATHER(P_L1D, CB_L1D) GATHER(P_L1U, CB_L1U) }
      else { GATHER(P_L2, CB_L2) }
      #undef GATHER
      wp = wredf(wp);
      if (lane==0){
        int gp = nb + p;
        float vp, vm1p;
        if (j==0){ vp = vj[gp]; vm1p = 0.f; }
        else { vp = (wpv[gp] - a*vm1[gp] - gmm*vm2[gp])*ib; stc(vjw+gp, vp); vm1p = vm1[gp]; }
        stc(wjw+gp, wp);
        Aa += vp*wp; Gg += vm1p*wp; Nn += wp*wp;
      }
    }
    if (lane==0){ redm[0*4+wv]=Aa; redm[1*4+wv]=Gg; redm[2*4+wv]=Nn; }
    __syncthreads();
    if (t==0){
      float A0=redm[0]+redm[1]+redm[2]+redm[3];
      float G0=redm[4]+redm[5]+redm[6]+redm[7];
      float N0=redm[8]+redm[9]+redm[10]+redm[11];
      float* sl2 = ws + W_SLOT + ((size_t)j*1024 + b)*8;
      stc2(sl2, make_float2(A0,G0)); stc(sl2+2, N0);
    }
    barx(ws, b, g, bbase, Ng, chk, lb, ph, j, shr); ph++;
  }

  // ---- eig: one wave of each group's checker block ----
  if (chk && t<64){
    int i = t;
    if (i < M_LZ){
      const float* TT = ws + W_TT + (size_t)(g*64 + i)*32;
      float a=TT[0], gg=TT[1], n=TT[2];
      TTa[i]=a; TTb[i]=sqrtf(fmaxf(n-a*a-gg*gg,1e-20f));
    }
    double lo=1e300, hi=-1e300;
    if (i < M_LZ){
      double r=(i? fabs((double)TTb[i-1]):0.0) + (i<M_LZ-1? fabs((double)TTb[i]):0.0);
      lo=(double)TTa[i]-r; hi=(double)TTa[i]+r;
    }
    #pragma unroll
    for(int o=32;o;o>>=1){ lo=fmin(lo,__shfl_xor(lo,o,64)); hi=fmax(hi,__shfl_xor(hi,o,64)); }
    lo -= 1.0; hi += 1.0;
    for (int round=0; round<4; round++){
      double x = lo + (hi-lo)*(double)(i+1)/65.0;
      double d = 1.0; int cnt2=0;
      for (int k2=0;k2<M_LZ;k2++){
        double bi = k2? (double)TTb[k2-1] : 0.0;
        d = ((double)TTa[k2]-x) - bi*bi/d;
        if (d==0.0) d = -1e-300;
        if (d<0.0) cnt2++;
      }
      double nlo = (cnt2< M_LZ)? x : -1e300;
      double nhi = (cnt2==M_LZ)? x :  1e300;
      #pragma unroll
      for(int o=32;o;o>>=1){ nlo=fmax(nlo,__shfl_xor(nlo,o,64)); nhi=fmin(nhi,__shfl_xor(nhi,o,64)); }
      if (nlo>-1e299) lo=nlo;
      if (nhi< 1e299) hi=nhi;
    }
    double lam = 0.5*(lo+hi);
    if (i==0) stc(ws+W_EPS+(size_t)g*32, (lam>0.0)? (float)(1.0/lam) : 0.1f);
  }
  barx(ws, b, g, bbase, Ng, chk, lb, ph, -1, shr); ph++;   // eps visible within group

  // ---- Phase D: 16 harmonic steps (one wave per row, float2 per lane) ----
  {
    float eps = ws[W_EPS+(size_t)g*32];
    for (int s=0;s<16;s++){
      const float* inH = ws + W_H + (size_t)(s>0? s-1:0)*HBUF;
      for (int p = gwv; p < crows; p += GW){
        int gp = nb + p;
        float2 own, acc={0.f,0.f};
        if (s==0) own = ((const float2*)(zc + (size_t)p*128))[lane];
        else      own = ((const float2*)(inH + (size_t)gp*128))[lane];
        #define HG(PP,CBB) { \
          const int* rp=ptr+PP; int e=rp[p+1]; \
          for(int k=rp[p];k<e;k++){ \
            float v=val[CBB+k]; int q=cidx[CBB+k]; \
            float2 xq; \
            if (s==0) xq = ((const float2*)(zc+(size_t)q*128))[lane]; \
            else      xq = ((const float2*)(inH+(size_t)(nb+q)*128))[lane]; \
            acc.x+=v*xq.x; acc.y+=v*xq.y; \
          } }
        if (g==0){ HG(P_L0, CB_L0) }
        else if (g==1){ HG(P_L1D, CB_L1D) HG(P_L1U, CB_L1U) }
        else { HG(P_L2, CB_L2) }
        #undef HG
        float2 r;
        r.x = own.x - eps*acc.x; r.y = own.y - eps*acc.y;
        float* dst;
        if (s<15) dst = ws + W_H + (size_t)s*HBUF + (size_t)gp*128;
        else {
          float* outp; size_t ostride;
          if(g==0){ outp=ws+W_SCAT+S0_OFF+256; ostride=384; }
          else if(g==1){ outp=ws+W_SCAT+S1_OFF+512; ostride=640; }
          else { outp=ws+W_SCAT+S2_OFF+256; ostride=384; }
          dst = outp + (size_t)p*ostride;
        }
        stc2(dst + 2*lane, r);
      }
      if (s<15){ barx(ws, b, g, bbase, Ng, chk, lb, ph, -1, shr); ph++; }
    }
  }

  // ---- Phase C: forward SpMMs (all blocks) ----
  for (int wid2 = b*4+wv; wid2 < 18432; wid2 += 4096){
    int task,p;
    if(wid2<1024){task=0;p=wid2;}
    else if(wid2<2048){task=1;p=wid2-1024;}
    else if(wid2<5120){task=2;p=wid2-2048;}
    else if(wid2<8192){task=3;p=wid2-5120;}
    else if(wid2<11264){task=4;p=wid2-8192;}
    else if(wid2<13312){task=5;p=wid2-11264;}
    else if(wid2<16384){task=6;p=wid2-13312;}
    else {task=7;p=wid2-16384;}
    const float* in; const int* rp; int cb2; float* outp; int ostride;
    int mode=0; float Vp=0.f, bb=0.f; const float* U=nullptr;
    switch(task){
      case 0: rp=ptr+P_L0;  cb2=CB_L0;  in=z0; outp=ws+W_SCAT+S0_OFF+0;   ostride=384; break;
      case 1: rp=ptr+P_B1;  cb2=CB_B1;  in=z1; outp=ws+W_SCAT+S0_OFF+128; ostride=384; break;
      case 2: rp=ptr+P_L1D; cb2=CB_L1D; in=z1; outp=ws+W_SCAT+S1_OFF+0;   ostride=640;
              mode=1; U=ws+W_UV; Vp=ws[W_UV+3072+p]; bb=adb[0]; break;
      case 3: rp=ptr+P_L1U; cb2=CB_L1U; in=z1; outp=ws+W_SCAT+S1_OFF+128; ostride=640;
              mode=1; U=ws+W_UV+6144; Vp=ws[W_UV+9216+p]; bb=aub[0]; break;
      case 4: rp=ptr+P_B2;  cb2=CB_B2;  in=z2; outp=ws+W_SCAT+S1_OFF+384; ostride=640; break;
      case 5: rp=ptr+P_L2;  cb2=CB_L2;  in=z2; outp=ws+W_SCAT+S2_OFF+0;   ostride=384; break;
      case 6: rp=ptr+P_B1T; cb2=CB_B1T; in=z0; outp=ws+W_SCAT+S1_OFF+256; ostride=640; break;
      default:rp=ptr+P_B2T; cb2=CB_B2T; in=z1; outp=ws+W_SCAT+S2_OFF+128; ostride=384; break;
    }
    float2 s={0.f,0.f};
    int e=rp[p+1];
    for (int k=rp[p]; k<e; k++){
      int q = cidx[cb2+k];
      float v;
      if (mode) v = 1.0f/(1.0f+__expf(-(U[q]+Vp+bb)));
      else v = val[cb2+k];
      float2 xq = ((const float2*)(in+(size_t)q*128))[lane];
      s.x += v*xq.x; s.y += v*xq.y;
    }
    stc2(outp + (size_t)p*ostride + 2*lane, s);
  }
  barx(ws, b, 3, 0, 1024, b==0, b, ph, -1, shr); ph++;   // global join: SCAT complete

  // ---- Phase E: projection GEMMs (blocks 0..191), K-tile 16 ----
  if (b < 192){
    const float* S; const float* W; float* outp; int K; int blk;
    if (b<32){       S=ws+W_SCAT+S0_OFF; W=ws+W_WCAT+WC0; outp=out;        K=384; blk=b; }
    else if (b<128){ S=ws+W_SCAT+S1_OFF; W=ws+W_WCAT+WC1; outp=out+131072; K=640; blk=b-32; }
    else {           S=ws+W_SCAT+S2_OFF; W=ws+W_WCAT+WC2; outp=out+524288; K=384; blk=b-128; }
    int r0=blk*32;
    int ty=t>>5, tx=t&31;
    float acc[4][4]={};
    for (int k0=0; k0<K; k0+=16){
      {
        int r=t>>3, kq=(t&7)*2;
        const float* src=S+(size_t)(r0+r)*K + k0+kq;
        Sl[r*17+kq]=src[0]; Sl[r*17+kq+1]=src[1];
      }
      {
        int kk=t>>4, cq=(t&15)*8;
        const float* src=W+(size_t)(k0+kk)*128+cq;
        #pragma unroll
        for(int i=0;i<8;i++) Wl[kk*128+cq+i]=src[i];
      }
      __syncthreads();
      #pragma unroll
      for(int k=0;k<16;k++){
        float sv[4], wvv2[4];
        #pragma unroll
        for(int i=0;i<4;i++) sv[i]=Sl[(ty*4+i)*17+k];
        #pragma unroll
        for(int i=0;i<4;i++) wvv2[i]=Wl[k*128+tx+32*i];
        #pragma unroll
        for(int a2=0;a2<4;a2++)
          #pragma unroll
          for(int b2=0;b2<4;b2++) acc[a2][b2]+=sv[a2]*wvv2[b2];
      }
      __syncthreads();
    }
    #pragma unroll
    for(int a2=0;a2<4;a2++)
      #pragma unroll
      for(int b2=0;b2<4;b2++){
        int r=r0+ty*4+a2, col=tx+32*b2;
        outp[(size_t)r*128+col]=fmaxf(acc[a2][b2],0.f);
      }
  }
}

// ---------------- host ----------------
extern "C" void kernel_launch(void* const* d_in, const int* in_sizes, int n_in,
                              void* d_out, int out_size, void* d_ws, size_t ws_size,
                              hipStream_t stream){
  const float* z0 =(const float*)d_in[0];
  const float* z1 =(const float*)d_in[1];
  const float* z2 =(const float*)d_in[2];
  const float* L0 =(const float*)d_in[3];
  const float* L1d=(const float*)d_in[4];
  const float* L1u=(const float*)d_in[5];
  const float* L2 =(const float*)d_in[6];
  const float* B1 =(const float*)d_in[7];
  const float* B2 =(const float*)d_in[8];
  const float* Wd =(const float*)d_in[9];
  const float* Wu =(const float*)d_in[10];
  const float* Wh =(const float*)d_in[11];
  const float* Wb1=(const float*)d_in[12];
  const float* Wb2=(const float*)d_in[13];
  const float* adw=(const float*)d_in[14];
  const float* adb=(const float*)d_in[15];
  const float* auw=(const float*)d_in[16];
  const float* aub=(const float*)d_in[17];
  float* ws=(float*)d_ws;
  int* wsi=(int*)d_ws;
  float* out=(float*)d_out;

  hipLaunchKernelGGL(k_wprep, dim3(64), dim3(256), 0, stream, Wd,Wu,Wh,Wb1,Wb2,ws);
  hipLaunchKernelGGL(k_count, dim3(3328), dim3(256), 0, stream, L0,L1d,L1u,L2,B1,B2, wsi+W_CNT);
  hipLaunchKernelGGL(k_prefix, dim3(8), dim3(256), 0, stream, wsi+W_CNT, wsi+W_PTR, wsi+W_CUR);
  hipLaunchKernelGGL(k_fill, dim3(3328), dim3(256), 0, stream, L0,L1d,L1u,L2,B1,B2, wsi+W_PTR, wsi+W_CIDX, ws+W_VAL);
  hipLaunchKernelGGL(k_fillT, dim3(1024), dim3(256), 0, stream, ws);
  hipLaunchKernelGGL(k_solve, dim3(1024), dim3(256), 0, stream,
                     ws, z0, z1, z2, adw, adb, auw, aub, out);
}

// Round 13
// 1319.975 us; speedup vs baseline: 1.7024x; 1.1465x over previous
//
#include <hip/hip_runtime.h>
#include <string.h>

// ---------------- problem constants ----------------
constexpr int M_LZ = 64;   // Lanczos steps (lz step ~2us marginal; buy back 5.5x absmax margin)

// CSR capacity per matrix (expected nnz * ~1.25)
constexpr int CAP_L0 = 26240, CAP_L1 = 118016, CAP_L2 = 52480, CAP_B1 = 39360, CAP_B2 = 78720;
constexpr int CB_L0 = 0;
constexpr int CB_L1D = CB_L0 + CAP_L0;
constexpr int CB_L1U = CB_L1D + CAP_L1;
constexpr int CB_L2  = CB_L1U + CAP_L1;
constexpr int CB_B1  = CB_L2 + CAP_L2;
constexpr int CB_B2  = CB_B1 + CAP_B1;
constexpr int CAP_TOT= CB_B2 + CAP_B2;   // 432832
constexpr int CB_B1T = CAP_TOT;
constexpr int CB_B2T = CB_B1T + CAP_B1;
constexpr int CAP_TOT2 = CB_B2T + CAP_B2; // 550912

// rowptr offsets (ints) within W_PTR region
constexpr int P_L0=0, P_L1D=1025, P_L1U=4098, P_L2=7171, P_B1=9220, P_B2=10245;
constexpr int P_B1T=13320, P_B2T=16393;   // region size 18444
// row-count offsets within W_CNT region
constexpr int C_L0=0, C_L1D=1024, C_L1U=4096, C_L2=7168, C_B1=9216, C_B2=10240;
constexpr int C_B1T=13312, C_B2T=16384;   // region size 18432

constexpr size_t HBUF  = (size_t)6144*128;          // 786432 words

// workspace layout (units: 4-byte words)
constexpr size_t W_CNT = 0;                         // 18432 ints
constexpr size_t W_PTR = 18432;                     // 18444 ints
constexpr size_t W_CUR = W_PTR + 18444;             // 5120 ints
constexpr size_t W_CIDX= W_CUR + 5120;              // CAP_TOT2 ints
constexpr size_t W_VAL = W_CIDX + CAP_TOT2;         // CAP_TOT2 floats
// write-once step-indexed Lanczos vectors: v_0..v_63 then w_0..w_63 (global 6144 rows)
constexpr size_t W_VW  = W_VAL + CAP_TOT2;          // 128*6144 = 786432
// tridiagonal entries: TT[g][j] = (a, g, n), padded to one 128B line each
constexpr size_t W_TT  = W_VW + 786432;             // 3*64*32 = 6144
constexpr size_t W_EPS = W_TT + 6144;               // 4*32 (per-group padded line)
constexpr size_t W_UV  = W_EPS + 128;               // 4*3072 (U_d,V_d,U_u,V_u)
// write-once harmonic buffers: [s][row][128]
constexpr size_t W_H   = W_UV + 4*3072;             // 15*HBUF
constexpr size_t W_SCAT= W_H + 15*HBUF;
constexpr size_t S0_OFF= 0;                          // 1024 x 384
constexpr size_t S1_OFF= (size_t)1024*384;           // 3072 x 640
constexpr size_t S2_OFF= S1_OFF + (size_t)3072*640;  // 2048 x 384
constexpr size_t SCAT_TOT = S2_OFF + (size_t)2048*384;
constexpr size_t W_WCAT= W_SCAT + SCAT_TOT;          // 1408*128 concatenated weights
constexpr size_t WC0=0, WC1=(size_t)384*128, WC2=WC1+(size_t)640*128;
// per-block dot partial slots, step-indexed (write-once): [j][b] -> 8 floats (32B)
constexpr size_t W_SLOT= W_WCAT + (size_t)1408*128;  // 64*1024*8 = 524288
// per-block arrival flags (monotonic phase counters), padded 128B each
constexpr size_t W_FLG = W_SLOT + 524288;            // 1024*32
// release copies: 4 groups x 16 leaves, padded 128B each
constexpr size_t W_REL = W_FLG + 32768;              // 2048

__device__ __forceinline__ float wredf(float v){
  #pragma unroll
  for(int o=32;o;o>>=1) v += __shfl_xor(v,o,64);
  return v;
}
__device__ __forceinline__ int wredi(int v){
  #pragma unroll
  for(int o=32;o;o>>=1) v += __shfl_xor(v,o,64);
  return v;
}
// fold 4 nnz-subgroups (lanes l, l^16, l^32, l^48) for 8 accumulator comps
__device__ __forceinline__ void red4x2(float4& a0, float4& a1){
  #pragma unroll
  for (int o=16;o<=32;o<<=1){
    a0.x+=__shfl_xor(a0.x,o,64); a0.y+=__shfl_xor(a0.y,o,64);
    a0.z+=__shfl_xor(a0.z,o,64); a0.w+=__shfl_xor(a0.w,o,64);
    a1.x+=__shfl_xor(a1.x,o,64); a1.y+=__shfl_xor(a1.y,o,64);
    a1.z+=__shfl_xor(a1.z,o,64); a1.w+=__shfl_xor(a1.w,o,64);
  }
}

// agent-scope (L2-bypassing) ops
__device__ __forceinline__ float ldc(const float* p){
  return __hip_atomic_load(p, __ATOMIC_RELAXED, __HIP_MEMORY_SCOPE_AGENT);
}
__device__ __forceinline__ float2 ldc2(const float* p){
  unsigned long long u = __hip_atomic_load((const unsigned long long*)p,
                          __ATOMIC_RELAXED, __HIP_MEMORY_SCOPE_AGENT);
  float2 r; memcpy(&r,&u,8); return r;
}
__device__ __forceinline__ void stc(float* p, float v){
  __hip_atomic_store(p, v, __ATOMIC_RELAXED, __HIP_MEMORY_SCOPE_AGENT);
}
__device__ __forceinline__ void stc2(float* p, float2 v){
  unsigned long long u; memcpy(&u,&v,8);
  __hip_atomic_store((unsigned long long*)p, u, __ATOMIC_RELAXED, __HIP_MEMORY_SCOPE_AGENT);
}
__device__ __forceinline__ int ldci(const int* p){
  return __hip_atomic_load(p, __ATOMIC_RELAXED, __HIP_MEMORY_SCOPE_AGENT);
}
__device__ __forceinline__ void stci(int* p, int v){
  __hip_atomic_store(p, v, __ATOMIC_RELAXED, __HIP_MEMORY_SCOPE_AGENT);
}

// ---- flag-array barrier: NO same-address RMW anywhere ----
__device__ __forceinline__ void barx(float* ws, int b, int grp, int lbase, int Ng,
                                     bool chk, int lb, int ph, int jslot, float* shr){
  const int t = threadIdx.x, lane = t&63, wvv = t>>6;
  int* flg = (int*)ws + W_FLG;
  int* rel = (int*)ws + W_REL;
  __builtin_amdgcn_s_waitcnt(0);   // every thread drains its stores
  __syncthreads();
  if (t==0) stci(flg + (size_t)b*32, ph+1);
  if (chk){
    for (int s=t; s<Ng; s+=256){
      const int* f = flg + (size_t)(lbase+s)*32;
      while (ldci(f) < ph+1) __builtin_amdgcn_s_sleep(1);
    }
    if (jslot>=0){
      float pa=0.f, pg=0.f, pn=0.f;
      for (int s=t; s<Ng; s+=256){
        const float* sl = ws + W_SLOT + ((size_t)jslot*1024 + lbase+s)*8;
        float2 ag = ldc2(sl); float nn = ldc(sl+2);
        pa+=ag.x; pg+=ag.y; pn+=nn;
      }
      pa=wredf(pa); pg=wredf(pg); pn=wredf(pn);
      if (lane==0){ shr[0*4+wvv]=pa; shr[1*4+wvv]=pg; shr[2*4+wvv]=pn; }
    }
    __syncthreads();
    if (t==0){
      if (jslot>=0){
        float a=shr[0]+shr[1]+shr[2]+shr[3];
        float g=shr[4]+shr[5]+shr[6]+shr[7];
        float n=shr[8]+shr[9]+shr[10]+shr[11];
        float* TT = ws + W_TT + (size_t)(grp*64 + jslot)*32;
        stc2(TT, make_float2(a,g)); stc(TT+2, n);
        __builtin_amdgcn_s_waitcnt(0);   // TT visible before release
      }
      #pragma unroll
      for (int i=0;i<16;i++) stci(rel + (size_t)(grp*16+i)*32, ph+1);
    }
    __syncthreads();
  } else {
    if (t==0){
      const int* r = rel + (size_t)(grp*16 + (lb&15))*32;
      while (ldci(r) < ph+1) __builtin_amdgcn_s_sleep(1);
    }
    __syncthreads();
  }
}

// ---------------- weight prep + zeroing of counters/flags ----------------
__global__ void k_wprep(const float* Wd,const float* Wu,const float* Wh,
                        const float* Wb1,const float* Wb2, float* ws){
  int t = blockIdx.x*256 + threadIdx.x;
  if (t >= 16384) return;
  int* wsi = (int*)ws;
  if (t < 5120) wsi[W_CNT + 13312 + t] = 0;          // transpose col counters
  if (t < 5120) wsi[W_CUR + t] = 0;                  // cursors
  for (int i=t; i<32768+2048; i+=16384) wsi[W_FLG+i] = 0;  // flags + releases
  float sd = Wd[t]  + Wd[16384+t]  + Wd[32768+t];
  float su = Wu[t]  + Wu[16384+t]  + Wu[32768+t];
  float s1 = Wb1[t] + Wb1[16384+t] + Wb1[32768+t];
  float s2 = Wb2[t] + Wb2[16384+t] + Wb2[32768+t];
  float wh = Wh[t];
  float* W0 = ws + W_WCAT + WC0;
  float* W1 = ws + W_WCAT + WC1;
  float* W2 = ws + W_WCAT + WC2;
  W0[t]=sd; W0[16384+t]=s1; W0[32768+t]=wh;
  W1[t]=sd; W1[16384+t]=su; W1[32768+t]=s1; W1[49152+t]=s2; W1[65536+t]=wh;
  W2[t]=su; W2[16384+t]=s2; W2[32768+t]=wh;
}

// ---------------- CSR extraction (proven) ----------------
__device__ __forceinline__ void mat_meta(int wid, const float* L0,const float* L1d,const float* L1u,
    const float* L2,const float* B1,const float* B2,
    const float*& M,int& ncol,int& lrow,int& co,int& po,int& cb,int& cap,int& tco){
  if (wid < 1024){ M=L0;  ncol=1024; lrow=wid;        co=C_L0;  po=P_L0;  cb=CB_L0;  cap=CAP_L0; tco=-1; }
  else if (wid < 4096){ M=L1d; ncol=3072; lrow=wid-1024;  co=C_L1D; po=P_L1D; cb=CB_L1D; cap=CAP_L1; tco=-1; }
  else if (wid < 7168){ M=L1u; ncol=3072; lrow=wid-4096;  co=C_L1U; po=P_L1U; cb=CB_L1U; cap=CAP_L1; tco=-1; }
  else if (wid < 9216){ M=L2;  ncol=2048; lrow=wid-7168;  co=C_L2;  po=P_L2;  cb=CB_L2;  cap=CAP_L2; tco=-1; }
  else if (wid < 10240){ M=B1; ncol=3072; lrow=wid-9216;  co=C_B1;  po=P_B1;  cb=CB_B1;  cap=CAP_B1; tco=C_B1T; }
  else { M=B2; ncol=2048; lrow=wid-10240; co=C_B2;  po=P_B2;  cb=CB_B2;  cap=CAP_B2; tco=C_B2T; }
}

__global__ void k_count(const float* L0,const float* L1d,const float* L1u,const float* L2,
                        const float* B1,const float* B2,int* cnt){
  int wid = blockIdx.x*4 + (threadIdx.x>>6);
  int lane = threadIdx.x & 63;
  if (wid >= 13312) return;
  const float* M; int ncol,lrow,co,po,cb,cap,tco;
  mat_meta(wid,L0,L1d,L1u,L2,B1,B2,M,ncol,lrow,co,po,cb,cap,tco);
  const float4* row4 = (const float4*)(M + (size_t)lrow*ncol);
  int c = 0;
  for (int j0=0; j0<ncol; j0+=256){
    float4 v = row4[(j0>>2)+lane];
    int n0=v.x!=0.f, n1=v.y!=0.f, n2=v.z!=0.f, n3=v.w!=0.f;
    c += n0+n1+n2+n3;
    if (tco>=0){
      int jb = j0 + lane*4;
      if (n0) atomicAdd(cnt+tco+jb,   1);
      if (n1) atomicAdd(cnt+tco+jb+1, 1);
      if (n2) atomicAdd(cnt+tco+jb+2, 1);
      if (n3) atomicAdd(cnt+tco+jb+3, 1);
    }
  }
  c = wredi(c);
  if (lane==0) cnt[co+lrow] = c;
}

__global__ void k_prefix(const int* cnt, int* ptr, int* cur){
  __shared__ int lds[257];
  const int rows[8]={1024,3072,3072,2048,1024,3072,3072,2048};
  const int cofs[8]={C_L0,C_L1D,C_L1U,C_L2,C_B1,C_B2,C_B1T,C_B2T};
  const int pofs[8]={P_L0,P_L1D,P_L1U,P_L2,P_B1,P_B2,P_B1T,P_B2T};
  int b=blockIdx.x, t=threadIdx.x;
  int R=rows[b]; const int* c=cnt+cofs[b]; int* p=ptr+pofs[b];
  int* cc = (b==6)? cur : (b==7)? cur+3072 : nullptr;
  int chunk=(R+255)/256;
  int lo=t*chunk, hi=min(R,lo+chunk);
  int s=0;
  for(int i=lo;i<hi;i++) s+=c[i];
  lds[t]=s; __syncthreads();
  if(t==0){ int run=0; for(int i=0;i<256;i++){int x=lds[i];lds[i]=run;run+=x;} lds[256]=run; }
  __syncthreads();
  int run=lds[t];
  for(int i=lo;i<hi;i++){ p[i]=run; if(cc) cc[i]=run; run+=c[i]; }
  if(t==0) p[R]=lds[256];
}

__global__ void k_fill(const float* L0,const float* L1d,const float* L1u,const float* L2,
                       const float* B1,const float* B2,const int* ptr,int* cidx,float* val){
  int wid = blockIdx.x*4 + (threadIdx.x>>6);
  int lane = threadIdx.x & 63;
  if (wid >= 13312) return;
  const float* M; int ncol,lrow,co,po,cb,cap,tco;
  mat_meta(wid,L0,L1d,L1u,L2,B1,B2,M,ncol,lrow,co,po,cb,cap,tco);
  const float4* row4 = (const float4*)(M + (size_t)lrow*ncol);
  int base = ptr[po+lrow];
  int run = 0;
  for (int j0=0; j0<ncol; j0+=256){
    float4 v = row4[(j0>>2)+lane];
    int n0=v.x!=0.f, n1=v.y!=0.f, n2=v.z!=0.f, n3=v.w!=0.f;
    int local = n0+n1+n2+n3;
    int incl = local;
    #pragma unroll
    for (int o=1;o<64;o<<=1){
      int tmp = __shfl_up(incl,o,64);
      if (lane>=o) incl += tmp;
    }
    int tot = __shfl(incl,63,64);
    int pos = base + run + incl - local;
    int jb = j0 + lane*4;
    if (n0){ if(pos<cap){cidx[cb+pos]=jb;   val[cb+pos]=v.x;} pos++; }
    if (n1){ if(pos<cap){cidx[cb+pos]=jb+1; val[cb+pos]=v.y;} pos++; }
    if (n2){ if(pos<cap){cidx[cb+pos]=jb+2; val[cb+pos]=v.z;} pos++; }
    if (n3){ if(pos<cap){cidx[cb+pos]=jb+3; val[cb+pos]=v.w;} pos++; }
    run += tot;
  }
}

__global__ void k_fillT(float* ws){
  int wid = blockIdx.x*4 + (threadIdx.x>>6);
  int lane = threadIdx.x & 63;
  if (wid >= 4096) return;
  int* wsi=(int*)ws;
  const int* ptr=wsi+W_PTR; int* cidx=wsi+W_CIDX; float* val=ws+W_VAL;
  int* cur=wsi+W_CUR;
  if (wid < 1024){
    int r=wid;
    int e=ptr[P_B1+r+1];
    for(int k=ptr[P_B1+r]+lane;k<e;k+=64){
      int c=cidx[CB_B1+k]; float v=val[CB_B1+k];
      int pos=atomicAdd(cur+c,1);
      cidx[CB_B1T+pos]=r; val[CB_B1T+pos]=v;
    }
  } else {
    int r=wid-1024;
    int e=ptr[P_B2+r+1];
    for(int k=ptr[P_B2+r]+lane;k<e;k+=64){
      int c=cidx[CB_B2+k]; float v=val[CB_B2+k];
      int pos=atomicAdd(cur+3072+c,1);
      cidx[CB_B2T+pos]=r; val[CB_B2T+pos]=v;
    }
  }
}

// ================= FUSED PERSISTENT SOLVER =================
// 1024 blocks x 256 threads = 4 blocks/CU, all co-resident.
// Groups by nnz: g0=c0 [0,80), g1=c1 [80,848), g2=c2 [848,1024).
// Lanczos: one wave per row, lanes over nnz (1 mem round-trip).
// Harm/SpMM: 4 nnz-subgroups x 16 lanes x 8ch -> serial gather depth /4.
__global__ __launch_bounds__(256,4) void k_solve(float* ws,
    const float* z0,const float* z1,const float* z2,
    const float* adw,const float* adb,const float* auw,const float* aub,
    float* out){
  const int b = blockIdx.x, t = threadIdx.x;
  const int wv = t>>6, lane = t&63;
  const int sg = lane>>4, chn = lane&15;   // nnz-subgroup, channel-sixteenth
  const int* wsi=(const int*)ws;
  const int* ptr=wsi+W_PTR; const int* cidx=wsi+W_CIDX; const float* val=ws+W_VAL;

  __shared__ float smem[2616];             // 10464 B
  float* Sl  = smem;                       // [544]   phase E
  float* Wl  = smem + 544;                 // [2048]  phase E
  float* TTa = smem;                       // [64]    eig (alias, disjoint in time)
  float* TTb = smem + 64;                  // [64]
  float* redm= smem + 2592;                // [12]    phase B block partials
  float* shr = smem + 2604;                // [12]    barrier payload scratch

  // group mapping (block counts proportional to nnz; all divisible by 16)
  int g, nb, crows, bbase, Ng, lb;
  if (b<80){ g=0; lb=b;      nb=0;    crows=1024; bbase=0;   Ng=80;  }
  else if (b<848){ g=1; lb=b-80; nb=1024; crows=3072; bbase=80;  Ng=768; }
  else { g=2; lb=b-848; nb=4096; crows=2048; bbase=848; Ng=176; }
  const int gwv = lb*4 + wv;               // wave id within group
  const int GW  = Ng*4;                    // waves per group
  const bool chk = (b==bbase);
  const float* zc = (g==0)?z0:(g==1)?z1:z2;
  int ph = 0;

  // ---- Phase A: v_0 init + attention U,V ----
  { int i = b*256+t;
    if (i < 6144){
      float invs = (i<1024)?0.03125f:(i<4096)?0.0180421959f:0.0220970869f;
      unsigned uu=(unsigned)i*2654435761u; uu^=uu>>16; uu*=2246822519u; uu^=uu>>13;
      stc(ws+W_VW+i, (uu&1)?invs:-invs);     // v_0
    }
  }
  { int gw = b*4+wv;
    if (gw < 3072){
      float2 x  = ((const float2*)(z1+(size_t)gw*128))[lane];
      float2 a0 = ((const float2*)adw)[lane];
      float2 a1 = ((const float2*)adw)[64+lane];
      float2 b0 = ((const float2*)auw)[lane];
      float2 b1 = ((const float2*)auw)[64+lane];
      float ud=x.x*a0.x+x.y*a0.y, vd=x.x*a1.x+x.y*a1.y;
      float uu=x.x*b0.x+x.y*b0.y, vu=x.x*b1.x+x.y*b1.y;
      ud=wredf(ud); vd=wredf(vd); uu=wredf(uu); vu=wredf(vu);
      if(lane==0){ stc(ws+W_UV+gw,ud); stc(ws+W_UV+3072+gw,vd);
                   stc(ws+W_UV+6144+gw,uu); stc(ws+W_UV+9216+gw,vu); }
    }
  }
  barx(ws, b, 3, 0, 1024, b==0, b, ph, -1, shr); ph++;   // global: v_0, UV visible

  // ---- Phase B: M_LZ Lanczos steps (one wave per row) ----
  for (int j=0;j<M_LZ;j++){
    float a, gmm, ib;
    if (j==0){ a=0.f; gmm=0.f; ib=1.f; }
    else {
      const float* TT = ws + W_TT + (size_t)(g*64 + (j-1))*32;   // write-once padded line
      a = TT[0]; gmm = TT[1]; float n = TT[2];
      ib = 1.f/sqrtf(fmaxf(n - a*a - gmm*gmm, 1e-20f));
    }
    const float* vj   = ws + W_VW + (size_t)j*6144;
    const float* vm1  = ws + W_VW + (size_t)(j>0? j-1:0)*6144;
    const float* vm2  = ws + W_VW + (size_t)(j>1? j-2:0)*6144;
    const float* wpv  = ws + W_VW + (size_t)(64 + (j>0? j-1:0))*6144;
    float* vjw        = ws + W_VW + (size_t)j*6144;
    float* wjw        = ws + W_VW + (size_t)(64+j)*6144;
    float Aa=0.f, Gg=0.f, Nn=0.f;
    for (int p = gwv; p < crows; p += GW){
      float wp=0.f;
      #define GATHER(PP,CBB) { \
        const int* rp = ptr + PP; int e=rp[p+1]; \
        for (int k=rp[p]+lane; k<e; k+=64){ \
          int q = nb + cidx[CBB+k]; float v = val[CBB+k]; \
          float vq = (j==0)? vj[q] : (wpv[q] - a*vm1[q] - gmm*vm2[q])*ib; \
          wp += v*vq; \
        } }
      if (g==0){ GATHER(P_L0, CB_L0) }
      else if (g==1){ GATHER(P_L1D, CB_L1D) GATHER(P_L1U, CB_L1U) }
      else { GATHER(P_L2, CB_L2) }
      #undef GATHER
      wp = wredf(wp);
      if (lane==0){
        int gp = nb + p;
        float vp, vm1p;
        if (j==0){ vp = vj[gp]; vm1p = 0.f; }
        else { vp = (wpv[gp] - a*vm1[gp] - gmm*vm2[gp])*ib; stc(vjw+gp, vp); vm1p = vm1[gp]; }
        stc(wjw+gp, wp);
        Aa += vp*wp; Gg += vm1p*wp; Nn += wp*wp;
      }
    }
    if (lane==0){ redm[0*4+wv]=Aa; redm[1*4+wv]=Gg; redm[2*4+wv]=Nn; }
    __syncthreads();
    if (t==0){
      float A0=redm[0]+redm[1]+redm[2]+redm[3];
      float G0=redm[4]+redm[5]+redm[6]+redm[7];
      float N0=redm[8]+redm[9]+redm[10]+redm[11];
      float* sl2 = ws + W_SLOT + ((size_t)j*1024 + b)*8;
      stc2(sl2, make_float2(A0,G0)); stc(sl2+2, N0);
    }
    barx(ws, b, g, bbase, Ng, chk, lb, ph, j, shr); ph++;
  }

  // ---- eig: one wave of each group's checker block ----
  if (chk && t<64){
    int i = t;
    { const float* TT = ws + W_TT + (size_t)(g*64 + i)*32;
      float a=TT[0], gg=TT[1], n=TT[2];
      TTa[i]=a; TTb[i]=sqrtf(fmaxf(n-a*a-gg*gg,1e-20f));
    }
    double lo, hi;
    { double r=(i? fabs((double)TTb[i-1]):0.0) + (i<M_LZ-1? fabs((double)TTb[i]):0.0);
      lo=(double)TTa[i]-r; hi=(double)TTa[i]+r; }
    #pragma unroll
    for(int o=32;o;o>>=1){ lo=fmin(lo,__shfl_xor(lo,o,64)); hi=fmax(hi,__shfl_xor(hi,o,64)); }
    lo -= 1.0; hi += 1.0;
    for (int round=0; round<4; round++){
      double x = lo + (hi-lo)*(double)(i+1)/65.0;
      double d = 1.0; int cnt2=0;
      for (int k2=0;k2<M_LZ;k2++){
        double bi = k2? (double)TTb[k2-1] : 0.0;
        d = ((double)TTa[k2]-x) - bi*bi/d;
        if (d==0.0) d = -1e-300;
        if (d<0.0) cnt2++;
      }
      double nlo = (cnt2< M_LZ)? x : -1e300;
      double nhi = (cnt2==M_LZ)? x :  1e300;
      #pragma unroll
      for(int o=32;o;o>>=1){ nlo=fmax(nlo,__shfl_xor(nlo,o,64)); nhi=fmin(nhi,__shfl_xor(nhi,o,64)); }
      if (nlo>-1e299) lo=nlo;
      if (nhi< 1e299) hi=nhi;
    }
    double lam = 0.5*(lo+hi);
    if (i==0) stc(ws+W_EPS+(size_t)g*32, (lam>0.0)? (float)(1.0/lam) : 0.1f);
  }
  barx(ws, b, g, bbase, Ng, chk, lb, ph, -1, shr); ph++;   // eps visible within group

  // ---- Phase D: 16 harmonic steps (4-way nnz-parallel, 8 ch per lane) ----
  {
    float eps = ws[W_EPS+(size_t)g*32];
    for (int s=0;s<16;s++){
      const float* inH = ws + W_H + (size_t)(s>0? s-1:0)*HBUF;
      for (int p = gwv; p < crows; p += GW){
        int gp = nb + p;
        float4 a0={0.f,0.f,0.f,0.f}, a1={0.f,0.f,0.f,0.f};
        #define HG(PP,CBB) { \
          const int* rp=ptr+PP; int e=rp[p+1]; \
          for(int k=rp[p]+sg;k<e;k+=4){ \
            float v=val[CBB+k]; int q=cidx[CBB+k]; \
            const float* sr = (s==0)? zc+(size_t)q*128 : inH+(size_t)(nb+q)*128; \
            float4 x0 = ((const float4*)sr)[chn*2]; \
            float4 x1 = ((const float4*)sr)[chn*2+1]; \
            a0.x+=v*x0.x; a0.y+=v*x0.y; a0.z+=v*x0.z; a0.w+=v*x0.w; \
            a1.x+=v*x1.x; a1.y+=v*x1.y; a1.z+=v*x1.z; a1.w+=v*x1.w; \
          } }
        if (g==0){ HG(P_L0, CB_L0) }
        else if (g==1){ HG(P_L1D, CB_L1D) HG(P_L1U, CB_L1U) }
        else { HG(P_L2, CB_L2) }
        #undef HG
        red4x2(a0, a1);
        if (sg==0){
          const float* ownr = (s==0)? zc+(size_t)p*128 : inH+(size_t)gp*128;
          float4 o0 = ((const float4*)ownr)[chn*2];
          float4 o1 = ((const float4*)ownr)[chn*2+1];
          float* dst;
          if (s<15) dst = ws + W_H + (size_t)s*HBUF + (size_t)gp*128;
          else {
            float* outp; size_t ostride;
            if(g==0){ outp=ws+W_SCAT+S0_OFF+256; ostride=384; }
            else if(g==1){ outp=ws+W_SCAT+S1_OFF+512; ostride=640; }
            else { outp=ws+W_SCAT+S2_OFF+256; ostride=384; }
            dst = outp + (size_t)p*ostride;
          }
          stc2(dst+chn*8,   make_float2(o0.x-eps*a0.x, o0.y-eps*a0.y));
          stc2(dst+chn*8+2, make_float2(o0.z-eps*a0.z, o0.w-eps*a0.w));
          stc2(dst+chn*8+4, make_float2(o1.x-eps*a1.x, o1.y-eps*a1.y));
          stc2(dst+chn*8+6, make_float2(o1.z-eps*a1.z, o1.w-eps*a1.w));
        }
      }
      if (s<15){ barx(ws, b, g, bbase, Ng, chk, lb, ph, -1, shr); ph++; }
    }
  }

  // ---- Phase C: forward SpMMs (all blocks; 4-way nnz-parallel) ----
  for (int wid2 = b*4+wv; wid2 < 18432; wid2 += 4096){
    int task,p;
    if(wid2<1024){task=0;p=wid2;}
    else if(wid2<2048){task=1;p=wid2-1024;}
    else if(wid2<5120){task=2;p=wid2-2048;}
    else if(wid2<8192){task=3;p=wid2-5120;}
    else if(wid2<11264){task=4;p=wid2-8192;}
    else if(wid2<13312){task=5;p=wid2-11264;}
    else if(wid2<16384){task=6;p=wid2-13312;}
    else {task=7;p=wid2-16384;}
    const float* in; const int* rp; int cb2; float* outp; int ostride;
    int mode=0; float Vp=0.f, bb=0.f; const float* U=nullptr;
    switch(task){
      case 0: rp=ptr+P_L0;  cb2=CB_L0;  in=z0; outp=ws+W_SCAT+S0_OFF+0;   ostride=384; break;
      case 1: rp=ptr+P_B1;  cb2=CB_B1;  in=z1; outp=ws+W_SCAT+S0_OFF+128; ostride=384; break;
      case 2: rp=ptr+P_L1D; cb2=CB_L1D; in=z1; outp=ws+W_SCAT+S1_OFF+0;   ostride=640;
              mode=1; U=ws+W_UV; Vp=ws[W_UV+3072+p]; bb=adb[0]; break;
      case 3: rp=ptr+P_L1U; cb2=CB_L1U; in=z1; outp=ws+W_SCAT+S1_OFF+128; ostride=640;
              mode=1; U=ws+W_UV+6144; Vp=ws[W_UV+9216+p]; bb=aub[0]; break;
      case 4: rp=ptr+P_B2;  cb2=CB_B2;  in=z2; outp=ws+W_SCAT+S1_OFF+384; ostride=640; break;
      case 5: rp=ptr+P_L2;  cb2=CB_L2;  in=z2; outp=ws+W_SCAT+S2_OFF+0;   ostride=384; break;
      case 6: rp=ptr+P_B1T; cb2=CB_B1T; in=z0; outp=ws+W_SCAT+S1_OFF+256; ostride=640; break;
      default:rp=ptr+P_B2T; cb2=CB_B2T; in=z1; outp=ws+W_SCAT+S2_OFF+128; ostride=384; break;
    }
    float4 a0={0.f,0.f,0.f,0.f}, a1={0.f,0.f,0.f,0.f};
    int e=rp[p+1];
    for (int k=rp[p]+sg; k<e; k+=4){
      int q = cidx[cb2+k];
      float v;
      if (mode) v = 1.0f/(1.0f+__expf(-(U[q]+Vp+bb)));
      else v = val[cb2+k];
      const float* sr = in + (size_t)q*128;
      float4 x0 = ((const float4*)sr)[chn*2];
      float4 x1 = ((const float4*)sr)[chn*2+1];
      a0.x+=v*x0.x; a0.y+=v*x0.y; a0.z+=v*x0.z; a0.w+=v*x0.w;
      a1.x+=v*x1.x; a1.y+=v*x1.y; a1.z+=v*x1.z; a1.w+=v*x1.w;
    }
    red4x2(a0, a1);
    if (sg==0){
      float* dst = outp + (size_t)p*ostride;
      stc2(dst+chn*8,   make_float2(a0.x,a0.y));
      stc2(dst+chn*8+2, make_float2(a0.z,a0.w));
      stc2(dst+chn*8+4, make_float2(a1.x,a1.y));
      stc2(dst+chn*8+6, make_float2(a1.z,a1.w));
    }
  }
  barx(ws, b, 3, 0, 1024, b==0, b, ph, -1, shr); ph++;   // global join: SCAT complete

  // ---- Phase E: projection GEMMs (blocks 0..191), K-tile 16 ----
  if (b < 192){
    const float* S; const float* W; float* outp; int K; int blk;
    if (b<32){       S=ws+W_SCAT+S0_OFF; W=ws+W_WCAT+WC0; outp=out;        K=384; blk=b; }
    else if (b<128){ S=ws+W_SCAT+S1_OFF; W=ws+W_WCAT+WC1; outp=out+131072; K=640; blk=b-32; }
    else {           S=ws+W_SCAT+S2_OFF; W=ws+W_WCAT+WC2; outp=out+524288; K=384; blk=b-128; }
    int r0=blk*32;
    int ty=t>>5, tx=t&31;
    float acc[4][4]={};
    for (int k0=0; k0<K; k0+=16){
      {
        int r=t>>3, kq=(t&7)*2;
        const float* src=S+(size_t)(r0+r)*K + k0+kq;
        Sl[r*17+kq]=src[0]; Sl[r*17+kq+1]=src[1];
      }
      {
        int kk=t>>4, cq=(t&15)*8;
        const float* src=W+(size_t)(k0+kk)*128+cq;
        #pragma unroll
        for(int i=0;i<8;i++) Wl[kk*128+cq+i]=src[i];
      }
      __syncthreads();
      #pragma unroll
      for(int k=0;k<16;k++){
        float sv[4], wvv2[4];
        #pragma unroll
        for(int i=0;i<4;i++) sv[i]=Sl[(ty*4+i)*17+k];
        #pragma unroll
        for(int i=0;i<4;i++) wvv2[i]=Wl[k*128+tx+32*i];
        #pragma unroll
        for(int a2=0;a2<4;a2++)
          #pragma unroll
          for(int b2=0;b2<4;b2++) acc[a2][b2]+=sv[a2]*wvv2[b2];
      }
      __syncthreads();
    }
    #pragma unroll
    for(int a2=0;a2<4;a2++)
      #pragma unroll
      for(int b2=0;b2<4;b2++){
        int r=r0+ty*4+a2, col=tx+32*b2;
        outp[(size_t)r*128+col]=fmaxf(acc[a2][b2],0.f);
      }
  }
}

// ---------------- host ----------------
extern "C" void kernel_launch(void* const* d_in, const int* in_sizes, int n_in,
                              void* d_out, int out_size, void* d_ws, size_t ws_size,
                              hipStream_t stream){
  const float* z0 =(const float*)d_in[0];
  const float* z1 =(const float*)d_in[1];
  const float* z2 =(const float*)d_in[2];
  const float* L0 =(const float*)d_in[3];
  const float* L1d=(const float*)d_in[4];
  const float* L1u=(const float*)d_in[5];
  const float* L2 =(const float*)d_in[6];
  const float* B1 =(const float*)d_in[7];
  const float* B2 =(const float*)d_in[8];
  const float* Wd =(const float*)d_in[9];
  const float* Wu =(const float*)d_in[10];
  const float* Wh =(const float*)d_in[11];
  const float* Wb1=(const float*)d_in[12];
  const float* Wb2=(const float*)d_in[13];
  const float* adw=(const float*)d_in[14];
  const float* adb=(const float*)d_in[15];
  const float* auw=(const float*)d_in[16];
  const float* aub=(const float*)d_in[17];
  float* ws=(float*)d_ws;
  int* wsi=(int*)d_ws;
  float* out=(float*)d_out;

  hipLaunchKernelGGL(k_wprep, dim3(64), dim3(256), 0, stream, Wd,Wu,Wh,Wb1,Wb2,ws);
  hipLaunchKernelGGL(k_count, dim3(3328), dim3(256), 0, stream, L0,L1d,L1u,L2,B1,B2, wsi+W_CNT);
  hipLaunchKernelGGL(k_prefix, dim3(8), dim3(256), 0, stream, wsi+W_CNT, wsi+W_PTR, wsi+W_CUR);
  hipLaunchKernelGGL(k_fill, dim3(3328), dim3(256), 0, stream, L0,L1d,L1u,L2,B1,B2, wsi+W_PTR, wsi+W_CIDX, ws+W_VAL);
  hipLaunchKernelGGL(k_fillT, dim3(1024), dim3(256), 0, stream, ws);
  hipLaunchKernelGGL(k_solve, dim3(1024), dim3(256), 0, stream,
                     ws, z0, z1, z2, adw, adb, auw, aub, out);
}

// Round 14
// 1276.845 us; speedup vs baseline: 1.7599x; 1.0338x over previous
//
#include <hip/hip_runtime.h>
#include <string.h>

// ---------------- problem constants ----------------
constexpr int M_LZ = 64;   // Lanczos steps

// CSR capacity per matrix (expected nnz * ~1.25)
constexpr int CAP_L0 = 26240, CAP_L1 = 118016, CAP_L2 = 52480, CAP_B1 = 39360, CAP_B2 = 78720;
constexpr int CB_L0 = 0;
constexpr int CB_L1D = CB_L0 + CAP_L0;
constexpr int CB_L1U = CB_L1D + CAP_L1;
constexpr int CB_L2  = CB_L1U + CAP_L1;
constexpr int CB_B1  = CB_L2 + CAP_L2;
constexpr int CB_B2  = CB_B1 + CAP_B1;
constexpr int CAP_TOT= CB_B2 + CAP_B2;   // 432832
constexpr int CB_B1T = CAP_TOT;
constexpr int CB_B2T = CB_B1T + CAP_B1;
constexpr int CAP_TOT2 = CB_B2T + CAP_B2; // 550912

// rowptr offsets (ints) within W_PTR region
constexpr int P_L0=0, P_L1D=1025, P_L1U=4098, P_L2=7171, P_B1=9220, P_B2=10245;
constexpr int P_B1T=13320, P_B2T=16393;   // region size 18444
// row-count offsets within W_CNT region
constexpr int C_L0=0, C_L1D=1024, C_L1U=4096, C_L2=7168, C_B1=9216, C_B2=10240;
constexpr int C_B1T=13312, C_B2T=16384;   // region size 18432

constexpr size_t HBUF  = (size_t)6144*128;          // 786432 words

// workspace layout (units: 4-byte words)
constexpr size_t W_CNT = 0;                         // 18432 ints
constexpr size_t W_PTR = 18432;                     // 18444 ints
constexpr size_t W_CUR = W_PTR + 18444;             // 5120 ints
constexpr size_t W_CIDX= W_CUR + 5120;              // CAP_TOT2 ints
constexpr size_t W_VAL = W_CIDX + CAP_TOT2;         // CAP_TOT2 floats
// write-once step-indexed Lanczos vectors: v_0..v_63 then w_0..w_63 (global 6144 rows)
constexpr size_t W_VW  = W_VAL + CAP_TOT2;          // 128*6144 = 786432
// tridiagonal entries: TT[g][j] = (a, g, n), padded to one 128B line each
constexpr size_t W_TT  = W_VW + 786432;             // 3*64*32 = 6144
constexpr size_t W_EPS = W_TT + 6144;               // 4*32 (per-group padded line)
constexpr size_t W_UV  = W_EPS + 128;               // 4*3072 (U_d,V_d,U_u,V_u)
// write-once harmonic buffers: [s][row][128]
constexpr size_t W_H   = W_UV + 4*3072;             // 15*HBUF
constexpr size_t W_SCAT= W_H + 15*HBUF;
constexpr size_t S0_OFF= 0;                          // 1024 x 384
constexpr size_t S1_OFF= (size_t)1024*384;           // 3072 x 640
constexpr size_t S2_OFF= S1_OFF + (size_t)3072*640;  // 2048 x 384
constexpr size_t SCAT_TOT = S2_OFF + (size_t)2048*384;
constexpr size_t W_WCAT= W_SCAT + SCAT_TOT;          // 1408*128 concatenated weights
constexpr size_t WC0=0, WC1=(size_t)384*128, WC2=WC1+(size_t)640*128;
// per-block dot partial slots, step-indexed (write-once): [j][b] -> 8 floats (32B)
constexpr size_t W_SLOT= W_WCAT + (size_t)1408*128;  // 64*2048*8 = 1048576
// per-block arrival flags (monotonic phase counters), padded 128B each
constexpr size_t W_FLG = W_SLOT + 1048576;           // 2048*32 = 65536
// release copies: 4 groups x 16 leaves, padded 128B each
constexpr size_t W_REL = W_FLG + 65536;              // 2048

__device__ __forceinline__ float wredf(float v){
  #pragma unroll
  for(int o=32;o;o>>=1) v += __shfl_xor(v,o,64);
  return v;
}
__device__ __forceinline__ int wredi(int v){
  #pragma unroll
  for(int o=32;o;o>>=1) v += __shfl_xor(v,o,64);
  return v;
}
// fold 4 nnz-subgroups (lanes l, l^16, l^32, l^48) for 8 accumulator comps
__device__ __forceinline__ void red4x2(float4& a0, float4& a1){
  #pragma unroll
  for (int o=16;o<=32;o<<=1){
    a0.x+=__shfl_xor(a0.x,o,64); a0.y+=__shfl_xor(a0.y,o,64);
    a0.z+=__shfl_xor(a0.z,o,64); a0.w+=__shfl_xor(a0.w,o,64);
    a1.x+=__shfl_xor(a1.x,o,64); a1.y+=__shfl_xor(a1.y,o,64);
    a1.z+=__shfl_xor(a1.z,o,64); a1.w+=__shfl_xor(a1.w,o,64);
  }
}

// agent-scope (L2-bypassing) ops
__device__ __forceinline__ float ldc(const float* p){
  return __hip_atomic_load(p, __ATOMIC_RELAXED, __HIP_MEMORY_SCOPE_AGENT);
}
__device__ __forceinline__ float2 ldc2(const float* p){
  unsigned long long u = __hip_atomic_load((const unsigned long long*)p,
                          __ATOMIC_RELAXED, __HIP_MEMORY_SCOPE_AGENT);
  float2 r; memcpy(&r,&u,8); return r;
}
__device__ __forceinline__ void stc(float* p, float v){
  __hip_atomic_store(p, v, __ATOMIC_RELAXED, __HIP_MEMORY_SCOPE_AGENT);
}
__device__ __forceinline__ void stc2(float* p, float2 v){
  unsigned long long u; memcpy(&u,&v,8);
  __hip_atomic_store((unsigned long long*)p, u, __ATOMIC_RELAXED, __HIP_MEMORY_SCOPE_AGENT);
}
__device__ __forceinline__ int ldci(const int* p){
  return __hip_atomic_load(p, __ATOMIC_RELAXED, __HIP_MEMORY_SCOPE_AGENT);
}
__device__ __forceinline__ void stci(int* p, int v){
  __hip_atomic_store(p, v, __ATOMIC_RELAXED, __HIP_MEMORY_SCOPE_AGENT);
}

// ---- flag-array barrier: NO same-address RMW anywhere ----
__device__ __forceinline__ void barx(float* ws, int b, int grp, int lbase, int Ng,
                                     bool chk, int lb, int ph, int jslot, float* shr){
  const int t = threadIdx.x, lane = t&63, wvv = t>>6;
  int* flg = (int*)ws + W_FLG;
  int* rel = (int*)ws + W_REL;
  __builtin_amdgcn_s_waitcnt(0);   // every thread drains its stores
  __syncthreads();
  if (t==0) stci(flg + (size_t)b*32, ph+1);
  if (chk){
    for (int s=t; s<Ng; s+=256){
      const int* f = flg + (size_t)(lbase+s)*32;
      while (ldci(f) < ph+1) __builtin_amdgcn_s_sleep(1);
    }
    if (jslot>=0){
      float pa=0.f, pg=0.f, pn=0.f;
      for (int s=t; s<Ng; s+=256){
        const float* sl = ws + W_SLOT + ((size_t)jslot*2048 + lbase+s)*8;
        float2 ag = ldc2(sl); float nn = ldc(sl+2);
        pa+=ag.x; pg+=ag.y; pn+=nn;
      }
      pa=wredf(pa); pg=wredf(pg); pn=wredf(pn);
      if (lane==0){ shr[0*4+wvv]=pa; shr[1*4+wvv]=pg; shr[2*4+wvv]=pn; }
    }
    __syncthreads();
    if (t==0){
      if (jslot>=0){
        float a=shr[0]+shr[1]+shr[2]+shr[3];
        float g=shr[4]+shr[5]+shr[6]+shr[7];
        float n=shr[8]+shr[9]+shr[10]+shr[11];
        float* TT = ws + W_TT + (size_t)(grp*64 + jslot)*32;
        stc2(TT, make_float2(a,g)); stc(TT+2, n);
        __builtin_amdgcn_s_waitcnt(0);   // TT visible before release
      }
      #pragma unroll
      for (int i=0;i<16;i++) stci(rel + (size_t)(grp*16+i)*32, ph+1);
    }
    __syncthreads();
  } else {
    if (t==0){
      const int* r = rel + (size_t)(grp*16 + (lb&15))*32;
      while (ldci(r) < ph+1) __builtin_amdgcn_s_sleep(1);
    }
    __syncthreads();
  }
}

// ---------------- weight prep + zeroing of counters/flags ----------------
__global__ void k_wprep(const float* Wd,const float* Wu,const float* Wh,
                        const float* Wb1,const float* Wb2, float* ws){
  int t = blockIdx.x*256 + threadIdx.x;
  if (t >= 16384) return;
  int* wsi = (int*)ws;
  if (t < 5120) wsi[W_CNT + 13312 + t] = 0;          // transpose col counters
  if (t < 5120) wsi[W_CUR + t] = 0;                  // cursors
  for (int i=t; i<65536+2048; i+=16384) wsi[W_FLG+i] = 0;  // flags + releases
  float sd = Wd[t]  + Wd[16384+t]  + Wd[32768+t];
  float su = Wu[t]  + Wu[16384+t]  + Wu[32768+t];
  float s1 = Wb1[t] + Wb1[16384+t] + Wb1[32768+t];
  float s2 = Wb2[t] + Wb2[16384+t] + Wb2[32768+t];
  float wh = Wh[t];
  float* W0 = ws + W_WCAT + WC0;
  float* W1 = ws + W_WCAT + WC1;
  float* W2 = ws + W_WCAT + WC2;
  W0[t]=sd; W0[16384+t]=s1; W0[32768+t]=wh;
  W1[t]=sd; W1[16384+t]=su; W1[32768+t]=s1; W1[49152+t]=s2; W1[65536+t]=wh;
  W2[t]=su; W2[16384+t]=s2; W2[32768+t]=wh;
}

// ---------------- CSR extraction (proven) ----------------
__device__ __forceinline__ void mat_meta(int wid, const float* L0,const float* L1d,const float* L1u,
    const float* L2,const float* B1,const float* B2,
    const float*& M,int& ncol,int& lrow,int& co,int& po,int& cb,int& cap,int& tco){
  if (wid < 1024){ M=L0;  ncol=1024; lrow=wid;        co=C_L0;  po=P_L0;  cb=CB_L0;  cap=CAP_L0; tco=-1; }
  else if (wid < 4096){ M=L1d; ncol=3072; lrow=wid-1024;  co=C_L1D; po=P_L1D; cb=CB_L1D; cap=CAP_L1; tco=-1; }
  else if (wid < 7168){ M=L1u; ncol=3072; lrow=wid-4096;  co=C_L1U; po=P_L1U; cb=CB_L1U; cap=CAP_L1; tco=-1; }
  else if (wid < 9216){ M=L2;  ncol=2048; lrow=wid-7168;  co=C_L2;  po=P_L2;  cb=CB_L2;  cap=CAP_L2; tco=-1; }
  else if (wid < 10240){ M=B1; ncol=3072; lrow=wid-9216;  co=C_B1;  po=P_B1;  cb=CB_B1;  cap=CAP_B1; tco=C_B1T; }
  else { M=B2; ncol=2048; lrow=wid-10240; co=C_B2;  po=P_B2;  cb=CB_B2;  cap=CAP_B2; tco=C_B2T; }
}

__global__ void k_count(const float* L0,const float* L1d,const float* L1u,const float* L2,
                        const float* B1,const float* B2,int* cnt){
  int wid = blockIdx.x*4 + (threadIdx.x>>6);
  int lane = threadIdx.x & 63;
  if (wid >= 13312) return;
  const float* M; int ncol,lrow,co,po,cb,cap,tco;
  mat_meta(wid,L0,L1d,L1u,L2,B1,B2,M,ncol,lrow,co,po,cb,cap,tco);
  const float4* row4 = (const float4*)(M + (size_t)lrow*ncol);
  int c = 0;
  for (int j0=0; j0<ncol; j0+=256){
    float4 v = row4[(j0>>2)+lane];
    int n0=v.x!=0.f, n1=v.y!=0.f, n2=v.z!=0.f, n3=v.w!=0.f;
    c += n0+n1+n2+n3;
    if (tco>=0){
      int jb = j0 + lane*4;
      if (n0) atomicAdd(cnt+tco+jb,   1);
      if (n1) atomicAdd(cnt+tco+jb+1, 1);
      if (n2) atomicAdd(cnt+tco+jb+2, 1);
      if (n3) atomicAdd(cnt+tco+jb+3, 1);
    }
  }
  c = wredi(c);
  if (lane==0) cnt[co+lrow] = c;
}

__global__ void k_prefix(const int* cnt, int* ptr, int* cur){
  __shared__ int lds[257];
  const int rows[8]={1024,3072,3072,2048,1024,3072,3072,2048};
  const int cofs[8]={C_L0,C_L1D,C_L1U,C_L2,C_B1,C_B2,C_B1T,C_B2T};
  const int pofs[8]={P_L0,P_L1D,P_L1U,P_L2,P_B1,P_B2,P_B1T,P_B2T};
  int b=blockIdx.x, t=threadIdx.x;
  int R=rows[b]; const int* c=cnt+cofs[b]; int* p=ptr+pofs[b];
  int* cc = (b==6)? cur : (b==7)? cur+3072 : nullptr;
  int chunk=(R+255)/256;
  int lo=t*chunk, hi=min(R,lo+chunk);
  int s=0;
  for(int i=lo;i<hi;i++) s+=c[i];
  lds[t]=s; __syncthreads();
  if(t==0){ int run=0; for(int i=0;i<256;i++){int x=lds[i];lds[i]=run;run+=x;} lds[256]=run; }
  __syncthreads();
  int run=lds[t];
  for(int i=lo;i<hi;i++){ p[i]=run; if(cc) cc[i]=run; run+=c[i]; }
  if(t==0) p[R]=lds[256];
}

__global__ void k_fill(const float* L0,const float* L1d,const float* L1u,const float* L2,
                       const float* B1,const float* B2,const int* ptr,int* cidx,float* val){
  int wid = blockIdx.x*4 + (threadIdx.x>>6);
  int lane = threadIdx.x & 63;
  if (wid >= 13312) return;
  const float* M; int ncol,lrow,co,po,cb,cap,tco;
  mat_meta(wid,L0,L1d,L1u,L2,B1,B2,M,ncol,lrow,co,po,cb,cap,tco);
  const float4* row4 = (const float4*)(M + (size_t)lrow*ncol);
  int base = ptr[po+lrow];
  int run = 0;
  for (int j0=0; j0<ncol; j0+=256){
    float4 v = row4[(j0>>2)+lane];
    int n0=v.x!=0.f, n1=v.y!=0.f, n2=v.z!=0.f, n3=v.w!=0.f;
    int local = n0+n1+n2+n3;
    int incl = local;
    #pragma unroll
    for (int o=1;o<64;o<<=1){
      int tmp = __shfl_up(incl,o,64);
      if (lane>=o) incl += tmp;
    }
    int tot = __shfl(incl,63,64);
    int pos = base + run + incl - local;
    int jb = j0 + lane*4;
    if (n0){ if(pos<cap){cidx[cb+pos]=jb;   val[cb+pos]=v.x;} pos++; }
    if (n1){ if(pos<cap){cidx[cb+pos]=jb+1; val[cb+pos]=v.y;} pos++; }
    if (n2){ if(pos<cap){cidx[cb+pos]=jb+2; val[cb+pos]=v.z;} pos++; }
    if (n3){ if(pos<cap){cidx[cb+pos]=jb+3; val[cb+pos]=v.w;} pos++; }
    run += tot;
  }
}

__global__ void k_fillT(float* ws){
  int wid = blockIdx.x*4 + (threadIdx.x>>6);
  int lane = threadIdx.x & 63;
  if (wid >= 4096) return;
  int* wsi=(int*)ws;
  const int* ptr=wsi+W_PTR; int* cidx=wsi+W_CIDX; float* val=ws+W_VAL;
  int* cur=wsi+W_CUR;
  if (wid < 1024){
    int r=wid;
    int e=ptr[P_B1+r+1];
    for(int k=ptr[P_B1+r]+lane;k<e;k+=64){
      int c=cidx[CB_B1+k]; float v=val[CB_B1+k];
      int pos=atomicAdd(cur+c,1);
      cidx[CB_B1T+pos]=r; val[CB_B1T+pos]=v;
    }
  } else {
    int r=wid-1024;
    int e=ptr[P_B2+r+1];
    for(int k=ptr[P_B2+r]+lane;k<e;k+=64){
      int c=cidx[CB_B2+k]; float v=val[CB_B2+k];
      int pos=atomicAdd(cur+3072+c,1);
      cidx[CB_B2T+pos]=r; val[CB_B2T+pos]=v;
    }
  }
}

// ================= FUSED PERSISTENT SOLVER =================
// 2048 blocks x 256 threads, 8 blocks/CU (2048 thr/CU = HW max) -> 32 waves/CU.
// Groups by nnz: g0 [0,160), g1 [160,1696), g2 [1696,2048).
// Each block owns 2 row-slots; each row gets TWO waves (nnz split mod 2),
// giving 8-way nnz parallelism with the in-wave 4-subgroup split. LDS combine.
__global__ __launch_bounds__(256,8) void k_solve(float* ws,
    const float* z0,const float* z1,const float* z2,
    const float* adw,const float* adb,const float* auw,const float* aub,
    float* out){
  const int b = blockIdx.x, t = threadIdx.x;
  const int wv = t>>6, lane = t&63;
  const int rr = wv>>1, sw = wv&1;         // row-slot within block, sub-wave
  const int sg = lane>>4, chn = lane&15;   // in-wave nnz-subgroup, channel-16th
  const int* wsi=(const int*)ws;
  const int* ptr=wsi+W_PTR; const int* cidx=wsi+W_CIDX; const float* val=ws+W_VAL;

  __shared__ float smem[2616];             // 10464 B
  float* Sl  = smem;                       // [544]   phase E
  float* Wl  = smem + 544;                 // [2048]  phase E
  float* hbuf= smem;                       // [512]   harm combine (alias)
  float* lzr = smem;                       // [4]     lz combine (alias)
  float* TTa = smem;                       // [64]    eig (alias)
  float* TTb = smem + 64;                  // [64]
  float* redm= smem + 2592;                // [12]
  float* shr = smem + 2604;                // [12]    barrier payload scratch

  // group mapping (block counts proportional to nnz; all divisible by 16)
  int g, nb, crows, bbase, Ng, lb;
  if (b<160){ g=0; lb=b;        nb=0;    crows=1024; bbase=0;    Ng=160;  }
  else if (b<1696){ g=1; lb=b-160;  nb=1024; crows=3072; bbase=160;  Ng=1536; }
  else { g=2; lb=b-1696; nb=4096; crows=2048; bbase=1696; Ng=352;  }
  const int RS = Ng*2;                               // row-slots per group
  const int niter = (crows + RS - 1)/RS;             // group-uniform
  const bool chk = (b==bbase);
  const float* zc = (g==0)?z0:(g==1)?z1:z2;
  int ph = 0;

  // ---- Phase A: v_0 init + attention U,V ----
  { int i = b*256+t;
    if (i < 6144){
      float invs = (i<1024)?0.03125f:(i<4096)?0.0180421959f:0.0220970869f;
      unsigned uu=(unsigned)i*2654435761u; uu^=uu>>16; uu*=2246822519u; uu^=uu>>13;
      stc(ws+W_VW+i, (uu&1)?invs:-invs);     // v_0
    }
  }
  { int gw = b*4+wv;
    if (gw < 3072){
      float2 x  = ((const float2*)(z1+(size_t)gw*128))[lane];
      float2 a0 = ((const float2*)adw)[lane];
      float2 a1 = ((const float2*)adw)[64+lane];
      float2 b0 = ((const float2*)auw)[lane];
      float2 b1 = ((const float2*)auw)[64+lane];
      float ud=x.x*a0.x+x.y*a0.y, vd=x.x*a1.x+x.y*a1.y;
      float uu=x.x*b0.x+x.y*b0.y, vu=x.x*b1.x+x.y*b1.y;
      ud=wredf(ud); vd=wredf(vd); uu=wredf(uu); vu=wredf(vu);
      if(lane==0){ stc(ws+W_UV+gw,ud); stc(ws+W_UV+3072+gw,vd);
                   stc(ws+W_UV+6144+gw,uu); stc(ws+W_UV+9216+gw,vu); }
    }
  }
  barx(ws, b, 3, 0, 2048, b==0, b, ph, -1, shr); ph++;   // global: v_0, UV visible

  // ---- Phase B: M_LZ Lanczos steps (2 waves per row, LDS combine) ----
  for (int j=0;j<M_LZ;j++){
    float a, gmm, ib;
    if (j==0){ a=0.f; gmm=0.f; ib=1.f; }
    else {
      const float* TT = ws + W_TT + (size_t)(g*64 + (j-1))*32;
      a = TT[0]; gmm = TT[1]; float n = TT[2];
      ib = 1.f/sqrtf(fmaxf(n - a*a - gmm*gmm, 1e-20f));
    }
    const float* vj   = ws + W_VW + (size_t)j*6144;
    const float* vm1  = ws + W_VW + (size_t)(j>0? j-1:0)*6144;
    const float* vm2  = ws + W_VW + (size_t)(j>1? j-2:0)*6144;
    const float* wpv  = ws + W_VW + (size_t)(64 + (j>0? j-1:0))*6144;
    float* vjw        = ws + W_VW + (size_t)j*6144;
    float* wjw        = ws + W_VW + (size_t)(64+j)*6144;
    float Aa=0.f, Gg=0.f, Nn=0.f;
    for (int it=0; it<niter; it++){
      int p = lb*2 + rr + it*RS;
      bool act = (p < crows);
      float wp=0.f;
      if (act){
        #define GATHER(PP,CBB) { \
          const int* rp = ptr + PP; int e=rp[p+1]; \
          for (int k=rp[p]+sw*64+lane; k<e; k+=128){ \
            int q = nb + cidx[CBB+k]; float v = val[CBB+k]; \
            float vq = (j==0)? vj[q] : (wpv[q] - a*vm1[q] - gmm*vm2[q])*ib; \
            wp += v*vq; \
          } }
        if (g==0){ GATHER(P_L0, CB_L0) }
        else if (g==1){ GATHER(P_L1D, CB_L1D) GATHER(P_L1U, CB_L1U) }
        else { GATHER(P_L2, CB_L2) }
        #undef GATHER
        wp = wredf(wp);
      }
      if (lane==0) lzr[rr*2+sw] = wp;
      __syncthreads();
      if (act && sw==0 && lane==0){
        float wtot = lzr[rr*2] + lzr[rr*2+1];
        int gp = nb + p;
        float vp, vm1p;
        if (j==0){ vp = vj[gp]; vm1p = 0.f; }
        else { vp = (wpv[gp] - a*vm1[gp] - gmm*vm2[gp])*ib; stc(vjw+gp, vp); vm1p = vm1[gp]; }
        stc(wjw+gp, wtot);
        Aa += vp*wtot; Gg += vm1p*wtot; Nn += wtot*wtot;
      }
      __syncthreads();
    }
    if (sw==0 && lane==0){ redm[rr*3+0]=Aa; redm[rr*3+1]=Gg; redm[rr*3+2]=Nn; }
    __syncthreads();
    if (t==0){
      float* sl2 = ws + W_SLOT + ((size_t)j*2048 + b)*8;
      stc2(sl2, make_float2(redm[0]+redm[3], redm[1]+redm[4]));
      stc(sl2+2, redm[2]+redm[5]);
    }
    barx(ws, b, g, bbase, Ng, chk, lb, ph, j, shr); ph++;
  }

  // ---- eig: one wave of each group's checker block ----
  if (chk && t<64){
    int i = t;
    { const float* TT = ws + W_TT + (size_t)(g*64 + i)*32;
      float a=TT[0], gg=TT[1], n=TT[2];
      TTa[i]=a; TTb[i]=sqrtf(fmaxf(n-a*a-gg*gg,1e-20f));
    }
    double lo, hi;
    { double r=(i? fabs((double)TTb[i-1]):0.0) + (i<M_LZ-1? fabs((double)TTb[i]):0.0);
      lo=(double)TTa[i]-r; hi=(double)TTa[i]+r; }
    #pragma unroll
    for(int o=32;o;o>>=1){ lo=fmin(lo,__shfl_xor(lo,o,64)); hi=fmax(hi,__shfl_xor(hi,o,64)); }
    lo -= 1.0; hi += 1.0;
    for (int round=0; round<4; round++){
      double x = lo + (hi-lo)*(double)(i+1)/65.0;
      double d = 1.0; int cnt2=0;
      for (int k2=0;k2<M_LZ;k2++){
        double bi = k2? (double)TTb[k2-1] : 0.0;
        d = ((double)TTa[k2]-x) - bi*bi/d;
        if (d==0.0) d = -1e-300;
        if (d<0.0) cnt2++;
      }
      double nlo = (cnt2< M_LZ)? x : -1e300;
      double nhi = (cnt2==M_LZ)? x :  1e300;
      #pragma unroll
      for(int o=32;o;o>>=1){ nlo=fmax(nlo,__shfl_xor(nlo,o,64)); nhi=fmin(nhi,__shfl_xor(nhi,o,64)); }
      if (nlo>-1e299) lo=nlo;
      if (nhi< 1e299) hi=nhi;
    }
    double lam = 0.5*(lo+hi);
    if (i==0) stc(ws+W_EPS+(size_t)g*32, (lam>0.0)? (float)(1.0/lam) : 0.1f);
  }
  barx(ws, b, g, bbase, Ng, chk, lb, ph, -1, shr); ph++;   // eps visible within group

  // ---- Phase D: 16 harmonic steps (8-way nnz-parallel: 2 waves x 4 subgroups) ----
  {
    float eps = ws[W_EPS+(size_t)g*32];
    for (int s=0;s<16;s++){
      const float* inH = ws + W_H + (size_t)(s>0? s-1:0)*HBUF;
      for (int it=0; it<niter; it++){
        int p = lb*2 + rr + it*RS;
        bool act = (p < crows);
        float4 a0={0.f,0.f,0.f,0.f}, a1={0.f,0.f,0.f,0.f};
        if (act){
          int u = sw*4 + sg;
          #define HG(PP,CBB) { \
            const int* rp=ptr+PP; int e=rp[p+1]; \
            for(int k=rp[p]+u;k<e;k+=8){ \
              float v=val[CBB+k]; int q=cidx[CBB+k]; \
              const float* sr = (s==0)? zc+(size_t)q*128 : inH+(size_t)(nb+q)*128; \
              float4 x0 = ((const float4*)sr)[chn*2]; \
              float4 x1 = ((const float4*)sr)[chn*2+1]; \
              a0.x+=v*x0.x; a0.y+=v*x0.y; a0.z+=v*x0.z; a0.w+=v*x0.w; \
              a1.x+=v*x1.x; a1.y+=v*x1.y; a1.z+=v*x1.z; a1.w+=v*x1.w; \
            } }
          if (g==0){ HG(P_L0, CB_L0) }
          else if (g==1){ HG(P_L1D, CB_L1D) HG(P_L1U, CB_L1U) }
          else { HG(P_L2, CB_L2) }
          #undef HG
          red4x2(a0, a1);
        }
        if (sg==0){
          float* hb = hbuf + (size_t)(rr*2+sw)*128 + chn*8;
          hb[0]=a0.x; hb[1]=a0.y; hb[2]=a0.z; hb[3]=a0.w;
          hb[4]=a1.x; hb[5]=a1.y; hb[6]=a1.z; hb[7]=a1.w;
        }
        __syncthreads();
        if (act && sw==0){
          const float* h0 = hbuf + (size_t)(rr*2)*128;
          const float* h1 = hbuf + (size_t)(rr*2+1)*128;
          float sx = h0[2*lane]   + h1[2*lane];
          float sy = h0[2*lane+1] + h1[2*lane+1];
          int gp = nb + p;
          float2 own;
          if (s==0) own = ((const float2*)(zc + (size_t)p*128))[lane];
          else      own = ((const float2*)(inH + (size_t)gp*128))[lane];
          float2 r2 = make_float2(own.x - eps*sx, own.y - eps*sy);
          float* dst;
          if (s<15) dst = ws + W_H + (size_t)s*HBUF + (size_t)gp*128;
          else {
            float* outp; size_t ostride;
            if(g==0){ outp=ws+W_SCAT+S0_OFF+256; ostride=384; }
            else if(g==1){ outp=ws+W_SCAT+S1_OFF+512; ostride=640; }
            else { outp=ws+W_SCAT+S2_OFF+256; ostride=384; }
            dst = outp + (size_t)p*ostride;
          }
          stc2(dst + 2*lane, r2);
        }
        __syncthreads();
      }
      if (s<15){ barx(ws, b, g, bbase, Ng, chk, lb, ph, -1, shr); ph++; }
    }
  }

  // ---- Phase C: forward SpMMs (all blocks; 4-way nnz-parallel, stride 8192) ----
  for (int wid2 = b*4+wv; wid2 < 18432; wid2 += 8192){
    int task,p;
    if(wid2<1024){task=0;p=wid2;}
    else if(wid2<2048){task=1;p=wid2-1024;}
    else if(wid2<5120){task=2;p=wid2-2048;}
    else if(wid2<8192){task=3;p=wid2-5120;}
    else if(wid2<11264){task=4;p=wid2-8192;}
    else if(wid2<13312){task=5;p=wid2-11264;}
    else if(wid2<16384){task=6;p=wid2-13312;}
    else {task=7;p=wid2-16384;}
    const float* in; const int* rp; int cb2; float* outp; int ostride;
    int mode=0; float Vp=0.f, bb=0.f; const float* U=nullptr;
    switch(task){
      case 0: rp=ptr+P_L0;  cb2=CB_L0;  in=z0; outp=ws+W_SCAT+S0_OFF+0;   ostride=384; break;
      case 1: rp=ptr+P_B1;  cb2=CB_B1;  in=z1; outp=ws+W_SCAT+S0_OFF+128; ostride=384; break;
      case 2: rp=ptr+P_L1D; cb2=CB_L1D; in=z1; outp=ws+W_SCAT+S1_OFF+0;   ostride=640;
              mode=1; U=ws+W_UV; Vp=ws[W_UV+3072+p]; bb=adb[0]; break;
      case 3: rp=ptr+P_L1U; cb2=CB_L1U; in=z1; outp=ws+W_SCAT+S1_OFF+128; ostride=640;
              mode=1; U=ws+W_UV+6144; Vp=ws[W_UV+9216+p]; bb=aub[0]; break;
      case 4: rp=ptr+P_B2;  cb2=CB_B2;  in=z2; outp=ws+W_SCAT+S1_OFF+384; ostride=640; break;
      case 5: rp=ptr+P_L2;  cb2=CB_L2;  in=z2; outp=ws+W_SCAT+S2_OFF+0;   ostride=384; break;
      case 6: rp=ptr+P_B1T; cb2=CB_B1T; in=z0; outp=ws+W_SCAT+S1_OFF+256; ostride=640; break;
      default:rp=ptr+P_B2T; cb2=CB_B2T; in=z1; outp=ws+W_SCAT+S2_OFF+128; ostride=384; break;
    }
    float4 a0={0.f,0.f,0.f,0.f}, a1={0.f,0.f,0.f,0.f};
    int e=rp[p+1];
    for (int k=rp[p]+sg; k<e; k+=4){
      int q = cidx[cb2+k];
      float v;
      if (mode) v = 1.0f/(1.0f+__expf(-(U[q]+Vp+bb)));
      else v = val[cb2+k];
      const float* sr = in + (size_t)q*128;
      float4 x0 = ((const float4*)sr)[chn*2];
      float4 x1 = ((const float4*)sr)[chn*2+1];
      a0.x+=v*x0.x; a0.y+=v*x0.y; a0.z+=v*x0.z; a0.w+=v*x0.w;
      a1.x+=v*x1.x; a1.y+=v*x1.y; a1.z+=v*x1.z; a1.w+=v*x1.w;
    }
    red4x2(a0, a1);
    if (sg==0){
      float* dst = outp + (size_t)p*ostride;
      stc2(dst+chn*8,   make_float2(a0.x,a0.y));
      stc2(dst+chn*8+2, make_float2(a0.z,a0.w));
      stc2(dst+chn*8+4, make_float2(a1.x,a1.y));
      stc2(dst+chn*8+6, make_float2(a1.z,a1.w));
    }
  }
  barx(ws, b, 3, 0, 2048, b==0, b, ph, -1, shr); ph++;   // global join: SCAT complete

  // ---- Phase E: projection GEMMs (blocks 0..191), K-tile 16 ----
  if (b < 192){
    const float* S; const float* W; float* outp; int K; int blk;
    if (b<32){       S=ws+W_SCAT+S0_OFF; W=ws+W_WCAT+WC0; outp=out;        K=384; blk=b; }
    else if (b<128){ S=ws+W_SCAT+S1_OFF; W=ws+W_WCAT+WC1; outp=out+131072; K=640; blk=b-32; }
    else {           S=ws+W_SCAT+S2_OFF; W=ws+W_WCAT+WC2; outp=out+524288; K=384; blk=b-128; }
    int r0=blk*32;
    int ty=t>>5, tx=t&31;
    float acc[4][4]={};
    for (int k0=0; k0<K; k0+=16){
      {
        int r=t>>3, kq=(t&7)*2;
        const float* src=S+(size_t)(r0+r)*K + k0+kq;
        Sl[r*17+kq]=src[0]; Sl[r*17+kq+1]=src[1];
      }
      {
        int kk=t>>4, cq=(t&15)*8;
        const float* src=W+(size_t)(k0+kk)*128+cq;
        #pragma unroll
        for(int i=0;i<8;i++) Wl[kk*128+cq+i]=src[i];
      }
      __syncthreads();
      #pragma unroll
      for(int k=0;k<16;k++){
        float sv[4], wvv2[4];
        #pragma unroll
        for(int i=0;i<4;i++) sv[i]=Sl[(ty*4+i)*17+k];
        #pragma unroll
        for(int i=0;i<4;i++) wvv2[i]=Wl[k*128+tx+32*i];
        #pragma unroll
        for(int a2=0;a2<4;a2++)
          #pragma unroll
          for(int b2=0;b2<4;b2++) acc[a2][b2]+=sv[a2]*wvv2[b2];
      }
      __syncthreads();
    }
    #pragma unroll
    for(int a2=0;a2<4;a2++)
      #pragma unroll
      for(int b2=0;b2<4;b2++){
        int r=r0+ty*4+a2, col=tx+32*b2;
        outp[(size_t)r*128+col]=fmaxf(acc[a2][b2],0.f);
      }
  }
}

// ---------------- host ----------------
extern "C" void kernel_launch(void* const* d_in, const int* in_sizes, int n_in,
                              void* d_out, int out_size, void* d_ws, size_t ws_size,
                              hipStream_t stream){
  const float* z0 =(const float*)d_in[0];
  const float* z1 =(const float*)d_in[1];
  const float* z2 =(const float*)d_in[2];
  const float* L0 =(const float*)d_in[3];
  const float* L1d=(const float*)d_in[4];
  const float* L1u=(const float*)d_in[5];
  const float* L2 =(const float*)d_in[6];
  const float* B1 =(const float*)d_in[7];
  const float* B2 =(const float*)d_in[8];
  const float* Wd =(const float*)d_in[9];
  const float* Wu =(const float*)d_in[10];
  const float* Wh =(const float*)d_in[11];
  const float* Wb1=(const float*)d_in[12];
  const float* Wb2=(const float*)d_in[13];
  const float* adw=(const float*)d_in[14];
  const float* adb=(const float*)d_in[15];
  const float* auw=(const float*)d_in[16];
  const float* aub=(const float*)d_in[17];
  float* ws=(float*)d_ws;
  int* wsi=(int*)d_ws;
  float* out=(float*)d_out;

  hipLaunchKernelGGL(k_wprep, dim3(64), dim3(256), 0, stream, Wd,Wu,Wh,Wb1,Wb2,ws);
  hipLaunchKernelGGL(k_count, dim3(3328), dim3(256), 0, stream, L0,L1d,L1u,L2,B1,B2, wsi+W_CNT);
  hipLaunchKernelGGL(k_prefix, dim3(8), dim3(256), 0, stream, wsi+W_CNT, wsi+W_PTR, wsi+W_CUR);
  hipLaunchKernelGGL(k_fill, dim3(3328), dim3(256), 0, stream, L0,L1d,L1u,L2,B1,B2, wsi+W_PTR, wsi+W_CIDX, ws+W_VAL);
  hipLaunchKernelGGL(k_fillT, dim3(1024), dim3(256), 0, stream, ws);
  hipLaunchKernelGGL(k_solve, dim3(2048), dim3(256), 0, stream,
                     ws, z0, z1, z2, adw, adb, auw, aub, out);
}

// Round 15
// 1263.722 us; speedup vs baseline: 1.7782x; 1.0104x over previous
//
#include <hip/hip_runtime.h>
#include <string.h>

// ---------------- problem constants ----------------
constexpr int M_LZ = 64;   // Lanczos steps

// CSR capacity per matrix (expected nnz * ~1.25)
constexpr int CAP_L0 = 26240, CAP_L1 = 118016, CAP_L2 = 52480, CAP_B1 = 39360, CAP_B2 = 78720;
constexpr int CB_L0 = 0;
constexpr int CB_L1D = CB_L0 + CAP_L0;
constexpr int CB_L1U = CB_L1D + CAP_L1;
constexpr int CB_L2  = CB_L1U + CAP_L1;
constexpr int CB_B1  = CB_L2 + CAP_L2;
constexpr int CB_B2  = CB_B1 + CAP_B1;
constexpr int CAP_TOT= CB_B2 + CAP_B2;   // 432832
constexpr int CB_B1T = CAP_TOT;
constexpr int CB_B2T = CB_B1T + CAP_B1;
constexpr int CAP_TOT2 = CB_B2T + CAP_B2; // 550912

// rowptr offsets (ints) within W_PTR region
constexpr int P_L0=0, P_L1D=1025, P_L1U=4098, P_L2=7171, P_B1=9220, P_B2=10245;
constexpr int P_B1T=13320, P_B2T=16393;   // region size 18444
// row-count offsets within W_CNT region
constexpr int C_L0=0, C_L1D=1024, C_L1U=4096, C_L2=7168, C_B1=9216, C_B2=10240;
constexpr int C_B1T=13312, C_B2T=16384;   // region size 18432

constexpr size_t HBUF  = (size_t)6144*128;          // 786432 words

// workspace layout (units: 4-byte words)
constexpr size_t W_CNT = 0;                         // 18432 ints
constexpr size_t W_PTR = 18432;                     // 18444 ints
constexpr size_t W_CUR = W_PTR + 18444;             // 5120 ints
constexpr size_t W_CIDX= W_CUR + 5120;              // CAP_TOT2 ints
constexpr size_t W_VAL = W_CIDX + CAP_TOT2;         // CAP_TOT2 floats
// write-once step-indexed Lanczos vectors: v_0..v_63 then w_0..w_63 (global 6144 rows)
constexpr size_t W_VW  = W_VAL + CAP_TOT2;          // 128*6144 = 786432
// tridiagonal entries: TT[g][j] = (a, g, n), padded to one 128B line each
constexpr size_t W_TT  = W_VW + 786432;             // 3*64*32 = 6144
constexpr size_t W_EPS = W_TT + 6144;               // 4*32 (per-group padded line)
constexpr size_t W_UV  = W_EPS + 128;               // 4*3072 (U_d,V_d,U_u,V_u)
// write-once harmonic buffers: [s][row][128]
constexpr size_t W_H   = W_UV + 4*3072;             // 15*HBUF
constexpr size_t W_SCAT= W_H + 15*HBUF;
constexpr size_t S0_OFF= 0;                          // 1024 x 384
constexpr size_t S1_OFF= (size_t)1024*384;           // 3072 x 640
constexpr size_t S2_OFF= S1_OFF + (size_t)3072*640;  // 2048 x 384
constexpr size_t SCAT_TOT = S2_OFF + (size_t)2048*384;
constexpr size_t W_WCAT= W_SCAT + SCAT_TOT;          // 1408*128 concatenated weights
constexpr size_t WC0=0, WC1=(size_t)384*128, WC2=WC1+(size_t)640*128;
// per-block dot partial slots, step-indexed (write-once): [j][b] -> 8 floats (32B)
constexpr size_t W_SLOT= W_WCAT + (size_t)1408*128;  // 64*2048*8 = 1048576
// per-block arrival flags (monotonic phase counters), padded 128B each
constexpr size_t W_FLG = W_SLOT + 1048576;           // 2048*32 = 65536
// release copies: 4 groups x 16 leaves, padded 128B each
constexpr size_t W_REL = W_FLG + 65536;              // 2048

__device__ __forceinline__ float wredf(float v){
  #pragma unroll
  for(int o=32;o;o>>=1) v += __shfl_xor(v,o,64);
  return v;
}
__device__ __forceinline__ int wredi(int v){
  #pragma unroll
  for(int o=32;o;o>>=1) v += __shfl_xor(v,o,64);
  return v;
}
// fold 4 nnz-subgroups (lanes l, l^16, l^32, l^48) for 8 accumulator comps
__device__ __forceinline__ void red4x2(float4& a0, float4& a1){
  #pragma unroll
  for (int o=16;o<=32;o<<=1){
    a0.x+=__shfl_xor(a0.x,o,64); a0.y+=__shfl_xor(a0.y,o,64);
    a0.z+=__shfl_xor(a0.z,o,64); a0.w+=__shfl_xor(a0.w,o,64);
    a1.x+=__shfl_xor(a1.x,o,64); a1.y+=__shfl_xor(a1.y,o,64);
    a1.z+=__shfl_xor(a1.z,o,64); a1.w+=__shfl_xor(a1.w,o,64);
  }
}

// agent-scope (L2-bypassing) ops
__device__ __forceinline__ float ldc(const float* p){
  return __hip_atomic_load(p, __ATOMIC_RELAXED, __HIP_MEMORY_SCOPE_AGENT);
}
__device__ __forceinline__ float2 ldc2(const float* p){
  unsigned long long u = __hip_atomic_load((const unsigned long long*)p,
                          __ATOMIC_RELAXED, __HIP_MEMORY_SCOPE_AGENT);
  float2 r; memcpy(&r,&u,8); return r;
}
__device__ __forceinline__ void stc(float* p, float v){
  __hip_atomic_store(p, v, __ATOMIC_RELAXED, __HIP_MEMORY_SCOPE_AGENT);
}
__device__ __forceinline__ void stc2(float* p, float2 v){
  unsigned long long u; memcpy(&u,&v,8);
  __hip_atomic_store((unsigned long long*)p, u, __ATOMIC_RELAXED, __HIP_MEMORY_SCOPE_AGENT);
}
__device__ __forceinline__ int ldci(const int* p){
  return __hip_atomic_load(p, __ATOMIC_RELAXED, __HIP_MEMORY_SCOPE_AGENT);
}
__device__ __forceinline__ void stci(int* p, int v){
  __hip_atomic_store(p, v, __ATOMIC_RELAXED, __HIP_MEMORY_SCOPE_AGENT);
}

// ---- flag-array barrier: NO same-address RMW anywhere ----
__device__ __forceinline__ void barx(float* ws, int b, int grp, int lbase, int Ng,
                                     bool chk, int lb, int ph, int jslot, float* shr){
  const int t = threadIdx.x, lane = t&63, wvv = t>>6;
  int* flg = (int*)ws + W_FLG;
  int* rel = (int*)ws + W_REL;
  __builtin_amdgcn_s_waitcnt(0);   // every thread drains its stores
  __syncthreads();
  if (t==0) stci(flg + (size_t)b*32, ph+1);
  if (chk){
    for (int s=t; s<Ng; s+=256){
      const int* f = flg + (size_t)(lbase+s)*32;
      while (ldci(f) < ph+1) __builtin_amdgcn_s_sleep(1);
    }
    if (jslot>=0){
      float pa=0.f, pg=0.f, pn=0.f;
      for (int s=t; s<Ng; s+=256){
        const float* sl = ws + W_SLOT + ((size_t)jslot*2048 + lbase+s)*8;
        float2 ag = ldc2(sl); float nn = ldc(sl+2);
        pa+=ag.x; pg+=ag.y; pn+=nn;
      }
      pa=wredf(pa); pg=wredf(pg); pn=wredf(pn);
      if (lane==0){ shr[0*4+wvv]=pa; shr[1*4+wvv]=pg; shr[2*4+wvv]=pn; }
    }
    __syncthreads();
    if (t==0){
      if (jslot>=0){
        float a=shr[0]+shr[1]+shr[2]+shr[3];
        float g=shr[4]+shr[5]+shr[6]+shr[7];
        float n=shr[8]+shr[9]+shr[10]+shr[11];
        float* TT = ws + W_TT + (size_t)(grp*64 + jslot)*32;
        stc2(TT, make_float2(a,g)); stc(TT+2, n);
        __builtin_amdgcn_s_waitcnt(0);   // TT visible before release
      }
      #pragma unroll
      for (int i=0;i<16;i++) stci(rel + (size_t)(grp*16+i)*32, ph+1);
    }
    __syncthreads();
  } else {
    if (t==0){
      const int* r = rel + (size_t)(grp*16 + (lb&15))*32;
      while (ldci(r) < ph+1) __builtin_amdgcn_s_sleep(1);
    }
    __syncthreads();
  }
}

// ---------------- weight prep + zeroing of counters/flags ----------------
__global__ void k_wprep(const float* Wd,const float* Wu,const float* Wh,
                        const float* Wb1,const float* Wb2, float* ws){
  int t = blockIdx.x*256 + threadIdx.x;
  if (t >= 16384) return;
  int* wsi = (int*)ws;
  if (t < 5120) wsi[W_CNT + 13312 + t] = 0;          // transpose col counters
  if (t < 5120) wsi[W_CUR + t] = 0;                  // cursors
  for (int i=t; i<65536+2048; i+=16384) wsi[W_FLG+i] = 0;  // flags + releases
  float sd = Wd[t]  + Wd[16384+t]  + Wd[32768+t];
  float su = Wu[t]  + Wu[16384+t]  + Wu[32768+t];
  float s1 = Wb1[t] + Wb1[16384+t] + Wb1[32768+t];
  float s2 = Wb2[t] + Wb2[16384+t] + Wb2[32768+t];
  float wh = Wh[t];
  float* W0 = ws + W_WCAT + WC0;
  float* W1 = ws + W_WCAT + WC1;
  float* W2 = ws + W_WCAT + WC2;
  W0[t]=sd; W0[16384+t]=s1; W0[32768+t]=wh;
  W1[t]=sd; W1[16384+t]=su; W1[32768+t]=s1; W1[49152+t]=s2; W1[65536+t]=wh;
  W2[t]=su; W2[16384+t]=s2; W2[32768+t]=wh;
}

// ---------------- CSR extraction (proven) ----------------
__device__ __forceinline__ void mat_meta(int wid, const float* L0,const float* L1d,const float* L1u,
    const float* L2,const float* B1,const float* B2,
    const float*& M,int& ncol,int& lrow,int& co,int& po,int& cb,int& cap,int& tco){
  if (wid < 1024){ M=L0;  ncol=1024; lrow=wid;        co=C_L0;  po=P_L0;  cb=CB_L0;  cap=CAP_L0; tco=-1; }
  else if (wid < 4096){ M=L1d; ncol=3072; lrow=wid-1024;  co=C_L1D; po=P_L1D; cb=CB_L1D; cap=CAP_L1; tco=-1; }
  else if (wid < 7168){ M=L1u; ncol=3072; lrow=wid-4096;  co=C_L1U; po=P_L1U; cb=CB_L1U; cap=CAP_L1; tco=-1; }
  else if (wid < 9216){ M=L2;  ncol=2048; lrow=wid-7168;  co=C_L2;  po=P_L2;  cb=CB_L2;  cap=CAP_L2; tco=-1; }
  else if (wid < 10240){ M=B1; ncol=3072; lrow=wid-9216;  co=C_B1;  po=P_B1;  cb=CB_B1;  cap=CAP_B1; tco=C_B1T; }
  else { M=B2; ncol=2048; lrow=wid-10240; co=C_B2;  po=P_B2;  cb=CB_B2;  cap=CAP_B2; tco=C_B2T; }
}

__global__ void k_count(const float* L0,const float* L1d,const float* L1u,const float* L2,
                        const float* B1,const float* B2,int* cnt){
  int wid = blockIdx.x*4 + (threadIdx.x>>6);
  int lane = threadIdx.x & 63;
  if (wid >= 13312) return;
  const float* M; int ncol,lrow,co,po,cb,cap,tco;
  mat_meta(wid,L0,L1d,L1u,L2,B1,B2,M,ncol,lrow,co,po,cb,cap,tco);
  const float4* row4 = (const float4*)(M + (size_t)lrow*ncol);
  int c = 0;
  for (int j0=0; j0<ncol; j0+=256){
    float4 v = row4[(j0>>2)+lane];
    int n0=v.x!=0.f, n1=v.y!=0.f, n2=v.z!=0.f, n3=v.w!=0.f;
    c += n0+n1+n2+n3;
    if (tco>=0){
      int jb = j0 + lane*4;
      if (n0) atomicAdd(cnt+tco+jb,   1);
      if (n1) atomicAdd(cnt+tco+jb+1, 1);
      if (n2) atomicAdd(cnt+tco+jb+2, 1);
      if (n3) atomicAdd(cnt+tco+jb+3, 1);
    }
  }
  c = wredi(c);
  if (lane==0) cnt[co+lrow] = c;
}

__global__ void k_prefix(const int* cnt, int* ptr, int* cur){
  __shared__ int lds[257];
  const int rows[8]={1024,3072,3072,2048,1024,3072,3072,2048};
  const int cofs[8]={C_L0,C_L1D,C_L1U,C_L2,C_B1,C_B2,C_B1T,C_B2T};
  const int pofs[8]={P_L0,P_L1D,P_L1U,P_L2,P_B1,P_B2,P_B1T,P_B2T};
  int b=blockIdx.x, t=threadIdx.x;
  int R=rows[b]; const int* c=cnt+cofs[b]; int* p=ptr+pofs[b];
  int* cc = (b==6)? cur : (b==7)? cur+3072 : nullptr;
  int chunk=(R+255)/256;
  int lo=t*chunk, hi=min(R,lo+chunk);
  int s=0;
  for(int i=lo;i<hi;i++) s+=c[i];
  lds[t]=s; __syncthreads();
  if(t==0){ int run=0; for(int i=0;i<256;i++){int x=lds[i];lds[i]=run;run+=x;} lds[256]=run; }
  __syncthreads();
  int run=lds[t];
  for(int i=lo;i<hi;i++){ p[i]=run; if(cc) cc[i]=run; run+=c[i]; }
  if(t==0) p[R]=lds[256];
}

__global__ void k_fill(const float* L0,const float* L1d,const float* L1u,const float* L2,
                       const float* B1,const float* B2,const int* ptr,int* cidx,float* val){
  int wid = blockIdx.x*4 + (threadIdx.x>>6);
  int lane = threadIdx.x & 63;
  if (wid >= 13312) return;
  const float* M; int ncol,lrow,co,po,cb,cap,tco;
  mat_meta(wid,L0,L1d,L1u,L2,B1,B2,M,ncol,lrow,co,po,cb,cap,tco);
  const float4* row4 = (const float4*)(M + (size_t)lrow*ncol);
  int base = ptr[po+lrow];
  int run = 0;
  for (int j0=0; j0<ncol; j0+=256){
    float4 v = row4[(j0>>2)+lane];
    int n0=v.x!=0.f, n1=v.y!=0.f, n2=v.z!=0.f, n3=v.w!=0.f;
    int local = n0+n1+n2+n3;
    int incl = local;
    #pragma unroll
    for (int o=1;o<64;o<<=1){
      int tmp = __shfl_up(incl,o,64);
      if (lane>=o) incl += tmp;
    }
    int tot = __shfl(incl,63,64);
    int pos = base + run + incl - local;
    int jb = j0 + lane*4;
    if (n0){ if(pos<cap){cidx[cb+pos]=jb;   val[cb+pos]=v.x;} pos++; }
    if (n1){ if(pos<cap){cidx[cb+pos]=jb+1; val[cb+pos]=v.y;} pos++; }
    if (n2){ if(pos<cap){cidx[cb+pos]=jb+2; val[cb+pos]=v.z;} pos++; }
    if (n3){ if(pos<cap){cidx[cb+pos]=jb+3; val[cb+pos]=v.w;} pos++; }
    run += tot;
  }
}

__global__ void k_fillT(float* ws){
  int wid = blockIdx.x*4 + (threadIdx.x>>6);
  int lane = threadIdx.x & 63;
  if (wid >= 4096) return;
  int* wsi=(int*)ws;
  const int* ptr=wsi+W_PTR; int* cidx=wsi+W_CIDX; float* val=ws+W_VAL;
  int* cur=wsi+W_CUR;
  if (wid < 1024){
    int r=wid;
    int e=ptr[P_B1+r+1];
    for(int k=ptr[P_B1+r]+lane;k<e;k+=64){
      int c=cidx[CB_B1+k]; float v=val[CB_B1+k];
      int pos=atomicAdd(cur+c,1);
      cidx[CB_B1T+pos]=r; val[CB_B1T+pos]=v;
    }
  } else {
    int r=wid-1024;
    int e=ptr[P_B2+r+1];
    for(int k=ptr[P_B2+r]+lane;k<e;k+=64){
      int c=cidx[CB_B2+k]; float v=val[CB_B2+k];
      int pos=atomicAdd(cur+3072+c,1);
      cidx[CB_B2T+pos]=r; val[CB_B2T+pos]=v;
    }
  }
}

// ================= FUSED PERSISTENT SOLVER =================
// 2048 blocks x 256 threads, 8 blocks/CU -> 32 waves/CU (94% occupancy).
// Groups by ROWS (niter=1 everywhere, no serial row-batches / stragglers):
//   g0=c0 [0,336) 1344 waves/1024 rows; g1=c1 [336,1360) 4096/3072;
//   g2=c2 [1360,2048) 2752/2048. ONE WAVE PER ROW in lz and harm.
__global__ __launch_bounds__(256,8) void k_solve(float* ws,
    const float* z0,const float* z1,const float* z2,
    const float* adw,const float* adb,const float* auw,const float* aub,
    float* out){
  const int b = blockIdx.x, t = threadIdx.x;
  const int wv = t>>6, lane = t&63;
  const int sg = lane>>4, chn = lane&15;   // nnz-subgroup, channel-sixteenth
  const int* wsi=(const int*)ws;
  const int* ptr=wsi+W_PTR; const int* cidx=wsi+W_CIDX; const float* val=ws+W_VAL;

  __shared__ float smem[2616];             // 10464 B
  float* Sl  = smem;                       // [544]   phase E
  float* Wl  = smem + 544;                 // [2048]  phase E
  float* TTa = smem;                       // [64]    eig (alias, disjoint in time)
  float* TTb = smem + 64;                  // [64]
  float* redm= smem + 2592;                // [12]    phase B block partials
  float* shr = smem + 2604;                // [12]    barrier payload scratch

  // group mapping (block counts proportional to ROWS; all divisible by 16)
  int g, nb, crows, bbase, Ng, lb;
  if (b<336){ g=0; lb=b;        nb=0;    crows=1024; bbase=0;    Ng=336;  }
  else if (b<1360){ g=1; lb=b-336;  nb=1024; crows=3072; bbase=336;  Ng=1024; }
  else { g=2; lb=b-1360; nb=4096; crows=2048; bbase=1360; Ng=688;  }
  const int gwv = lb*4 + wv;               // wave id within group
  const int GW  = Ng*4;                    // waves per group (>= crows)
  const bool chk = (b==bbase);
  const float* zc = (g==0)?z0:(g==1)?z1:z2;
  int ph = 0;

  // ---- Phase A: v_0 init + attention U,V ----
  { int i = b*256+t;
    if (i < 6144){
      float invs = (i<1024)?0.03125f:(i<4096)?0.0180421959f:0.0220970869f;
      unsigned uu=(unsigned)i*2654435761u; uu^=uu>>16; uu*=2246822519u; uu^=uu>>13;
      stc(ws+W_VW+i, (uu&1)?invs:-invs);     // v_0
    }
  }
  { int gw = b*4+wv;
    if (gw < 3072){
      float2 x  = ((const float2*)(z1+(size_t)gw*128))[lane];
      float2 a0 = ((const float2*)adw)[lane];
      float2 a1 = ((const float2*)adw)[64+lane];
      float2 b0 = ((const float2*)auw)[lane];
      float2 b1 = ((const float2*)auw)[64+lane];
      float ud=x.x*a0.x+x.y*a0.y, vd=x.x*a1.x+x.y*a1.y;
      float uu=x.x*b0.x+x.y*b0.y, vu=x.x*b1.x+x.y*b1.y;
      ud=wredf(ud); vd=wredf(vd); uu=wredf(uu); vu=wredf(vu);
      if(lane==0){ stc(ws+W_UV+gw,ud); stc(ws+W_UV+3072+gw,vd);
                   stc(ws+W_UV+6144+gw,uu); stc(ws+W_UV+9216+gw,vu); }
    }
  }
  barx(ws, b, 3, 0, 2048, b==0, b, ph, -1, shr); ph++;   // global: v_0, UV visible

  // ---- Phase B: M_LZ Lanczos steps (one wave per row, niter=1) ----
  for (int j=0;j<M_LZ;j++){
    float a, gmm, ib;
    if (j==0){ a=0.f; gmm=0.f; ib=1.f; }
    else {
      const float* TT = ws + W_TT + (size_t)(g*64 + (j-1))*32;
      a = TT[0]; gmm = TT[1]; float n = TT[2];
      ib = 1.f/sqrtf(fmaxf(n - a*a - gmm*gmm, 1e-20f));
    }
    const float* vj   = ws + W_VW + (size_t)j*6144;
    const float* vm1  = ws + W_VW + (size_t)(j>0? j-1:0)*6144;
    const float* vm2  = ws + W_VW + (size_t)(j>1? j-2:0)*6144;
    const float* wpv  = ws + W_VW + (size_t)(64 + (j>0? j-1:0))*6144;
    float* vjw        = ws + W_VW + (size_t)j*6144;
    float* wjw        = ws + W_VW + (size_t)(64+j)*6144;
    float Aa=0.f, Gg=0.f, Nn=0.f;
    for (int p = gwv; p < crows; p += GW){
      float wp=0.f;
      #define GATHER(PP,CBB) { \
        const int* rp = ptr + PP; int e=rp[p+1]; \
        for (int k=rp[p]+lane; k<e; k+=64){ \
          int q = nb + cidx[CBB+k]; float v = val[CBB+k]; \
          float vq = (j==0)? vj[q] : (wpv[q] - a*vm1[q] - gmm*vm2[q])*ib; \
          wp += v*vq; \
        } }
      if (g==0){ GATHER(P_L0, CB_L0) }
      else if (g==1){ GATHER(P_L1D, CB_L1D) GATHER(P_L1U, CB_L1U) }
      else { GATHER(P_L2, CB_L2) }
      #undef GATHER
      wp = wredf(wp);
      if (lane==0){
        int gp = nb + p;
        float vp, vm1p;
        if (j==0){ vp = vj[gp]; vm1p = 0.f; }
        else { vp = (wpv[gp] - a*vm1[gp] - gmm*vm2[gp])*ib; stc(vjw+gp, vp); vm1p = vm1[gp]; }
        stc(wjw+gp, wp);
        Aa += vp*wp; Gg += vm1p*wp; Nn += wp*wp;
      }
    }
    if (lane==0){ redm[0*4+wv]=Aa; redm[1*4+wv]=Gg; redm[2*4+wv]=Nn; }
    __syncthreads();
    if (t==0){
      float A0=redm[0]+redm[1]+redm[2]+redm[3];
      float G0=redm[4]+redm[5]+redm[6]+redm[7];
      float N0=redm[8]+redm[9]+redm[10]+redm[11];
      float* sl2 = ws + W_SLOT + ((size_t)j*2048 + b)*8;
      stc2(sl2, make_float2(A0,G0)); stc(sl2+2, N0);
    }
    barx(ws, b, g, bbase, Ng, chk, lb, ph, j, shr); ph++;
  }

  // ---- eig: one wave of each group's checker block ----
  if (chk && t<64){
    int i = t;
    { const float* TT = ws + W_TT + (size_t)(g*64 + i)*32;
      float a=TT[0], gg=TT[1], n=TT[2];
      TTa[i]=a; TTb[i]=sqrtf(fmaxf(n-a*a-gg*gg,1e-20f));
    }
    double lo, hi;
    { double r=(i? fabs((double)TTb[i-1]):0.0) + (i<M_LZ-1? fabs((double)TTb[i]):0.0);
      lo=(double)TTa[i]-r; hi=(double)TTa[i]+r; }
    #pragma unroll
    for(int o=32;o;o>>=1){ lo=fmin(lo,__shfl_xor(lo,o,64)); hi=fmax(hi,__shfl_xor(hi,o,64)); }
    lo -= 1.0; hi += 1.0;
    for (int round=0; round<4; round++){
      double x = lo + (hi-lo)*(double)(i+1)/65.0;
      double d = 1.0; int cnt2=0;
      for (int k2=0;k2<M_LZ;k2++){
        double bi = k2? (double)TTb[k2-1] : 0.0;
        d = ((double)TTa[k2]-x) - bi*bi/d;
        if (d==0.0) d = -1e-300;
        if (d<0.0) cnt2++;
      }
      double nlo = (cnt2< M_LZ)? x : -1e300;
      double nhi = (cnt2==M_LZ)? x :  1e300;
      #pragma unroll
      for(int o=32;o;o>>=1){ nlo=fmax(nlo,__shfl_xor(nlo,o,64)); nhi=fmin(nhi,__shfl_xor(nhi,o,64)); }
      if (nlo>-1e299) lo=nlo;
      if (nhi< 1e299) hi=nhi;
    }
    double lam = 0.5*(lo+hi);
    if (i==0) stc(ws+W_EPS+(size_t)g*32, (lam>0.0)? (float)(1.0/lam) : 0.1f);
  }
  barx(ws, b, g, bbase, Ng, chk, lb, ph, -1, shr); ph++;   // eps visible within group

  // ---- Phase D: 16 harmonic steps (one wave per row, 4-way nnz-parallel) ----
  {
    float eps = ws[W_EPS+(size_t)g*32];
    for (int s=0;s<16;s++){
      const float* inH = ws + W_H + (size_t)(s>0? s-1:0)*HBUF;
      for (int p = gwv; p < crows; p += GW){
        int gp = nb + p;
        float4 a0={0.f,0.f,0.f,0.f}, a1={0.f,0.f,0.f,0.f};
        #define HG(PP,CBB) { \
          const int* rp=ptr+PP; int e=rp[p+1]; \
          for(int k=rp[p]+sg;k<e;k+=4){ \
            float v=val[CBB+k]; int q=cidx[CBB+k]; \
            const float* sr = (s==0)? zc+(size_t)q*128 : inH+(size_t)(nb+q)*128; \
            float4 x0 = ((const float4*)sr)[chn*2]; \
            float4 x1 = ((const float4*)sr)[chn*2+1]; \
            a0.x+=v*x0.x; a0.y+=v*x0.y; a0.z+=v*x0.z; a0.w+=v*x0.w; \
            a1.x+=v*x1.x; a1.y+=v*x1.y; a1.z+=v*x1.z; a1.w+=v*x1.w; \
          } }
        if (g==0){ HG(P_L0, CB_L0) }
        else if (g==1){ HG(P_L1D, CB_L1D) HG(P_L1U, CB_L1U) }
        else { HG(P_L2, CB_L2) }
        #undef HG
        red4x2(a0, a1);
        if (sg==0){
          const float* ownr = (s==0)? zc+(size_t)p*128 : inH+(size_t)gp*128;
          float4 o0 = ((const float4*)ownr)[chn*2];
          float4 o1 = ((const float4*)ownr)[chn*2+1];
          float* dst;
          if (s<15) dst = ws + W_H + (size_t)s*HBUF + (size_t)gp*128;
          else {
            float* outp; size_t ostride;
            if(g==0){ outp=ws+W_SCAT+S0_OFF+256; ostride=384; }
            else if(g==1){ outp=ws+W_SCAT+S1_OFF+512; ostride=640; }
            else { outp=ws+W_SCAT+S2_OFF+256; ostride=384; }
            dst = outp + (size_t)p*ostride;
          }
          stc2(dst+chn*8,   make_float2(o0.x-eps*a0.x, o0.y-eps*a0.y));
          stc2(dst+chn*8+2, make_float2(o0.z-eps*a0.z, o0.w-eps*a0.w));
          stc2(dst+chn*8+4, make_float2(o1.x-eps*a1.x, o1.y-eps*a1.y));
          stc2(dst+chn*8+6, make_float2(o1.z-eps*a1.z, o1.w-eps*a1.w));
        }
      }
      if (s<15){ barx(ws, b, g, bbase, Ng, chk, lb, ph, -1, shr); ph++; }
    }
  }

  // ---- Phase C: forward SpMMs (all blocks; 4-way nnz-parallel, 8192 waves) ----
  for (int wid2 = b*4+wv; wid2 < 18432; wid2 += 8192){
    int task,p;
    if(wid2<1024){task=0;p=wid2;}
    else if(wid2<2048){task=1;p=wid2-1024;}
    else if(wid2<5120){task=2;p=wid2-2048;}
    else if(wid2<8192){task=3;p=wid2-5120;}
    else if(wid2<11264){task=4;p=wid2-8192;}
    else if(wid2<13312){task=5;p=wid2-11264;}
    else if(wid2<16384){task=6;p=wid2-13312;}
    else {task=7;p=wid2-16384;}
    const float* in; const int* rp; int cb2; float* outp; int ostride;
    int mode=0; float Vp=0.f, bb=0.f; const float* U=nullptr;
    switch(task){
      case 0: rp=ptr+P_L0;  cb2=CB_L0;  in=z0; outp=ws+W_SCAT+S0_OFF+0;   ostride=384; break;
      case 1: rp=ptr+P_B1;  cb2=CB_B1;  in=z1; outp=ws+W_SCAT+S0_OFF+128; ostride=384; break;
      case 2: rp=ptr+P_L1D; cb2=CB_L1D; in=z1; outp=ws+W_SCAT+S1_OFF+0;   ostride=640;
              mode=1; U=ws+W_UV; Vp=ws[W_UV+3072+p]; bb=adb[0]; break;
      case 3: rp=ptr+P_L1U; cb2=CB_L1U; in=z1; outp=ws+W_SCAT+S1_OFF+128; ostride=640;
              mode=1; U=ws+W_UV+6144; Vp=ws[W_UV+9216+p]; bb=aub[0]; break;
      case 4: rp=ptr+P_B2;  cb2=CB_B2;  in=z2; outp=ws+W_SCAT+S1_OFF+384; ostride=640; break;
      case 5: rp=ptr+P_L2;  cb2=CB_L2;  in=z2; outp=ws+W_SCAT+S2_OFF+0;   ostride=384; break;
      case 6: rp=ptr+P_B1T; cb2=CB_B1T; in=z0; outp=ws+W_SCAT+S1_OFF+256; ostride=640; break;
      default:rp=ptr+P_B2T; cb2=CB_B2T; in=z1; outp=ws+W_SCAT+S2_OFF+128; ostride=384; break;
    }
    float4 a0={0.f,0.f,0.f,0.f}, a1={0.f,0.f,0.f,0.f};
    int e=rp[p+1];
    for (int k=rp[p]+sg; k<e; k+=4){
      int q = cidx[cb2+k];
      float v;
      if (mode) v = 1.0f/(1.0f+__expf(-(U[q]+Vp+bb)));
      else v = val[cb2+k];
      const float* sr = in + (size_t)q*128;
      float4 x0 = ((const float4*)sr)[chn*2];
      float4 x1 = ((const float4*)sr)[chn*2+1];
      a0.x+=v*x0.x; a0.y+=v*x0.y; a0.z+=v*x0.z; a0.w+=v*x0.w;
      a1.x+=v*x1.x; a1.y+=v*x1.y; a1.z+=v*x1.z; a1.w+=v*x1.w;
    }
    red4x2(a0, a1);
    if (sg==0){
      float* dst = outp + (size_t)p*ostride;
      stc2(dst+chn*8,   make_float2(a0.x,a0.y));
      stc2(dst+chn*8+2, make_float2(a0.z,a0.w));
      stc2(dst+chn*8+4, make_float2(a1.x,a1.y));
      stc2(dst+chn*8+6, make_float2(a1.z,a1.w));
    }
  }
  barx(ws, b, 3, 0, 2048, b==0, b, ph, -1, shr); ph++;   // global join: SCAT complete

  // ---- Phase E: projection GEMMs (blocks 0..191), K-tile 16 ----
  if (b < 192){
    const float* S; const float* W; float* outp; int K; int blk;
    if (b<32){       S=ws+W_SCAT+S0_OFF; W=ws+W_WCAT+WC0; outp=out;        K=384; blk=b; }
    else if (b<128){ S=ws+W_SCAT+S1_OFF; W=ws+W_WCAT+WC1; outp=out+131072; K=640; blk=b-32; }
    else {           S=ws+W_SCAT+S2_OFF; W=ws+W_WCAT+WC2; outp=out+524288; K=384; blk=b-128; }
    int r0=blk*32;
    int ty=t>>5, tx=t&31;
    float acc[4][4]={};
    for (int k0=0; k0<K; k0+=16){
      {
        int r=t>>3, kq=(t&7)*2;
        const float* src=S+(size_t)(r0+r)*K + k0+kq;
        Sl[r*17+kq]=src[0]; Sl[r*17+kq+1]=src[1];
      }
      {
        int kk=t>>4, cq=(t&15)*8;
        const float* src=W+(size_t)(k0+kk)*128+cq;
        #pragma unroll
        for(int i=0;i<8;i++) Wl[kk*128+cq+i]=src[i];
      }
      __syncthreads();
      #pragma unroll
      for(int k=0;k<16;k++){
        float sv[4], wvv2[4];
        #pragma unroll
        for(int i=0;i<4;i++) sv[i]=Sl[(ty*4+i)*17+k];
        #pragma unroll
        for(int i=0;i<4;i++) wvv2[i]=Wl[k*128+tx+32*i];
        #pragma unroll
        for(int a2=0;a2<4;a2++)
          #pragma unroll
          for(int b2=0;b2<4;b2++) acc[a2][b2]+=sv[a2]*wvv2[b2];
      }
      __syncthreads();
    }
    #pragma unroll
    for(int a2=0;a2<4;a2++)
      #pragma unroll
      for(int b2=0;b2<4;b2++){
        int r=r0+ty*4+a2, col=tx+32*b2;
        outp[(size_t)r*128+col]=fmaxf(acc[a2][b2],0.f);
      }
  }
}

// ---------------- host ----------------
extern "C" void kernel_launch(void* const* d_in, const int* in_sizes, int n_in,
                              void* d_out, int out_size, void* d_ws, size_t ws_size,
                              hipStream_t stream){
  const float* z0 =(const float*)d_in[0];
  const float* z1 =(const float*)d_in[1];
  const float* z2 =(const float*)d_in[2];
  const float* L0 =(const float*)d_in[3];
  const float* L1d=(const float*)d_in[4];
  const float* L1u=(const float*)d_in[5];
  const float* L2 =(const float*)d_in[6];
  const float* B1 =(const float*)d_in[7];
  const float* B2 =(const float*)d_in[8];
  const float* Wd =(const float*)d_in[9];
  const float* Wu =(const float*)d_in[10];
  const float* Wh =(const float*)d_in[11];
  const float* Wb1=(const float*)d_in[12];
  const float* Wb2=(const float*)d_in[13];
  const float* adw=(const float*)d_in[14];
  const float* adb=(const float*)d_in[15];
  const float* auw=(const float*)d_in[16];
  const float* aub=(const float*)d_in[17];
  float* ws=(float*)d_ws;
  int* wsi=(int*)d_ws;
  float* out=(float*)d_out;

  hipLaunchKernelGGL(k_wprep, dim3(64), dim3(256), 0, stream, Wd,Wu,Wh,Wb1,Wb2,ws);
  hipLaunchKernelGGL(k_count, dim3(3328), dim3(256), 0, stream, L0,L1d,L1u,L2,B1,B2, wsi+W_CNT);
  hipLaunchKernelGGL(k_prefix, dim3(8), dim3(256), 0, stream, wsi+W_CNT, wsi+W_PTR, wsi+W_CUR);
  hipLaunchKernelGGL(k_fill, dim3(3328), dim3(256), 0, stream, L0,L1d,L1u,L2,B1,B2, wsi+W_PTR, wsi+W_CIDX, ws+W_VAL);
  hipLaunchKernelGGL(k_fillT, dim3(1024), dim3(256), 0, stream, ws);
  hipLaunchKernelGGL(k_solve, dim3(2048), dim3(256), 0, stream,
                     ws, z0, z1, z2, adw, adb, auw, aub, out);
}